// Round 4
// baseline (139137.744 us; speedup 1.0000x reference)
//
#include <hip/hip_runtime.h>

// Problem constants
constexpr int B_   = 32;
constexpr int S_   = 512;
constexpr int T_   = 512;
constexpr int ENC_ = 512;
constexpr int ATT_ = 128;
constexpr int PO_  = 256;
constexpr int DEC_ = 1024;
constexpr int M_   = 128;
constexpr int G3_  = 3072;

// Output offsets (floats)
constexpr int MEL_OFF  = 0;
constexpr int STOP_OFF = B_*T_*M_;            // 2,097,152
constexpr int AW_OFF   = STOP_OFF + B_*T_;    // 2,113,536

typedef __attribute__((ext_vector_type(8))) short bf16x8;
typedef __attribute__((ext_vector_type(4))) float f32x4;

__device__ __forceinline__ float frcp(float x){ return __builtin_amdgcn_rcpf(x); }
__device__ __forceinline__ float ftanh(float x){ float e = __expf(2.f*x); return 1.f - 2.f*frcp(e + 1.f); }
__device__ __forceinline__ float fsig(float x){ return frcp(1.f + __expf(-x)); }

__device__ __forceinline__ float2 upk2(unsigned u){
    return make_float2(__builtin_bit_cast(float, u << 16),
                       __builtin_bit_cast(float, u & 0xffff0000u));
}
__device__ __forceinline__ unsigned short f2b(float f){
    unsigned u = __builtin_bit_cast(unsigned, f);
    return (unsigned short)((u + 0x7fffu + ((u >> 16) & 1u)) >> 16);
}
__device__ __forceinline__ unsigned pk2(float a, float b){
    return (unsigned)f2b(a) | ((unsigned)f2b(b) << 16);
}

// agent-scope write-through stores (device-coherent)
__device__ __forceinline__ void astf(float* p, float v){
    __hip_atomic_store(p, v, __ATOMIC_RELAXED, __HIP_MEMORY_SCOPE_AGENT);
}
union F2U { float2 f; unsigned long long u; };
__device__ __forceinline__ void ast2f(float* p, float a, float b){
    F2U x; x.f = make_float2(a, b);
    __hip_atomic_store((unsigned long long*)p, x.u, __ATOMIC_RELAXED, __HIP_MEMORY_SCOPE_AGENT);
}
__device__ __forceinline__ void astu(unsigned* p, unsigned v){
    __hip_atomic_store(p, v, __ATOMIC_RELAXED, __HIP_MEMORY_SCOPE_AGENT);
}

// grid barrier with proper agent-scope release/acquire (acquire invalidates L1/L2
// so subsequent PLAIN loads of cross-block data are fresh; read-only data is LDS-pinned
// so the invalidate is cheap)
__device__ __forceinline__ void gbar(unsigned* cnt, unsigned target){
    __builtin_amdgcn_fence(__ATOMIC_RELEASE, "agent");
    __syncthreads();
    if (threadIdx.x == 0){
        __hip_atomic_fetch_add(cnt, 1u, __ATOMIC_RELAXED, __HIP_MEMORY_SCOPE_AGENT);
        while (__hip_atomic_load(cnt, __ATOMIC_RELAXED, __HIP_MEMORY_SCOPE_AGENT) < target)
            __builtin_amdgcn_s_sleep(2);
    }
    __syncthreads();
    __builtin_amdgcn_fence(__ATOMIC_ACQUIRE, "agent");
}

__device__ __forceinline__ bf16x8 packA(const float* row){
    float4 a = *(const float4*)row, b = *(const float4*)(row + 4);
    bf16x8 r;
    r[0] = (short)f2b(a.x); r[1] = (short)f2b(a.y); r[2] = (short)f2b(a.z); r[3] = (short)f2b(a.w);
    r[4] = (short)f2b(b.x); r[5] = (short)f2b(b.y); r[6] = (short)f2b(b.z); r[7] = (short)f2b(b.w);
    return r;
}
__device__ __forceinline__ f32x4 mfma16(bf16x8 a, bf16x8 b, f32x4 c){
    return __builtin_amdgcn_mfma_f32_16x16x32_bf16(a, b, c, 0, 0, 0);
}
__device__ __forceinline__ void lds_fadd(float* p, float v){
    __hip_atomic_fetch_add(p, v, __ATOMIC_RELAXED, __HIP_MEMORY_SCOPE_WORKGROUP);
}

// ================= prep kernels =================

// elementwise re-layout into bf16 staging (fragment order for MFMA operands)
__global__ __launch_bounds__(256) void k_prep_w(const float* __restrict__ enc,
        const float* __restrict__ whh, const float* __restrict__ wih,
        const float* __restrict__ oww,
        unsigned short* __restrict__ enc_b, unsigned short* __restrict__ whh_f,
        unsigned short* __restrict__ wix_f, unsigned short* __restrict__ wic_f,
        unsigned short* __restrict__ ow_g){
    long long idx = (long long)blockIdx.x*256 + threadIdx.x;
    if (idx < 8388608LL){                       // enc_b [256 blk][64 s][512 e]
        int blk = (int)(idx >> 15); int r = (int)(idx & 32767);
        int s = r >> 9, e = r & 511;
        int b = blk & 31, ss = blk >> 5;
        enc_b[idx] = f2b(enc[((size_t)b*S_ + ss*64 + s)*ENC_ + e]);
    } else if (idx < 11534336LL){               // whh_f [192 g][32 kc][64 l][8 e]
        long long q = idx - 8388608LL;
        int g = (int)(q >> 14); int r = (int)(q & 16383);
        int kc = r >> 9, l = (r >> 3) & 63, e = r & 7;
        int k = kc*32 + (l >> 4)*8 + e;
        whh_f[q] = f2b(whh[(size_t)(g*16 + (l & 15))*DEC_ + k]);
    } else if (idx < 12320768LL){               // wix_f [192 g][8 kc][64][8]
        long long q = idx - 11534336LL;
        int g = (int)(q >> 12); int r = (int)(q & 4095);
        int kc = r >> 9, l = (r >> 3) & 63, e = r & 7;
        int k = kc*32 + (l >> 4)*8 + e;
        wix_f[q] = f2b(wih[(size_t)(g*16 + (l & 15))*768 + k]);
    } else if (idx < 13893632LL){               // wic_f [64 ds][3 jt][16 kc][64][8]
        long long q = idx - 12320768LL;
        int ds = (int)(q / 24576); int r = (int)(q % 24576);
        int jt = r >> 13; int r2 = r & 8191;
        int kc = r2 >> 9, l = (r2 >> 3) & 63, e = r2 & 7;
        int k = kc*32 + (l >> 4)*8 + e;
        int jg = jt*1024 + ds*16 + (l & 15);
        wic_f[q] = f2b(wih[(size_t)jg*768 + 256 + k]);
    } else if (idx < 14090240LL){               // ow_g [4 cg][32 oc][1536 k]
        long long q = idx - 13893632LL;
        int cg = (int)(q / 49152); int r = (int)(q % 49152);
        int oc = r / 1536, k = r % 1536;
        ow_g[q] = f2b(oww[(size_t)k*M_ + cg*32 + oc]);
    }
}

// ep_b[blk][64 s][128 a] = bf16(enc @ att_we + be), blk = (b = blk&31, ss = blk>>5)
__global__ __launch_bounds__(256) void k_encproj2(const float* __restrict__ enc,
        const float* __restrict__ we, const float* __restrict__ be,
        unsigned short* __restrict__ ep_b){
    __shared__ float we_s[64*128];
    __shared__ float enc_s[64*64];
    int blk = blockIdx.x, tid = threadIdx.x;
    int b = blk & 31, ss = blk >> 5;
    int s = tid >> 2, ag = tid & 3;
    float acc[32];
    #pragma unroll
    for (int j = 0; j < 32; ++j) acc[j] = 0.f;
    for (int kc = 0; kc < 8; ++kc){
        __syncthreads();
        for (int i = tid; i < 8192; i += 256)
            we_s[i] = we[(size_t)(kc*64 + (i >> 7))*ATT_ + (i & 127)];
        for (int i = tid; i < 4096; i += 256)
            enc_s[i] = enc[((size_t)b*S_ + ss*64 + (i >> 6))*ENC_ + kc*64 + (i & 63)];
        __syncthreads();
        for (int kk = 0; kk < 64; ++kk){
            float ev = enc_s[s*64 + kk];
            const float* wr = &we_s[(kk << 7) + (ag << 5)];
            #pragma unroll
            for (int j = 0; j < 32; ++j) acc[j] += ev*wr[j];
        }
    }
    #pragma unroll
    for (int j = 0; j < 32; ++j){
        int a = (ag << 5) + j;
        ep_b[((size_t)blk*64 + s)*ATT_ + a] = f2b(acc[j] + be[a]);
    }
}

// PreNet for all t (f32), unchanged logic from prior rounds
__global__ __launch_bounds__(128) void k_prenet(const float* __restrict__ tm,
        const float* __restrict__ w1, const float* __restrict__ b1,
        const float* __restrict__ w2, const float* __restrict__ b2,
        float* __restrict__ xall){
    __shared__ float mel_l[128*20];
    __shared__ float h1_l[256*20];
    int row0 = blockIdx.x << 4;
    int t = row0 >> 5, b0 = row0 & 31;
    int tid = threadIdx.x;
    for (int p = 0; p < 16; p++){
        int idx = tid + (p << 7);
        int k = idx & 127, r = idx >> 7;
        float v = 0.f;
        if (t > 0) v = tm[((size_t)(b0 + r)*T_ + (t - 1))*M_ + k];
        mel_l[k*20 + r] = v;
    }
    __syncthreads();
    float acc1[16], acc2[16];
    #pragma unroll
    for (int i = 0; i < 16; i++){ acc1[i] = 0.f; acc2[i] = 0.f; }
    for (int k = 0; k < M_; k++){
        float wa = w1[k*256 + tid];
        float wb = w1[k*256 + tid + 128];
        float mv[16];
        *(float4*)&mv[0]  = *(const float4*)&mel_l[k*20 + 0];
        *(float4*)&mv[4]  = *(const float4*)&mel_l[k*20 + 4];
        *(float4*)&mv[8]  = *(const float4*)&mel_l[k*20 + 8];
        *(float4*)&mv[12] = *(const float4*)&mel_l[k*20 + 12];
        #pragma unroll
        for (int r = 0; r < 16; r++){ acc1[r] += mv[r]*wa; acc2[r] += mv[r]*wb; }
    }
    float bb1a = b1[tid], bb1b = b1[tid + 128];
    #pragma unroll
    for (int r = 0; r < 16; r++){
        h1_l[tid*20 + r]         = fmaxf(acc1[r] + bb1a, 0.f);
        h1_l[(tid + 128)*20 + r] = fmaxf(acc2[r] + bb1b, 0.f);
    }
    __syncthreads();
    #pragma unroll
    for (int i = 0; i < 16; i++){ acc1[i] = 0.f; acc2[i] = 0.f; }
    for (int k = 0; k < 256; k++){
        float wa = w2[k*256 + tid];
        float wb = w2[k*256 + tid + 128];
        float mv[16];
        *(float4*)&mv[0]  = *(const float4*)&h1_l[k*20 + 0];
        *(float4*)&mv[4]  = *(const float4*)&h1_l[k*20 + 4];
        *(float4*)&mv[8]  = *(const float4*)&h1_l[k*20 + 8];
        *(float4*)&mv[12] = *(const float4*)&h1_l[k*20 + 12];
        #pragma unroll
        for (int r = 0; r < 16; r++){ acc1[r] += mv[r]*wa; acc2[r] += mv[r]*wb; }
    }
    float bb2a = b2[tid], bb2b = b2[tid + 128];
    #pragma unroll
    for (int r = 0; r < 16; r++){
        xall[((size_t)row0 + r)*PO_ + tid]       = fmaxf(acc1[r] + bb2a, 0.f);
        xall[((size_t)row0 + r)*PO_ + tid + 128] = fmaxf(acc2[r] + bb2b, 0.f);
    }
}

// ================= persistent decoder =================
// LDS byte offsets (dynamic, per-role layout; request = 155776)
#define OFF_ENC    0
#define OFF_WHH    65536
#define OFF_WIX    98304
#define OFF_EP     106496
#define OFF_REDG   122880
#define OFF_REDX   124928
#define OFF_DPL_G  126976
#define OFF_VL_G   127488
#define OFF_ESL_G  128000
#define OFF_CTX4   122880
#define OFF_MRED   131072
#define OFF_RD4    131328
#define OFF_WIC    65536
#define OFF_CTXF   114688
#define OFF_RED6   147456
#define OFF_HL     153600
#define OFF_RDL    155648
#define DYN_BYTES  155776

struct KP {
    const float* xall; const unsigned short* enc_b; const unsigned short* ep_b;
    const unsigned short* whh_f; const unsigned short* wix_f; const unsigned short* wic_f;
    const unsigned short* ow_g;
    const float* awd; const float* sw; const float* bd; const float* av; const float* avb;
    const float* bih; const float* bhh; const float* p_ob; const float* p_sb;
    float* hbuf; float* ghb; float* gixb; float* dpp; float* esb; float* denp;
    unsigned* ctxpb; unsigned* cnt; float* out;
};

__global__ __launch_bounds__(1024) void k_persist(KP p){
    extern __shared__ char sm[];
    const int bid = blockIdx.x, tid = threadIdx.x;
    const int lane = tid & 63;
    const int b_att = bid & 31, ss = bid >> 5;
    const bool is_gh   = (bid < 192);
    const bool is_gate = (bid >= 192);
    const bool is_mel  = (bid >= 96 && bid < 128);

    float* att_red = (float*)(sm + (is_gh ? OFF_REDG : OFF_RED6));
    float* att_dpl = (float*)(sm + (is_gh ? OFF_DPL_G : OFF_HL));
    float* att_vl  = att_dpl + 128;
    float* att_esl = att_dpl + 256;

    // ---- preload LDS (once) ----
    {
        uint4* d = (uint4*)(sm + OFF_ENC);
        const uint4* s4 = (const uint4*)(p.enc_b + (size_t)bid*32768);
        for (int i = tid; i < 4096; i += 1024) d[i] = s4[i];
        if (is_gh){
            uint4* wd_ = (uint4*)(sm + OFF_WHH);
            const uint4* ws = (const uint4*)(p.whh_f + (size_t)bid*16384);
            for (int i = tid; i < 2048; i += 1024) wd_[i] = ws[i];
            uint4* xd = (uint4*)(sm + OFF_WIX);
            const uint4* xs = (const uint4*)(p.wix_f + (size_t)bid*4096);
            if (tid < 512) xd[tid] = xs[tid];
            uint4* ed = (uint4*)(sm + OFF_EP);
            const uint4* es = (const uint4*)(p.ep_b + (size_t)bid*8192);
            if (tid < 1024) ed[tid] = es[tid];
        } else {
            uint4* wd_ = (uint4*)(sm + OFF_WIC);
            const uint4* ws = (const uint4*)(p.wic_f + (size_t)(bid - 192)*24576);
            for (int i = tid; i < 3072; i += 1024) wd_[i] = ws[i];
        }
    }
    __syncthreads();

    const int ds = bid - 192;                 // gate role
    const int midx = bid - 96;                // mel role
    const int mbg = midx >> 2, mcg = midx & 3;
    unsigned epoch = 0;

    for (int t = 0; t < T_; ++t){
        const int par = t & 1;
        const float* hp = p.hbuf + (size_t)(t % 3)*(B_*DEC_);
        float*       hn = p.hbuf + (size_t)((t + 1) % 3)*(B_*DEC_);

        // ================= P1: attention (all blocks) =================
        {
            // dproj = bd + sum of 64 dp partials
            {
                int a = tid & 127, g = tid >> 7;
                const float* dppb = p.dpp + b_att*128 + a;
                float dp = 0.f;
                #pragma unroll
                for (int i = 0; i < 8; ++i) dp += dppb[(size_t)(g*8 + i)*4096];
                att_red[tid] = dp;
            }
            __syncthreads();
            if (tid < 128){
                float s = p.bd[tid];
                #pragma unroll
                for (int g = 0; g < 8; ++g) s += att_red[g*128 + tid];
                att_dpl[tid] = s; att_vl[tid] = p.av[tid];
            }
            __syncthreads();
            // scores for 64 s (this block's slice)
            {
                const int sl = tid >> 4, ag = tid & 15;
                const unsigned* epr = is_gh ?
                    (const unsigned*)(sm + OFF_EP) + sl*64 + ag*4 :
                    (const unsigned*)(p.ep_b) + (size_t)bid*4096 + sl*64 + ag*4;
                float sc = 0.f;
                #pragma unroll
                for (int i = 0; i < 4; ++i){
                    float2 e2 = upk2(epr[i]);
                    int a = ag*8 + i*2;
                    sc += ftanh(e2.x + att_dpl[a])*att_vl[a]
                        + ftanh(e2.y + att_dpl[a+1])*att_vl[a+1];
                }
                att_red[tid] = sc;
            }
            __syncthreads();
            if (tid < 64){
                float s = p.avb[0];
                #pragma unroll
                for (int g = 0; g < 16; ++g) s += att_red[tid*16 + g];
                float ev = __expf(s);
                att_esl[tid] = ev;
                astf(&p.esb[b_att*512 + ss*64 + tid], ev);
                float d = ev;
                #pragma unroll
                for (int m = 1; m <= 32; m <<= 1) d += __shfl_xor(d, m);
                if (tid == 0) astf(&p.denp[par*256 + ss*32 + b_att], d);
            }
            __syncthreads();
            // ctx partials from LDS enc slice
            {
                const int e2 = tid >> 2, sg = tid & 3;
                const unsigned* er = (const unsigned*)(sm + OFF_ENC);
                float cx = 0.f, cy = 0.f;
                #pragma unroll 4
                for (int i = 0; i < 16; ++i){
                    int s = sg*16 + i;
                    float2 v = upk2(er[s*256 + e2]);
                    float e = att_esl[s];
                    cx += e*v.x; cy += e*v.y;
                }
                cx += __shfl_xor(cx, 1); cy += __shfl_xor(cy, 1);
                cx += __shfl_xor(cx, 2); cy += __shfl_xor(cy, 2);
                if (sg == 0)
                    astu(&p.ctxpb[(size_t)(par*8 + ss)*8192 + b_att*256 + e2], pk2(cx, cy));
            }
        }
        __syncthreads();

        // ---- P1: gh + gix MFMA (blocks 0..191, 16 j each) ----
        if (is_gh){
            float* rg = (float*)(sm + OFF_REDG);
            if (tid < 1024) rg[tid] = 0.f;      // zeroes REDG+REDX (1024 f32)
            __syncthreads();
            {
                const int w = tid >> 6, bt = w & 1, kp = w >> 1;
                const int arow = lane & 15, g = lane >> 4;
                const float* hrow = hp + (size_t)(bt*16 + arow)*DEC_;
                f32x4 acch = {0.f, 0.f, 0.f, 0.f};
                #pragma unroll
                for (int c = 0; c < 4; ++c){
                    int kc = kp*4 + c;
                    bf16x8 a = packA(hrow + kc*32 + g*8);
                    bf16x8 b = *(const bf16x8*)(sm + OFF_WHH + ((kc*64 + lane) << 4));
                    acch = mfma16(a, b, acch);
                }
                const float* xrow = p.xall + ((size_t)t*B_ + bt*16 + arow)*PO_;
                bf16x8 ax = packA(xrow + kp*32 + g*8);
                bf16x8 bx = *(const bf16x8*)(sm + OFF_WIX + ((kp*64 + lane) << 4));
                f32x4 accx = {0.f, 0.f, 0.f, 0.f};
                accx = mfma16(ax, bx, accx);
                float* rx = (float*)(sm + OFF_REDX);
                #pragma unroll
                for (int r = 0; r < 4; ++r){
                    int ci = bt*256 + (g*4 + r)*16 + (lane & 15);
                    lds_fadd(&rg[ci], acch[r]);
                    lds_fadd(&rx[ci], accx[r]);
                }
            }
            __syncthreads();
            if (tid < 256){
                int rowb = tid >> 3, cp = tid & 7;
                const float* rg2 = (const float*)(sm + OFF_REDG);
                const float* rx2 = (const float*)(sm + OFF_REDX);
                int j0 = bid*16;
                ast2f(&p.ghb[(size_t)rowb*G3_ + j0 + cp*2], rg2[rowb*16 + cp*2], rg2[rowb*16 + cp*2 + 1]);
                ast2f(&p.gixb[(size_t)rowb*G3_ + j0 + cp*2], rx2[rowb*16 + cp*2], rx2[rowb*16 + cp*2 + 1]);
            }
        }
        gbar(p.cnt, (++epoch)*256u);

        // ================= P2 =================
        if (is_gate){
            float* rd_l = (float*)(sm + OFF_RDL);
            float* red6 = (float*)(sm + OFF_RED6);
            float* h_l  = (float*)(sm + OFF_HL);
            if (tid < 32){
                float d = 0.f;
                #pragma unroll
                for (int s2 = 0; s2 < 8; ++s2) d += p.denp[par*256 + s2*32 + tid];
                rd_l[tid] = frcp(d);
            }
            for (int i = tid; i < 1536; i += 1024) red6[i] = 0.f;
            __syncthreads();
            // stage normalized ctx (bf16) into fragment layout
            {
                unsigned* cf = (unsigned*)(sm + OFF_CTXF);
                for (int i = tid; i < 8192; i += 1024){
                    int l = (i >> 2) & 63, kc = (i >> 8) & 15, bt = (i >> 12) & 1;
                    int b = bt*16 + (l & 15);
                    int ep2 = kc*16 + (l >> 4)*4 + (i & 3);
                    float sx = 0.f, sy = 0.f;
                    #pragma unroll
                    for (int s2 = 0; s2 < 8; ++s2){
                        float2 v = upk2(p.ctxpb[(size_t)(par*8 + s2)*8192 + b*256 + ep2]);
                        sx += v.x; sy += v.y;
                    }
                    float r = rd_l[b];
                    cf[i] = pk2(sx*r, sy*r);
                }
            }
            __syncthreads();
            {
                const int w = tid >> 6;
                if (w < 12){
                    const int jt = w >> 2, bt = (w >> 1) & 1, kp = w & 1;
                    f32x4 acc = {0.f, 0.f, 0.f, 0.f};
                    #pragma unroll
                    for (int c = 0; c < 8; ++c){
                        int kc = kp*8 + c;
                        bf16x8 a = *(const bf16x8*)(sm + OFF_CTXF + ((bt*16 + kc)*64 + lane)*16);
                        bf16x8 b = *(const bf16x8*)(sm + OFF_WIC + (((jt*16 + kc)*64 + lane) << 4));
                        acc = mfma16(a, b, acc);
                    }
                    #pragma unroll
                    for (int r = 0; r < 4; ++r)
                        lds_fadd(&red6[(bt*3 + jt)*256 + ((lane >> 4)*4 + r)*16 + (lane & 15)], acc[r]);
                } else {
                    // aw writes (256 spare threads)
                    int i = tid - 768;
                    int flat = ds*256 + i;
                    int b2 = flat >> 9, s = flat & 511;
                    float d = 0.f;
                    #pragma unroll
                    for (int s2 = 0; s2 < 8; ++s2) d += p.denp[par*256 + s2*32 + b2];
                    astf(&p.out[AW_OFF + ((size_t)b2*T_ + t)*S_ + s], p.esb[b2*512 + s]*frcp(d));
                }
            }
            __syncthreads();
            // gates -> h(t+1)
            if (tid < 512){
                int b = tid >> 4, dl = tid & 15;
                int dg = ds*16 + dl;
                int bt = b >> 4, brow = b & 15;
                float gicr = red6[(bt*3 + 0)*256 + brow*16 + dl];
                float gicz = red6[(bt*3 + 1)*256 + brow*16 + dl];
                float gicn = red6[(bt*3 + 2)*256 + brow*16 + dl];
                const float* gx = p.gixb + (size_t)b*G3_;
                const float* gg = p.ghb + (size_t)b*G3_;
                float gir = gx[dg]        + gicr + p.bih[dg];
                float giz = gx[1024 + dg] + gicz + p.bih[1024 + dg];
                float gin = gx[2048 + dg] + gicn + p.bih[2048 + dg];
                float Ghr = gg[dg]        + p.bhh[dg];
                float Ghz = gg[1024 + dg] + p.bhh[1024 + dg];
                float Ghn = gg[2048 + dg] + p.bhh[2048 + dg];
                float rr = fsig(gir + Ghr);
                float zz = fsig(giz + Ghz);
                float nn = ftanh(gin + rr*Ghn);
                float hv = (1.f - zz)*nn + zz*hp[(size_t)b*DEC_ + dg];
                astf(&hn[(size_t)b*DEC_ + dg], hv);
                h_l[b*16 + dl] = hv;
            }
            __syncthreads();
            // dp partials for step t+1
            {
                int b = tid >> 5, ap = tid & 31;
                int a = ap*2;
                float s0 = 0.f, s1 = 0.f;
                #pragma unroll
                for (int dl = 0; dl < 16; ++dl){
                    float hd = h_l[b*16 + dl];
                    float2 w2 = *(const float2*)&p.awd[(size_t)(ds*16 + dl)*ATT_ + a];
                    s0 += hd*w2.x; s1 += hd*w2.y;
                }
                ast2f(&p.dpp[(size_t)(ds*32 + b)*128 + a], s0, s1);
            }
        } else if (is_mel && t >= 1){
            // mel/stop for step t-1: dout = [h(t), ctx(t-1)]
            float* ctx4 = (float*)(sm + OFF_CTX4);
            float* mred = (float*)(sm + OFF_MRED);
            float* rd4  = (float*)(sm + OFF_RD4);
            const int pm = (t - 1) & 1;
            const float* hm = p.hbuf + (size_t)(t % 3)*(B_*DEC_);
            if (tid < 4){
                float d = 0.f;
                #pragma unroll
                for (int s2 = 0; s2 < 8; ++s2) d += p.denp[pm*256 + s2*32 + mbg*4 + tid];
                rd4[tid] = frcp(d);
            }
            __syncthreads();
            for (int i = tid; i < 1024; i += 1024){
                int bb = i >> 8, ep2 = i & 255;
                float sx = 0.f, sy = 0.f;
                #pragma unroll
                for (int s2 = 0; s2 < 8; ++s2){
                    float2 v = upk2(p.ctxpb[(size_t)(pm*8 + s2)*8192 + (mbg*4 + bb)*256 + ep2]);
                    sx += v.x; sy += v.y;
                }
                float r = rd4[bb];
                ctx4[bb*512 + ep2*2] = sx*r; ctx4[bb*512 + ep2*2 + 1] = sy*r;
            }
            __syncthreads();
            {
                int ob = tid >> 8, oc = (tid >> 3) & 31, kg = tid & 7;
                const unsigned* owr = (const unsigned*)(p.ow_g + ((size_t)(mcg*32 + oc))*1536);
                const float* hb = hm + (size_t)(mbg*4 + ob)*DEC_;
                float a = 0.f;
                for (int kk = 0; kk < 96; ++kk){
                    int k = kg*192 + kk*2;
                    float2 w2 = upk2(owr[k >> 1]);
                    float d0 = (k < 1024) ? hb[k] : ctx4[ob*512 + k - 1024];
                    float d1 = (k + 1 < 1024) ? hb[k + 1] : ctx4[ob*512 + k + 1 - 1024];
                    a += d0*w2.x + d1*w2.y;
                }
                a += __shfl_xor(a, 1); a += __shfl_xor(a, 2); a += __shfl_xor(a, 4);
                if (kg == 0){
                    int c = mcg*32 + oc;
                    astf(&p.out[MEL_OFF + ((size_t)(mbg*4 + ob)*T_ + (t - 1))*M_ + c],
                         a + p.p_ob[c]);
                }
            }
            if (mcg == 0){
                int ob = tid >> 8, kt = tid & 255;
                const float* hb = hm + (size_t)(mbg*4 + ob)*DEC_;
                float s = 0.f;
                #pragma unroll
                for (int i = 0; i < 6; ++i){
                    int k = kt*6 + i;
                    float dv = (k < 1024) ? hb[k] : ctx4[ob*512 + k - 1024];
                    s += dv*p.sw[k];
                }
                #pragma unroll
                for (int m = 1; m <= 32; m <<= 1) s += __shfl_xor(s, m);
                if (lane == 0) mred[tid >> 6] = s;
                __syncthreads();
                if (tid < 4){
                    float tot = mred[tid*4] + mred[tid*4 + 1] + mred[tid*4 + 2] + mred[tid*4 + 3];
                    astf(&p.out[STOP_OFF + (mbg*4 + tid)*T_ + (t - 1)], tot + p.p_sb[0]);
                }
            }
        }
        gbar(p.cnt, (++epoch)*256u);
    }

    // tail: mel/stop for t-1 = 511 (uses h(512) just computed)
    if (is_mel){
        float* ctx4 = (float*)(sm + OFF_CTX4);
        float* mred = (float*)(sm + OFF_MRED);
        float* rd4  = (float*)(sm + OFF_RD4);
        const int tt = T_;
        const int pm = (tt - 1) & 1;
        const float* hm = p.hbuf + (size_t)(tt % 3)*(B_*DEC_);
        if (tid < 4){
            float d = 0.f;
            #pragma unroll
            for (int s2 = 0; s2 < 8; ++s2) d += p.denp[pm*256 + s2*32 + mbg*4 + tid];
            rd4[tid] = frcp(d);
        }
        __syncthreads();
        for (int i = tid; i < 1024; i += 1024){
            int bb = i >> 8, ep2 = i & 255;
            float sx = 0.f, sy = 0.f;
            #pragma unroll
            for (int s2 = 0; s2 < 8; ++s2){
                float2 v = upk2(p.ctxpb[(size_t)(pm*8 + s2)*8192 + (mbg*4 + bb)*256 + ep2]);
                sx += v.x; sy += v.y;
            }
            float r = rd4[bb];
            ctx4[bb*512 + ep2*2] = sx*r; ctx4[bb*512 + ep2*2 + 1] = sy*r;
        }
        __syncthreads();
        {
            int ob = tid >> 8, oc = (tid >> 3) & 31, kg = tid & 7;
            const unsigned* owr = (const unsigned*)(p.ow_g + ((size_t)(mcg*32 + oc))*1536);
            const float* hb = hm + (size_t)(mbg*4 + ob)*DEC_;
            float a = 0.f;
            for (int kk = 0; kk < 96; ++kk){
                int k = kg*192 + kk*2;
                float2 w2 = upk2(owr[k >> 1]);
                float d0 = (k < 1024) ? hb[k] : ctx4[ob*512 + k - 1024];
                float d1 = (k + 1 < 1024) ? hb[k + 1] : ctx4[ob*512 + k + 1 - 1024];
                a += d0*w2.x + d1*w2.y;
            }
            a += __shfl_xor(a, 1); a += __shfl_xor(a, 2); a += __shfl_xor(a, 4);
            if (kg == 0){
                int c = mcg*32 + oc;
                astf(&p.out[MEL_OFF + ((size_t)(mbg*4 + ob)*T_ + (tt - 1))*M_ + c], a + p.p_ob[c]);
            }
        }
        if (mcg == 0){
            int ob = tid >> 8, kt = tid & 255;
            const float* hb = hm + (size_t)(mbg*4 + ob)*DEC_;
            float s = 0.f;
            #pragma unroll
            for (int i = 0; i < 6; ++i){
                int k = kt*6 + i;
                float dv = (k < 1024) ? hb[k] : ctx4[ob*512 + k - 1024];
                s += dv*p.sw[k];
            }
            #pragma unroll
            for (int m = 1; m <= 32; m <<= 1) s += __shfl_xor(s, m);
            if (lane == 0) mred[tid >> 6] = s;
            __syncthreads();
            if (tid < 4){
                float tot = mred[tid*4] + mred[tid*4 + 1] + mred[tid*4 + 2] + mred[tid*4 + 3];
                astf(&p.out[STOP_OFF + (mbg*4 + tid)*T_ + (tt - 1)], tot + p.p_sb[0]);
            }
        }
    }
}

extern "C" void kernel_launch(void* const* d_in, const int* in_sizes, int n_in,
                              void* d_out, int out_size, void* d_ws, size_t ws_size,
                              hipStream_t stream){
    const float* enc = (const float*)d_in[0];
    const float* tm  = (const float*)d_in[1];
    const float* pw1 = (const float*)d_in[2];
    const float* pb1 = (const float*)d_in[3];
    const float* pw2 = (const float*)d_in[4];
    const float* pb2 = (const float*)d_in[5];
    const float* awe = (const float*)d_in[6];
    const float* abe = (const float*)d_in[7];
    const float* awd = (const float*)d_in[8];
    const float* abd = (const float*)d_in[9];
    const float* av  = (const float*)d_in[10];
    const float* avb = (const float*)d_in[11];
    const float* wih = (const float*)d_in[12];
    const float* whh = (const float*)d_in[13];
    const float* bih = (const float*)d_in[14];
    const float* bhh = (const float*)d_in[15];
    const float* oww = (const float*)d_in[16];
    const float* obb = (const float*)d_in[17];
    const float* sww = (const float*)d_in[18];
    const float* sbb = (const float*)d_in[19];
    float* out = (float*)d_out;
    float* ws  = (float*)d_ws;

    // workspace layout (float slots), ~52 MB
    float* xall = ws;                                      // 4,194,304
    unsigned short* enc_b = (unsigned short*)(ws + 4194304);   // 8,388,608 ush
    unsigned short* ep_b  = (unsigned short*)(ws + 8388608);   // 2,097,152 ush
    unsigned short* whh_f = (unsigned short*)(ws + 9437184);   // 3,145,728 ush
    unsigned short* wix_f = (unsigned short*)(ws + 11010048);  //   786,432 ush
    unsigned short* wic_f = (unsigned short*)(ws + 11403264);  // 1,572,864 ush
    unsigned short* ow_g  = (unsigned short*)(ws + 12189696);  //   196,608 ush
    float* hbuf  = ws + 12288000;   //  98,304
    float* ghb   = ws + 12386304;   //  98,304
    float* gixb  = ws + 12484608;   //  98,304
    float* dpp   = ws + 12582912;   // 262,144
    unsigned* ctxpb = (unsigned*)(ws + 12845056);  // 131,072
    float* denp  = ws + 12976128;   //     512
    float* esb   = ws + 12976640;   //  16,384
    unsigned* cnt = (unsigned*)(ws + 12993024);

    hipMemsetAsync(hbuf, 0, (size_t)98304*4, stream);
    hipMemsetAsync(dpp, 0, (size_t)262144*4, stream);
    hipMemsetAsync(cnt, 0, 64, stream);

    k_prep_w<<<55040, 256, 0, stream>>>(enc, whh, wih, oww,
                                        enc_b, whh_f, wix_f, wic_f, ow_g);
    k_encproj2<<<256, 256, 0, stream>>>(enc, awe, abe, ep_b);
    k_prenet<<<1024, 128, 0, stream>>>(tm, pw1, pb1, pw2, pb2, xall);

    hipFuncSetAttribute((const void*)k_persist,
                        hipFuncAttributeMaxDynamicSharedMemorySize, DYN_BYTES);

    KP kp;
    kp.xall = xall; kp.enc_b = enc_b; kp.ep_b = ep_b;
    kp.whh_f = whh_f; kp.wix_f = wix_f; kp.wic_f = wic_f; kp.ow_g = ow_g;
    kp.awd = awd; kp.sw = sww; kp.bd = abd; kp.av = av; kp.avb = avb;
    kp.bih = bih; kp.bhh = bhh; kp.p_ob = obb; kp.p_sb = sbb;
    kp.hbuf = hbuf; kp.ghb = ghb; kp.gixb = gixb; kp.dpp = dpp;
    kp.esb = esb; kp.denp = denp; kp.ctxpb = ctxpb; kp.cnt = cnt; kp.out = out;

    KP* kparg = &kp;
    void* args[] = { (void*)kparg };
    hipLaunchCooperativeKernel((void*)k_persist, dim3(256), dim3(1024),
                               args, DYN_BYTES, stream);
}

// Round 8
// 25511.613 us; speedup vs baseline: 5.4539x; 5.4539x over previous
//
#include <hip/hip_runtime.h>

// Problem constants
constexpr int B_   = 32;
constexpr int S_   = 512;
constexpr int T_   = 512;
constexpr int ENC_ = 512;
constexpr int ATT_ = 128;
constexpr int PO_  = 256;
constexpr int DEC_ = 1024;
constexpr int M_   = 128;

// Output offsets (floats)
constexpr int MEL_OFF  = 0;
constexpr int STOP_OFF = B_*T_*M_;            // 2,097,152
constexpr int AW_OFF   = STOP_OFF + B_*T_;    // 2,113,536

typedef __attribute__((ext_vector_type(8))) short bf16x8;
typedef __attribute__((ext_vector_type(4))) float f32x4;
typedef unsigned long long ull;

__device__ __forceinline__ float frcp(float x){ return __builtin_amdgcn_rcpf(x); }
__device__ __forceinline__ float ftanh(float x){ float e = __expf(2.f*x); return 1.f - 2.f*frcp(e + 1.f); }
__device__ __forceinline__ float fsig(float x){ return frcp(1.f + __expf(-x)); }

__device__ __forceinline__ float2 upk2(unsigned u){
    return make_float2(__builtin_bit_cast(float, u << 16),
                       __builtin_bit_cast(float, u & 0xffff0000u));
}
__device__ __forceinline__ unsigned short f2b(float f){
    unsigned u = __builtin_bit_cast(unsigned, f);
    return (unsigned short)((u + 0x7fffu + ((u >> 16) & 1u)) >> 16);
}
__device__ __forceinline__ float b2f(unsigned short u){
    return __builtin_bit_cast(float, (unsigned)u << 16);
}
__device__ __forceinline__ unsigned pk2(float a, float b){
    return (unsigned)f2b(a) | ((unsigned)f2b(b) << 16);
}

// ---- relaxed agent-scope (device-coherent) accessors (R3-proven) -------------
__device__ __forceinline__ float ald(const float* p){
    return __hip_atomic_load(p, __ATOMIC_RELAXED, __HIP_MEMORY_SCOPE_AGENT);
}
__device__ __forceinline__ ull ald64(const void* p){
    return __hip_atomic_load((const ull*)p, __ATOMIC_RELAXED, __HIP_MEMORY_SCOPE_AGENT);
}
__device__ __forceinline__ unsigned aldu(const unsigned* p){
    return __hip_atomic_load(p, __ATOMIC_RELAXED, __HIP_MEMORY_SCOPE_AGENT);
}
__device__ __forceinline__ void astf(float* p, float v){
    __hip_atomic_store(p, v, __ATOMIC_RELAXED, __HIP_MEMORY_SCOPE_AGENT);
}
union F2U { float2 f; ull u; };
__device__ __forceinline__ void ast2f(float* p, float a, float b){
    F2U x; x.f = make_float2(a, b);
    __hip_atomic_store((ull*)p, x.u, __ATOMIC_RELAXED, __HIP_MEMORY_SCOPE_AGENT);
}
__device__ __forceinline__ void astu(unsigned* p, unsigned v){
    __hip_atomic_store(p, v, __ATOMIC_RELAXED, __HIP_MEMORY_SCOPE_AGENT);
}

// ---- global barrier: NO cache fences (R3-proven). drain stores -> count ------
__device__ __forceinline__ void gbar(unsigned* cnt, unsigned target){
    asm volatile("s_waitcnt vmcnt(0) lgkmcnt(0)" ::: "memory");
    __syncthreads();
    if (threadIdx.x == 0){
        __hip_atomic_fetch_add(cnt, 1u, __ATOMIC_RELAXED, __HIP_MEMORY_SCOPE_AGENT);
        while (__hip_atomic_load(cnt, __ATOMIC_RELAXED, __HIP_MEMORY_SCOPE_AGENT) < target)
            __builtin_amdgcn_s_sleep(1);
    }
    __syncthreads();
}

__device__ __forceinline__ f32x4 mfma16(bf16x8 a, bf16x8 b, f32x4 c){
    return __builtin_amdgcn_mfma_f32_16x16x32_bf16(a, b, c, 0, 0, 0);
}

// ================= prep: staged layouts =================
// enc_b [32 b][2 half][256 s][512 e] bf16
// wgh/wgl [32 ds][2 kh][6 jc][16 kc][64 l][8 e]  hi/lo bf16 split of whh B-frags
// wgx   [32 ds][6 jc][8 kc][64 l][8 e]           (wih x-part B-frags)
// wgc   [32 ds][6 jc][16 kc][64 l][8 e]          (wih ctx-part B-frags)
// ow_b  [4 q][32 oc][1536 k] bf16
// wdT32 [128 a][1024 k] f32  (awd transposed)
__global__ __launch_bounds__(256) void k_prep_w(const float* __restrict__ enc,
        const float* __restrict__ whh, const float* __restrict__ wih,
        const float* __restrict__ awd, const float* __restrict__ oww,
        unsigned short* __restrict__ enc_b, unsigned short* __restrict__ wgh,
        unsigned short* __restrict__ wgl, unsigned short* __restrict__ wgx,
        unsigned short* __restrict__ wgc, unsigned short* __restrict__ ow_b,
        float* __restrict__ wdT32){
    long long idx = (long long)blockIdx.x*256 + threadIdx.x;
    if (idx < 8388608LL){
        int bh = (int)(idx >> 17); int r = (int)(idx & 131071);
        int s = r >> 9, e = r & 511;
        int b = bh >> 1, half = bh & 1;
        enc_b[idx] = f2b(enc[((size_t)b*S_ + half*256 + s)*ENC_ + e]);
    } else if (idx < 14680064LL){
        long long qq = idx - 8388608LL;
        int lo = (qq >= 3145728LL);
        long long q = lo ? qq - 3145728LL : qq;
        int ds = (int)(q / 98304); int r = (int)(q % 98304);
        int kh = r / 49152; int r2 = r % 49152;
        int jc = r2 / 8192; int r3 = r2 % 8192;
        int kc = r3 >> 9, l = (r3 >> 3) & 63, e = r3 & 7;
        int j = (jc >> 1)*1024 + ds*32 + (jc & 1)*16 + (l & 15);
        int k = kh*512 + kc*32 + ((l >> 4) << 3) + e;
        float w = whh[(size_t)j*DEC_ + k];
        if (!lo) wgh[q] = f2b(w);
        else     wgl[q] = f2b(w - b2f(f2b(w)));
    } else if (idx < 15466496LL){
        long long q = idx - 14680064LL;
        int ds = (int)(q / 24576); int r = (int)(q % 24576);
        int jc = r / 4096; int r3 = r % 4096;
        int kc = r3 >> 9, l = (r3 >> 3) & 63, e = r3 & 7;
        int j = (jc >> 1)*1024 + ds*32 + (jc & 1)*16 + (l & 15);
        int k = kc*32 + ((l >> 4) << 3) + e;
        wgx[q] = f2b(wih[(size_t)j*768 + k]);
    } else if (idx < 17039360LL){
        long long q = idx - 15466496LL;
        int ds = (int)(q / 49152); int r = (int)(q % 49152);
        int jc = r / 8192; int r3 = r % 8192;
        int kc = r3 >> 9, l = (r3 >> 3) & 63, e = r3 & 7;
        int j = (jc >> 1)*1024 + ds*32 + (jc & 1)*16 + (l & 15);
        int k = kc*32 + ((l >> 4) << 3) + e;
        wgc[q] = f2b(wih[(size_t)j*768 + 256 + k]);
    } else if (idx < 17235968LL){
        long long q = idx - 17039360LL;
        int cg = (int)(q / 49152); int r = (int)(q % 49152);
        int oc = r / 1536, k = r % 1536;
        ow_b[q] = f2b(oww[(size_t)k*M_ + cg*32 + oc]);
    } else if (idx < 17367040LL){
        long long q = idx - 17235968LL;
        int a = (int)(q >> 10), k = (int)(q & 1023);
        wdT32[q] = awd[(size_t)k*M_ + a];
    }
}

// ep_b[b][512 s][128 a] bf16 = enc @ att_we + be
__global__ __launch_bounds__(256) void k_encproj(const float* __restrict__ enc,
        const float* __restrict__ we, const float* __restrict__ be,
        unsigned short* __restrict__ ep_b){
    __shared__ float we_s[64*128];
    __shared__ float enc_s[64*64];
    int blk = blockIdx.x, tid = threadIdx.x;
    int b = blk >> 3, ss = blk & 7;
    int s = tid >> 2, ag = tid & 3;
    float acc[32];
    #pragma unroll
    for (int j = 0; j < 32; ++j) acc[j] = 0.f;
    for (int kc = 0; kc < 8; ++kc){
        __syncthreads();
        for (int i = tid; i < 8192; i += 256)
            we_s[i] = we[(size_t)(kc*64 + (i >> 7))*ATT_ + (i & 127)];
        for (int i = tid; i < 4096; i += 256)
            enc_s[i] = enc[((size_t)b*S_ + ss*64 + (i >> 6))*ENC_ + kc*64 + (i & 63)];
        __syncthreads();
        for (int kk = 0; kk < 64; ++kk){
            float ev = enc_s[s*64 + kk];
            const float* wr = &we_s[(kk << 7) + (ag << 5)];
            #pragma unroll
            for (int j = 0; j < 32; ++j) acc[j] += ev*wr[j];
        }
    }
    #pragma unroll
    for (int j = 0; j < 32; ++j){
        int a = (ag << 5) + j;
        ep_b[((size_t)b*512 + ss*64 + s)*ATT_ + a] = f2b(acc[j] + be[a]);
    }
}

// PreNet (f32 math, bf16 output)
__global__ __launch_bounds__(128) void k_prenet(const float* __restrict__ tm,
        const float* __restrict__ w1, const float* __restrict__ b1,
        const float* __restrict__ w2, const float* __restrict__ b2,
        unsigned short* __restrict__ xall){
    __shared__ float mel_l[128*20];
    __shared__ float h1_l[256*20];
    int row0 = blockIdx.x << 4;
    int t = row0 >> 5, b0 = row0 & 31;
    int tid = threadIdx.x;
    for (int p = 0; p < 16; p++){
        int idx = tid + (p << 7);
        int k = idx & 127, r = idx >> 7;
        float v = 0.f;
        if (t > 0) v = tm[((size_t)(b0 + r)*T_ + (t - 1))*M_ + k];
        mel_l[k*20 + r] = v;
    }
    __syncthreads();
    float acc1[16], acc2[16];
    #pragma unroll
    for (int i = 0; i < 16; i++){ acc1[i] = 0.f; acc2[i] = 0.f; }
    for (int k = 0; k < M_; k++){
        float wa = w1[k*256 + tid];
        float wb = w1[k*256 + tid + 128];
        float mv[16];
        *(float4*)&mv[0]  = *(const float4*)&mel_l[k*20 + 0];
        *(float4*)&mv[4]  = *(const float4*)&mel_l[k*20 + 4];
        *(float4*)&mv[8]  = *(const float4*)&mel_l[k*20 + 8];
        *(float4*)&mv[12] = *(const float4*)&mel_l[k*20 + 12];
        #pragma unroll
        for (int r = 0; r < 16; r++){ acc1[r] += mv[r]*wa; acc2[r] += mv[r]*wb; }
    }
    float bb1a = b1[tid], bb1b = b1[tid + 128];
    #pragma unroll
    for (int r = 0; r < 16; r++){
        h1_l[tid*20 + r]         = fmaxf(acc1[r] + bb1a, 0.f);
        h1_l[(tid + 128)*20 + r] = fmaxf(acc2[r] + bb1b, 0.f);
    }
    __syncthreads();
    #pragma unroll
    for (int i = 0; i < 16; i++){ acc1[i] = 0.f; acc2[i] = 0.f; }
    for (int k = 0; k < 256; k++){
        float wa = w2[k*256 + tid];
        float wb = w2[k*256 + tid + 128];
        float mv[16];
        *(float4*)&mv[0]  = *(const float4*)&h1_l[k*20 + 0];
        *(float4*)&mv[4]  = *(const float4*)&h1_l[k*20 + 4];
        *(float4*)&mv[8]  = *(const float4*)&h1_l[k*20 + 8];
        *(float4*)&mv[12] = *(const float4*)&h1_l[k*20 + 12];
        #pragma unroll
        for (int r = 0; r < 16; r++){ acc1[r] += mv[r]*wa; acc2[r] += mv[r]*wb; }
    }
    float bb2a = b2[tid], bb2b = b2[tid + 128];
    #pragma unroll
    for (int r = 0; r < 16; r++){
        xall[((size_t)row0 + r)*PO_ + tid]       = f2b(fmaxf(acc1[r] + bb2a, 0.f));
        xall[((size_t)row0 + r)*PO_ + tid + 128] = f2b(fmaxf(acc2[r] + bb2b, 0.f));
    }
}

// ================= persistent lockstep decoder =================
#define DYN_BYTES 115712

struct KP {
    const unsigned short* xall_b; const unsigned short* enc_b; const unsigned short* ep_b;
    const unsigned short* wgh; const unsigned short* wgl; const unsigned short* wgx;
    const unsigned short* wgc; const unsigned short* ow_b;
    const float* wdT32; const float* sw; const float* bd; const float* av; const float* avb;
    const float* bih; const float* bhh; const float* p_ob; const float* p_sb;
    float* h_f32; unsigned short* h_fhi; unsigned short* h_flo;
    unsigned short* ctx_b; float* den; float* es_b; float* pgh; float* pgx;
    unsigned* cnt; float* out;
};

__global__ __launch_bounds__(1024) void k_persist(KP p){
    extern __shared__ char sm[];
    const int bid = blockIdx.x, tid = threadIdx.x;
    const int lane = tid & 63;
    unsigned epn = 0;
    unsigned* cnt = p.cnt;

    if (bid < 64){
        // ================= GATE (ds = bid>>1, kh = bid&1) =================
        const int ds = bid >> 1, kh = bid & 1;
        unsigned short* hf_hi = (unsigned short*)sm;           // ph1 32KB
        unsigned short* hf_lo = (unsigned short*)(sm + 32768); // ph1 32KB
        char* cf = sm;                                         // ph2 ctx frags 32KB
        float* gis   = (float*)(sm + 65536);                   // [32][100] 12800B
        float* pg_s  = (float*)(sm + 78336);                   // [3][3072] 36864B
        float* rden_l= (float*)(sm + 115200);                  // 32 f
        float h_reg = 0.f;
        const int pb = tid >> 5, pd = tid & 31;                // pointwise (b, dloc)

        for (int t = 0; t <= T_; ++t){
            // ---------- phase 1: gh (hi/lo split) + gix MFMA ----------
            if (t < T_){
                const ull* shi = (const ull*)p.h_fhi;
                const ull* slo = (const ull*)p.h_flo;
                for (int i = tid; i < 4096; i += 1024){
                    int u = i & 1, l = (i >> 1) & 63, kc = (i >> 7) & 15, bt = i >> 11;
                    size_t si = ((((size_t)bt*32 + kh*16 + kc)*64 + l) << 1) + u;
                    ((ull*)hf_hi)[i] = ald64(&shi[si]);
                    ((ull*)hf_lo)[i] = ald64(&slo[si]);
                }
                __syncthreads();
                int w = tid >> 6;
                if (w < 12){
                    int jc = w >> 1, bt = w & 1;
                    int r4 = lane >> 4, c16 = lane & 15;
                    size_t wo = ((size_t)((ds*2 + kh)*6 + jc)*16)*64 + lane;
                    const bf16x8* Bh = (const bf16x8*)p.wgh + wo;
                    const bf16x8* Bl = (const bf16x8*)p.wgl + wo;
                    f32x4 acc = {0.f,0.f,0.f,0.f};
                    #pragma unroll
                    for (int kc = 0; kc < 16; ++kc){
                        bf16x8 ah = *(const bf16x8*)(hf_hi + (((bt*16 + kc)*64 + lane) << 3));
                        bf16x8 al = *(const bf16x8*)(hf_lo + (((bt*16 + kc)*64 + lane) << 3));
                        acc = mfma16(ah, Bh[kc*64], acc);
                        acc = mfma16(al, Bh[kc*64], acc);
                        acc = mfma16(ah, Bl[kc*64], acc);
                    }
                    #pragma unroll
                    for (int r = 0; r < 4; ++r){
                        float v1 = __shfl_xor(acc[r], 1);
                        if (!(lane & 1)){
                            int b = bt*16 + r4*4 + r;
                            ast2f(&p.pgh[(((size_t)ds*2 + kh)*32 + b)*96 + jc*16 + c16],
                                  acc[r], v1);
                        }
                    }
                    if (kh){
                        const bf16x8* Xp = (const bf16x8*)p.wgx +
                            ((size_t)(ds*6 + jc)*8)*64 + lane;
                        f32x4 ax = {0.f,0.f,0.f,0.f};
                        #pragma unroll
                        for (int kc = 0; kc < 8; ++kc){
                            bf16x8 a = *(const bf16x8*)(p.xall_b +
                                ((size_t)t*32 + bt*16 + c16)*256 + kc*32 + r4*8);
                            ax = mfma16(a, Xp[kc*64], ax);
                        }
                        #pragma unroll
                        for (int r = 0; r < 4; ++r){
                            float v1 = __shfl_xor(ax[r], 1);
                            if (!(lane & 1)){
                                int b = bt*16 + r4*4 + r;
                                ast2f(&p.pgx[((size_t)ds*32 + b)*96 + jc*16 + c16],
                                      ax[r], v1);
                            }
                        }
                    }
                }
            }
            gbar(cnt, (++epn) << 8);
            // ---------- phase 2: gic + gates (kh==0) ----------
            if (t < T_ && kh == 0){
                const int slot = t & 1;
                if (tid < 32)
                    rden_l[tid] = frcp(ald(&p.den[slot*64 + tid]) +
                                       ald(&p.den[slot*64 + 32 + tid]));
                for (int i = tid; i < 4608; i += 1024){
                    int which = i / 1536, r = i - which*1536;
                    const ull* src = (which < 2) ?
                        ((const ull*)p.pgh + ((size_t)ds*2 + which)*1536 + r) :
                        ((const ull*)p.pgx + (size_t)ds*1536 + r);
                    ((ull*)pg_s)[i] = ald64(src);
                }
                __syncthreads();
                for (int i = tid; i < 2048; i += 1024){
                    int l = i & 63, kc = (i >> 6) & 15, bt = i >> 10;
                    int b = bt*16 + (l & 15);
                    int e0 = kc*32 + ((l >> 4) << 3);
                    const ull* c0 = (const ull*)p.ctx_b + (((size_t)slot*2 + 0)*32 + b)*128 + (e0 >> 2);
                    const ull* c1 = (const ull*)p.ctx_b + (((size_t)slot*2 + 1)*32 + b)*128 + (e0 >> 2);
                    ull u00 = ald64(c0), u01 = ald64(c0 + 1);
                    ull u10 = ald64(c1), u11 = ald64(c1 + 1);
                    float rd = rden_l[b];
                    uint2 x0 = __builtin_bit_cast(uint2, u00);
                    uint2 x1 = __builtin_bit_cast(uint2, u01);
                    uint2 y0 = __builtin_bit_cast(uint2, u10);
                    uint2 y1 = __builtin_bit_cast(uint2, u11);
                    float2 a0 = upk2(x0.x), b0 = upk2(y0.x);
                    float2 a1 = upk2(x0.y), b1 = upk2(y0.y);
                    float2 a2 = upk2(x1.x), b2 = upk2(y1.x);
                    float2 a3 = upk2(x1.y), b3 = upk2(y1.y);
                    unsigned w0 = pk2((a0.x + b0.x)*rd, (a0.y + b0.y)*rd);
                    unsigned w1 = pk2((a1.x + b1.x)*rd, (a1.y + b1.y)*rd);
                    unsigned w2 = pk2((a2.x + b2.x)*rd, (a2.y + b2.y)*rd);
                    unsigned w3 = pk2((a3.x + b3.x)*rd, (a3.y + b3.y)*rd);
                    *(uint4*)(cf + (size_t)i*16) = make_uint4(w0, w1, w2, w3);
                }
                __syncthreads();
                int w = tid >> 6;
                if (w < 12){
                    int jc = w >> 1, bt = w & 1;
                    int r4 = lane >> 4, c16 = lane & 15;
                    const bf16x8* Cp = (const bf16x8*)p.wgc +
                        ((size_t)(ds*6 + jc)*16)*64 + lane;
                    f32x4 acc = {0.f,0.f,0.f,0.f};
                    #pragma unroll
                    for (int kc = 0; kc < 16; ++kc){
                        bf16x8 a = *(const bf16x8*)(cf + (((bt*16 + kc)*64 + lane) << 4));
                        acc = mfma16(a, Cp[kc*64], acc);
                    }
                    #pragma unroll
                    for (int r = 0; r < 4; ++r)
                        gis[(bt*16 + r4*4 + r)*100 + jc*16 + c16] = acc[r];
                }
                __syncthreads();
                {
                    int b = pb, dl = pd;
                    int jgr = ds*32 + dl;
                    float gi_r = gis[b*100 + dl]      + pg_s[6144 + b*96 + dl]      + p.bih[jgr];
                    float gi_z = gis[b*100 + 32 + dl] + pg_s[6144 + b*96 + 32 + dl] + p.bih[1024 + jgr];
                    float gi_n = gis[b*100 + 64 + dl] + pg_s[6144 + b*96 + 64 + dl] + p.bih[2048 + jgr];
                    float gh_r = pg_s[b*96 + dl]      + pg_s[3072 + b*96 + dl]      + p.bhh[jgr];
                    float gh_z = pg_s[b*96 + 32 + dl] + pg_s[3072 + b*96 + 32 + dl] + p.bhh[1024 + jgr];
                    float gh_n = pg_s[b*96 + 64 + dl] + pg_s[3072 + b*96 + 64 + dl] + p.bhh[2048 + jgr];
                    float rr = fsig(gi_r + gh_r);
                    float zz = fsig(gi_z + gh_z);
                    float nn = ftanh(gi_n + rr*gh_n);
                    float hv = (1.f - zz)*nn + zz*h_reg;
                    h_reg = hv;
                    float hv1 = __shfl_xor(hv, 1);
                    if (!(dl & 1)){
                        int d = ds*32 + dl;
                        ast2f(&p.h_f32[(size_t)b*1024 + d], hv, hv1);
                        unsigned hipk = pk2(hv, hv1);
                        float lo0 = hv  - b2f(f2b(hv));
                        float lo1 = hv1 - b2f(f2b(hv1));
                        unsigned lopk = pk2(lo0, lo1);
                        int l2 = ((dl >> 3) << 4) + (b & 15);
                        size_t fo = ((((size_t)(b >> 4)*32 + ds)*64 + l2) << 2) + ((dl & 7) >> 1);
                        astu((unsigned*)p.h_fhi + fo, hipk);
                        astu((unsigned*)p.h_flo + fo, lopk);
                    }
                }
            }
            gbar(cnt, (++epn) << 8);
        }
    } else if (bid < 128){
        // ================= ATT (b, half) =================
        const int aa = bid - 64, b = aa >> 1, half = aa & 1;
        unsigned short* ep_l = (unsigned short*)sm;          // 65536
        float* red  = (float*)(sm + 65536);                  // [16][522] 33408
        float* sred = (float*)(sm + 98944);                  // 4096
        float* dpl  = (float*)(sm + 103040);                 // 512
        float* avl  = (float*)(sm + 103552);                 // 512
        float* esl  = (float*)(sm + 104064);                 // 1024
        float* h_lf = (float*)(sm + 105088);                 // 4096 (f32 h row)
        {
            // FIX(R8): pointer arithmetic in USH units first, then cast.
            // (R6/R7 did (ull*)base + rows*16 — half the correct stride.)
            const ull* src = (const ull*)(p.ep_b + ((size_t)b*512 + half*256)*128);
            for (int i = tid; i < 8192; i += 1024) ((ull*)ep_l)[i] = src[i];
            if (tid < 128) avl[tid] = p.av[tid];
        }
        __syncthreads();
        for (int t = 0; t <= T_; ++t){
            if (t < T_){
                const int slot = t & 1;
                if (tid < 512)
                    ((ull*)h_lf)[tid] = ald64((const ull*)p.h_f32 + (size_t)b*512 + tid);
                __syncthreads();
                {   // dproj partials (pure f32)
                    int a = tid & 127, kg = tid >> 7;
                    const float* hw = h_lf + kg*128;
                    const float* wr = p.wdT32 + (size_t)a*1024 + kg*128;
                    float s = 0.f;
                    #pragma unroll 8
                    for (int i = 0; i < 128; i += 4){
                        float4 h4 = *(const float4*)(hw + i);
                        float4 w4 = *(const float4*)(wr + i);
                        s += h4.x*w4.x + h4.y*w4.y + h4.z*w4.z + h4.w*w4.w;
                    }
                    red[kg*128 + a] = s;
                }
                __syncthreads();
                if (tid < 128){
                    float s = p.bd[tid];
                    #pragma unroll
                    for (int g = 0; g < 8; ++g) s += red[g*128 + tid];
                    dpl[tid] = s;
                }
                __syncthreads();
                {
                    int s = tid >> 2, ao = tid & 3;
                    const unsigned* er = (const unsigned*)ep_l + s*64 + ao*16;
                    float sc = 0.f;
                    #pragma unroll
                    for (int i = 0; i < 16; ++i){
                        float2 e2 = upk2(er[i]);
                        int a0 = ao*32 + i*2;
                        sc += ftanh(e2.x + dpl[a0])*avl[a0]
                            + ftanh(e2.y + dpl[a0+1])*avl[a0+1];
                    }
                    sred[tid] = sc;
                }
                __syncthreads();
                if (tid < 256){
                    float sc = sred[tid*4] + sred[tid*4+1] + sred[tid*4+2] + sred[tid*4+3] + p.avb[0];
                    float ev = __expf(sc);
                    esl[tid] = ev;
                    astf(&p.es_b[(size_t)slot*16384 + b*512 + half*256 + tid], ev);
                }
                __syncthreads();
                if (tid < 64){
                    float d = esl[tid*4] + esl[tid*4+1] + esl[tid*4+2] + esl[tid*4+3];
                    #pragma unroll
                    for (int m = 1; m <= 32; m <<= 1) d += __shfl_xor(d, m);
                    if (tid == 0) astf(&p.den[slot*64 + half*32 + b], d);
                }
                {
                    int eo = tid >> 4, sg = tid & 15;
                    int e8 = eo*8;
                    const unsigned short* eb = p.enc_b + ((size_t)b*2 + half)*131072;
                    float a0=0,a1=0,a2=0,a3=0,a4=0,a5=0,a6=0,a7=0;
                    #pragma unroll 4
                    for (int i = 0; i < 16; ++i){
                        int s = sg*16 + i;
                        float ev = esl[s];
                        uint4 u = *(const uint4*)(eb + (size_t)s*512 + e8);
                        float2 v0=upk2(u.x), v1=upk2(u.y), v2=upk2(u.z), v3=upk2(u.w);
                        a0+=ev*v0.x; a1+=ev*v0.y; a2+=ev*v1.x; a3+=ev*v1.y;
                        a4+=ev*v2.x; a5+=ev*v2.y; a6+=ev*v3.x; a7+=ev*v3.y;
                    }
                    float* rr = &red[sg*522 + e8];
                    rr[0]=a0; rr[1]=a1; rr[2]=a2; rr[3]=a3;
                    rr[4]=a4; rr[5]=a5; rr[6]=a6; rr[7]=a7;
                }
                __syncthreads();
                if (tid < 512){
                    float c = 0.f;
                    #pragma unroll
                    for (int sg = 0; sg < 16; ++sg) c += red[sg*522 + tid];
                    float c1 = __shfl_xor(c, 1);
                    if (!(tid & 1))
                        astu((unsigned*)p.ctx_b + (((size_t)slot*2 + half)*32 + b)*256 + (tid >> 1),
                             pk2(c, c1));
                }
            }
            gbar(cnt, (++epn) << 8);
            gbar(cnt, (++epn) << 8);
        }
    } else {
        // ================= MEL (b, q) =================
        const int m = bid - 128, b = m >> 2, q = m & 3;
        unsigned short* ow_l = (unsigned short*)sm;   // [32 oc][1538] = 98432B
        float* dout = (float*)(sm + 98432);           // 1536 f
        float* redm = (float*)(sm + 104576);          // [32][33]
        float* rdm  = (float*)(sm + 108800);
        float* stpr = (float*)(sm + 108816);          // 8 f
        {
            const ull* src = (const ull*)p.ow_b + (size_t)q*12288;
            for (int i = tid; i < 12288; i += 1024){
                int oc = i / 384, kq = i - oc*384;
                uint2 u = __builtin_bit_cast(uint2, src[i]);
                unsigned* d = (unsigned*)ow_l + (size_t)oc*769 + kq*2;
                d[0] = u.x; d[1] = u.y;
            }
        }
        __syncthreads();
        for (int t = 0; t <= T_; ++t){
            if (t >= 1){
                const int slot = (t - 1) & 1;
                if (tid < 512){
                    ull u = ald64((const ull*)p.h_f32 + (size_t)b*512 + tid);
                    *(float2*)&dout[tid*2] = __builtin_bit_cast(float2, u);
                } else if (tid < 768){
                    int i = tid - 512;
                    unsigned u0 = aldu((const unsigned*)p.ctx_b + (((size_t)slot*2 + 0)*32 + b)*256 + i);
                    unsigned u1 = aldu((const unsigned*)p.ctx_b + (((size_t)slot*2 + 1)*32 + b)*256 + i);
                    float2 f0 = upk2(u0), f1 = upk2(u1);
                    *(float2*)&dout[1024 + i*2] = make_float2(f0.x + f1.x, f0.y + f1.y);
                } else if (tid == 1023){
                    rdm[0] = frcp(ald(&p.den[slot*64 + b]) + ald(&p.den[slot*64 + 32 + b]));
                }
                __syncthreads();
                if (tid < 512) dout[1024 + tid] *= rdm[0];
                __syncthreads();
                {
                    int kg = tid >> 5, oc = tid & 31;
                    const unsigned* wr = (const unsigned*)ow_l + (size_t)oc*769 + kg*24;
                    const float* dr = dout + kg*48;
                    float a = 0.f;
                    #pragma unroll 6
                    for (int i = 0; i < 24; ++i){
                        float2 w2 = upk2(wr[i]);
                        a += dr[i*2]*w2.x + dr[i*2+1]*w2.y;
                    }
                    redm[kg*33 + oc] = a;
                }
                if (q == 0 && tid < 512){
                    int k3 = tid*3;
                    float s = dout[k3]*p.sw[k3] + dout[k3+1]*p.sw[k3+1] + dout[k3+2]*p.sw[k3+2];
                    #pragma unroll
                    for (int mm = 1; mm <= 32; mm <<= 1) s += __shfl_xor(s, mm);
                    if ((tid & 63) == 0) stpr[tid >> 6] = s;
                    float ev = ald(&p.es_b[(size_t)slot*16384 + b*512 + tid]);
                    p.out[AW_OFF + ((size_t)b*T_ + (t-1))*S_ + tid] = ev*rdm[0];
                }
                __syncthreads();
                if (tid < 32){
                    float a = 0.f;
                    #pragma unroll
                    for (int kg = 0; kg < 32; ++kg) a += redm[kg*33 + tid];
                    int c = q*32 + tid;
                    p.out[MEL_OFF + ((size_t)b*T_ + (t-1))*M_ + c] = a + p.p_ob[c];
                } else if (tid == 32 && q == 0){
                    float tot = 0.f;
                    #pragma unroll
                    for (int w2 = 0; w2 < 8; ++w2) tot += stpr[w2];
                    p.out[STOP_OFF + (size_t)b*T_ + (t-1)] = tot + p.p_sb[0];
                }
            }
            gbar(cnt, (++epn) << 8);
            gbar(cnt, (++epn) << 8);
        }
    }
}

extern "C" void kernel_launch(void* const* d_in, const int* in_sizes, int n_in,
                              void* d_out, int out_size, void* d_ws, size_t ws_size,
                              hipStream_t stream){
    const float* enc = (const float*)d_in[0];
    const float* tm  = (const float*)d_in[1];
    const float* pw1 = (const float*)d_in[2];
    const float* pb1 = (const float*)d_in[3];
    const float* pw2 = (const float*)d_in[4];
    const float* pb2 = (const float*)d_in[5];
    const float* awe = (const float*)d_in[6];
    const float* abe = (const float*)d_in[7];
    const float* awd = (const float*)d_in[8];
    const float* abd = (const float*)d_in[9];
    const float* av  = (const float*)d_in[10];
    const float* avb = (const float*)d_in[11];
    const float* wih = (const float*)d_in[12];
    const float* whh = (const float*)d_in[13];
    const float* bih = (const float*)d_in[14];
    const float* bhh = (const float*)d_in[15];
    const float* oww = (const float*)d_in[16];
    const float* obb = (const float*)d_in[17];
    const float* sww = (const float*)d_in[18];
    const float* sbb = (const float*)d_in[19];
    float* out = (float*)d_out;
    float* ws  = (float*)d_ws;

    // workspace (float offsets), total ~49.3 MB
    unsigned short* xall_b = (unsigned short*)ws;                //  4,194,304 ush
    unsigned short* enc_b  = (unsigned short*)(ws + 2097152);    //  8,388,608 ush
    unsigned short* ep_b   = (unsigned short*)(ws + 6291456);    //  2,097,152 ush
    unsigned short* wgh    = (unsigned short*)(ws + 7340032);    //  3,145,728 ush
    unsigned short* wgl    = (unsigned short*)(ws + 8912896);    //  3,145,728 ush
    unsigned short* wgx    = (unsigned short*)(ws + 10485760);   //    786,432 ush
    unsigned short* wgc    = (unsigned short*)(ws + 10878976);   //  1,572,864 ush
    float* wdT32 = ws + 11665408;                                //    131,072 f
    unsigned short* ow_b   = (unsigned short*)(ws + 11796480);   //    196,608 ush
    float* h_f32 = ws + 11894784;                                //     32,768 f
    unsigned short* h_fhi  = (unsigned short*)(ws + 11927552);   //     32,768 ush
    unsigned short* h_flo  = (unsigned short*)(ws + 11943936);   //     32,768 ush
    unsigned short* ctx_b  = (unsigned short*)(ws + 11960320);   //     65,536 ush
    float* den  = ws + 11993088;                                 //        128 f
    float* es_b = ws + 11993216;                                 //     32,768 f
    float* pgh  = ws + 12025984;                                 //    196,608 f
    float* pgx  = ws + 12222592;                                 //     98,304 f
    unsigned* cnt = (unsigned*)(ws + 12320896);

    hipMemsetAsync(h_f32, 0, 32768*4, stream);
    hipMemsetAsync(h_fhi, 0, 32768*2, stream);
    hipMemsetAsync(h_flo, 0, 32768*2, stream);
    hipMemsetAsync(cnt, 0, 64, stream);

    k_prep_w<<<67840, 256, 0, stream>>>(enc, whh, wih, awd, oww,
                                        enc_b, wgh, wgl, wgx, wgc, ow_b, wdT32);
    k_encproj<<<256, 256, 0, stream>>>(enc, awe, abe, ep_b);
    k_prenet<<<1024, 128, 0, stream>>>(tm, pw1, pb1, pw2, pb2, xall_b);

    hipFuncSetAttribute((const void*)k_persist,
                        hipFuncAttributeMaxDynamicSharedMemorySize, DYN_BYTES);

    KP kp;
    kp.xall_b = xall_b; kp.enc_b = enc_b; kp.ep_b = ep_b;
    kp.wgh = wgh; kp.wgl = wgl; kp.wgx = wgx; kp.wgc = wgc; kp.ow_b = ow_b;
    kp.wdT32 = wdT32; kp.sw = sww; kp.bd = abd; kp.av = av; kp.avb = avb;
    kp.bih = bih; kp.bhh = bhh; kp.p_ob = obb; kp.p_sb = sbb;
    kp.h_f32 = h_f32; kp.h_fhi = h_fhi; kp.h_flo = h_flo;
    kp.ctx_b = ctx_b; kp.den = den; kp.es_b = es_b; kp.pgh = pgh; kp.pgx = pgx;
    kp.cnt = cnt; kp.out = out;

    KP* kparg = &kp;
    void* args[] = { (void*)kparg };
    hipLaunchCooperativeKernel((void*)k_persist, dim3(256), dim3(1024),
                               args, DYN_BYTES, stream);
}

// Round 9
// 22136.205 us; speedup vs baseline: 6.2855x; 1.1525x over previous
//
#include <hip/hip_runtime.h>

// Problem constants
constexpr int B_   = 32;
constexpr int S_   = 512;
constexpr int T_   = 512;
constexpr int ENC_ = 512;
constexpr int ATT_ = 128;
constexpr int PO_  = 256;
constexpr int DEC_ = 1024;
constexpr int M_   = 128;

// Output offsets (floats)
constexpr int MEL_OFF  = 0;
constexpr int STOP_OFF = B_*T_*M_;            // 2,097,152
constexpr int AW_OFF   = STOP_OFF + B_*T_;    // 2,113,536

typedef __attribute__((ext_vector_type(8))) short bf16x8;
typedef __attribute__((ext_vector_type(4))) float f32x4;
typedef unsigned long long ull;

__device__ __forceinline__ float frcp(float x){ return __builtin_amdgcn_rcpf(x); }
__device__ __forceinline__ float ftanh(float x){ float e = __expf(2.f*x); return 1.f - 2.f*frcp(e + 1.f); }
__device__ __forceinline__ float fsig(float x){ return frcp(1.f + __expf(-x)); }

__device__ __forceinline__ float2 upk2(unsigned u){
    return make_float2(__builtin_bit_cast(float, u << 16),
                       __builtin_bit_cast(float, u & 0xffff0000u));
}
__device__ __forceinline__ unsigned short f2b(float f){
    unsigned u = __builtin_bit_cast(unsigned, f);
    return (unsigned short)((u + 0x7fffu + ((u >> 16) & 1u)) >> 16);
}
__device__ __forceinline__ unsigned pk2(float a, float b){
    return (unsigned)f2b(a) | ((unsigned)f2b(b) << 16);
}

// ---- relaxed agent-scope (device-coherent) accessors (R3/R8-proven) ----------
__device__ __forceinline__ float ald(const float* p){
    return __hip_atomic_load(p, __ATOMIC_RELAXED, __HIP_MEMORY_SCOPE_AGENT);
}
__device__ __forceinline__ ull ald64(const void* p){
    return __hip_atomic_load((const ull*)p, __ATOMIC_RELAXED, __HIP_MEMORY_SCOPE_AGENT);
}
__device__ __forceinline__ unsigned aldu(const unsigned* p){
    return __hip_atomic_load(p, __ATOMIC_RELAXED, __HIP_MEMORY_SCOPE_AGENT);
}
__device__ __forceinline__ void astf(float* p, float v){
    __hip_atomic_store(p, v, __ATOMIC_RELAXED, __HIP_MEMORY_SCOPE_AGENT);
}
union F2U { float2 f; ull u; };
__device__ __forceinline__ void ast2f(float* p, float a, float b){
    F2U x; x.f = make_float2(a, b);
    __hip_atomic_store((ull*)p, x.u, __ATOMIC_RELAXED, __HIP_MEMORY_SCOPE_AGENT);
}
__device__ __forceinline__ void astu(unsigned* p, unsigned v){
    __hip_atomic_store(p, v, __ATOMIC_RELAXED, __HIP_MEMORY_SCOPE_AGENT);
}

// ---- global barrier: NO cache fences (R3/R8-proven) --------------------------
__device__ __forceinline__ void gbar(unsigned* cnt, unsigned target){
    asm volatile("s_waitcnt vmcnt(0) lgkmcnt(0)" ::: "memory");
    __syncthreads();
    if (threadIdx.x == 0){
        __hip_atomic_fetch_add(cnt, 1u, __ATOMIC_RELAXED, __HIP_MEMORY_SCOPE_AGENT);
        while (__hip_atomic_load(cnt, __ATOMIC_RELAXED, __HIP_MEMORY_SCOPE_AGENT) < target)
            __builtin_amdgcn_s_sleep(1);
    }
    __syncthreads();
}

__device__ __forceinline__ f32x4 mfma16(bf16x8 a, bf16x8 b, f32x4 c){
    return __builtin_amdgcn_mfma_f32_16x16x32_bf16(a, b, c, 0, 0, 0);
}

// ================= prep: staged layouts =================
// enc_b [32 b][2 half][256 s][512 e] bf16
// wgh   [32 ds][2 kh][6 jc][16 kc][64 l][8 e]  (whh B-frags, single bf16)
// wgx   [32 ds][6 jc][8 kc][64 l][8 e]         (wih x-part B-frags)
// wgc   [32 ds][6 jc][16 kc][64 l][8 e]        (wih ctx-part B-frags)
// ow_b  [4 q][32 oc][1536 k] bf16
__global__ __launch_bounds__(256) void k_prep_w(const float* __restrict__ enc,
        const float* __restrict__ whh, const float* __restrict__ wih,
        const float* __restrict__ oww,
        unsigned short* __restrict__ enc_b, unsigned short* __restrict__ wgh,
        unsigned short* __restrict__ wgx, unsigned short* __restrict__ wgc,
        unsigned short* __restrict__ ow_b){
    long long idx = (long long)blockIdx.x*256 + threadIdx.x;
    if (idx < 8388608LL){
        int bh = (int)(idx >> 17); int r = (int)(idx & 131071);
        int s = r >> 9, e = r & 511;
        int b = bh >> 1, half = bh & 1;
        enc_b[idx] = f2b(enc[((size_t)b*S_ + half*256 + s)*ENC_ + e]);
    } else if (idx < 11534336LL){
        long long q = idx - 8388608LL;
        int ds = (int)(q / 98304); int r = (int)(q % 98304);
        int kh = r / 49152; int r2 = r % 49152;
        int jc = r2 / 8192; int r3 = r2 % 8192;
        int kc = r3 >> 9, l = (r3 >> 3) & 63, e = r3 & 7;
        int j = (jc >> 1)*1024 + ds*32 + (jc & 1)*16 + (l & 15);
        int k = kh*512 + kc*32 + ((l >> 4) << 3) + e;
        wgh[q] = f2b(whh[(size_t)j*DEC_ + k]);
    } else if (idx < 12320768LL){
        long long q = idx - 11534336LL;
        int ds = (int)(q / 24576); int r = (int)(q % 24576);
        int jc = r / 4096; int r3 = r % 4096;
        int kc = r3 >> 9, l = (r3 >> 3) & 63, e = r3 & 7;
        int j = (jc >> 1)*1024 + ds*32 + (jc & 1)*16 + (l & 15);
        int k = kc*32 + ((l >> 4) << 3) + e;
        wgx[q] = f2b(wih[(size_t)j*768 + k]);
    } else if (idx < 13893632LL){
        long long q = idx - 12320768LL;
        int ds = (int)(q / 49152); int r = (int)(q % 49152);
        int jc = r / 8192; int r3 = r % 8192;
        int kc = r3 >> 9, l = (r3 >> 3) & 63, e = r3 & 7;
        int j = (jc >> 1)*1024 + ds*32 + (jc & 1)*16 + (l & 15);
        int k = kc*32 + ((l >> 4) << 3) + e;
        wgc[q] = f2b(wih[(size_t)j*768 + 256 + k]);
    } else if (idx < 14090240LL){
        long long q = idx - 13893632LL;
        int cg = (int)(q / 49152); int r = (int)(q % 49152);
        int oc = r / 1536, k = r % 1536;
        ow_b[q] = f2b(oww[(size_t)k*M_ + cg*32 + oc]);
    }
}

// ep_b[b][512 s][128 a] bf16 = enc @ att_we + be
__global__ __launch_bounds__(256) void k_encproj(const float* __restrict__ enc,
        const float* __restrict__ we, const float* __restrict__ be,
        unsigned short* __restrict__ ep_b){
    __shared__ float we_s[64*128];
    __shared__ float enc_s[64*64];
    int blk = blockIdx.x, tid = threadIdx.x;
    int b = blk >> 3, ss = blk & 7;
    int s = tid >> 2, ag = tid & 3;
    float acc[32];
    #pragma unroll
    for (int j = 0; j < 32; ++j) acc[j] = 0.f;
    for (int kc = 0; kc < 8; ++kc){
        __syncthreads();
        for (int i = tid; i < 8192; i += 256)
            we_s[i] = we[(size_t)(kc*64 + (i >> 7))*ATT_ + (i & 127)];
        for (int i = tid; i < 4096; i += 256)
            enc_s[i] = enc[((size_t)b*S_ + ss*64 + (i >> 6))*ENC_ + kc*64 + (i & 63)];
        __syncthreads();
        for (int kk = 0; kk < 64; ++kk){
            float ev = enc_s[s*64 + kk];
            const float* wr = &we_s[(kk << 7) + (ag << 5)];
            #pragma unroll
            for (int j = 0; j < 32; ++j) acc[j] += ev*wr[j];
        }
    }
    #pragma unroll
    for (int j = 0; j < 32; ++j){
        int a = (ag << 5) + j;
        ep_b[((size_t)b*512 + ss*64 + s)*ATT_ + a] = f2b(acc[j] + be[a]);
    }
}

// PreNet (f32 math, bf16 output)
__global__ __launch_bounds__(128) void k_prenet(const float* __restrict__ tm,
        const float* __restrict__ w1, const float* __restrict__ b1,
        const float* __restrict__ w2, const float* __restrict__ b2,
        unsigned short* __restrict__ xall){
    __shared__ float mel_l[128*20];
    __shared__ float h1_l[256*20];
    int row0 = blockIdx.x << 4;
    int t = row0 >> 5, b0 = row0 & 31;
    int tid = threadIdx.x;
    for (int p = 0; p < 16; p++){
        int idx = tid + (p << 7);
        int k = idx & 127, r = idx >> 7;
        float v = 0.f;
        if (t > 0) v = tm[((size_t)(b0 + r)*T_ + (t - 1))*M_ + k];
        mel_l[k*20 + r] = v;
    }
    __syncthreads();
    float acc1[16], acc2[16];
    #pragma unroll
    for (int i = 0; i < 16; i++){ acc1[i] = 0.f; acc2[i] = 0.f; }
    for (int k = 0; k < M_; k++){
        float wa = w1[k*256 + tid];
        float wb = w1[k*256 + tid + 128];
        float mv[16];
        *(float4*)&mv[0]  = *(const float4*)&mel_l[k*20 + 0];
        *(float4*)&mv[4]  = *(const float4*)&mel_l[k*20 + 4];
        *(float4*)&mv[8]  = *(const float4*)&mel_l[k*20 + 8];
        *(float4*)&mv[12] = *(const float4*)&mel_l[k*20 + 12];
        #pragma unroll
        for (int r = 0; r < 16; r++){ acc1[r] += mv[r]*wa; acc2[r] += mv[r]*wb; }
    }
    float bb1a = b1[tid], bb1b = b1[tid + 128];
    #pragma unroll
    for (int r = 0; r < 16; r++){
        h1_l[tid*20 + r]         = fmaxf(acc1[r] + bb1a, 0.f);
        h1_l[(tid + 128)*20 + r] = fmaxf(acc2[r] + bb1b, 0.f);
    }
    __syncthreads();
    #pragma unroll
    for (int i = 0; i < 16; i++){ acc1[i] = 0.f; acc2[i] = 0.f; }
    for (int k = 0; k < 256; k++){
        float wa = w2[k*256 + tid];
        float wb = w2[k*256 + tid + 128];
        float mv[16];
        *(float4*)&mv[0]  = *(const float4*)&h1_l[k*20 + 0];
        *(float4*)&mv[4]  = *(const float4*)&h1_l[k*20 + 4];
        *(float4*)&mv[8]  = *(const float4*)&h1_l[k*20 + 8];
        *(float4*)&mv[12] = *(const float4*)&h1_l[k*20 + 12];
        #pragma unroll
        for (int r = 0; r < 16; r++){ acc1[r] += mv[r]*wa; acc2[r] += mv[r]*wb; }
    }
    float bb2a = b2[tid], bb2b = b2[tid + 128];
    #pragma unroll
    for (int r = 0; r < 16; r++){
        xall[((size_t)row0 + r)*PO_ + tid]       = f2b(fmaxf(acc1[r] + bb2a, 0.f));
        xall[((size_t)row0 + r)*PO_ + tid + 128] = f2b(fmaxf(acc2[r] + bb2b, 0.f));
    }
}

// ================= persistent lockstep decoder =================
#define DYN_BYTES 110592

struct KP {
    const unsigned short* xall_b; const unsigned short* enc_b; const unsigned short* ep_b;
    const unsigned short* wgh; const unsigned short* wgx; const unsigned short* wgc;
    const unsigned short* ow_b;
    const float* awd; const float* sw; const float* bd; const float* av; const float* avb;
    const float* bih; const float* bhh; const float* p_ob; const float* p_sb;
    float* h_f32; unsigned short* h_fb;
    unsigned short* ctx_b; float* den; float* es_b; float* pgh; float* pgx; float* dpp;
    unsigned* cnt; float* out;
};

__global__ __launch_bounds__(1024) void k_persist(KP p){
    extern __shared__ char sm[];
    const int bid = blockIdx.x, tid = threadIdx.x;
    const int lane = tid & 63;
    unsigned epn = 0;
    unsigned* cnt = p.cnt;

    if (bid < 64){
        // ================= GATE (ds = bid>>1, kh = bid&1) =================
        const int ds = bid >> 1, kh = bid & 1;
        unsigned short* hf_b = (unsigned short*)sm;            // ph1 32KB (alias cf)
        char* cf = sm;                                         // ph2 ctx frags 32KB
        float* gis   = (float*)(sm + 32768);                   // [32][100] 12800B
        float* pg_s  = (float*)(sm + 45568);                   // [3][3072] 36864B
        float* h_l   = (float*)(sm + 82432);                   // [32][32] 4096B
        float* rden_l= (float*)(sm + 86528);                   // 32 f
        float h_reg = 0.f;
        const int pb = tid >> 5, pd = tid & 31;                // pointwise (b, dloc)

        for (int t = 0; t <= T_; ++t){
            // ---------- phase 1: gh + gix MFMA ----------
            if (t < T_){
                const ull* shb = (const ull*)p.h_fb;
                for (int i = tid; i < 4096; i += 1024){
                    int u = i & 1, l = (i >> 1) & 63, kc = (i >> 7) & 15, bt = i >> 11;
                    size_t si = ((((size_t)bt*32 + kh*16 + kc)*64 + l) << 1) + u;
                    ((ull*)hf_b)[i] = ald64(&shb[si]);
                }
                __syncthreads();
                int w = tid >> 6;
                if (w < 12){
                    int jc = w >> 1, bt = w & 1;
                    int r4 = lane >> 4, c16 = lane & 15;
                    const bf16x8* Bh = (const bf16x8*)p.wgh +
                        ((size_t)((ds*2 + kh)*6 + jc)*16)*64 + lane;
                    f32x4 acc = {0.f,0.f,0.f,0.f};
                    #pragma unroll
                    for (int kc = 0; kc < 16; ++kc){
                        bf16x8 ah = *(const bf16x8*)(hf_b + (((bt*16 + kc)*64 + lane) << 3));
                        acc = mfma16(ah, Bh[kc*64], acc);
                    }
                    #pragma unroll
                    for (int r = 0; r < 4; ++r){
                        float v1 = __shfl_xor(acc[r], 1);
                        if (!(lane & 1)){
                            int b = bt*16 + r4*4 + r;
                            ast2f(&p.pgh[(((size_t)ds*2 + kh)*32 + b)*96 + jc*16 + c16],
                                  acc[r], v1);
                        }
                    }
                    if (kh){
                        const bf16x8* Xp = (const bf16x8*)p.wgx +
                            ((size_t)(ds*6 + jc)*8)*64 + lane;
                        f32x4 ax = {0.f,0.f,0.f,0.f};
                        #pragma unroll
                        for (int kc = 0; kc < 8; ++kc){
                            bf16x8 a = *(const bf16x8*)(p.xall_b +
                                ((size_t)t*32 + bt*16 + c16)*256 + kc*32 + r4*8);
                            ax = mfma16(a, Xp[kc*64], ax);
                        }
                        #pragma unroll
                        for (int r = 0; r < 4; ++r){
                            float v1 = __shfl_xor(ax[r], 1);
                            if (!(lane & 1)){
                                int b = bt*16 + r4*4 + r;
                                ast2f(&p.pgx[((size_t)ds*32 + b)*96 + jc*16 + c16],
                                      ax[r], v1);
                            }
                        }
                    }
                }
            }
            gbar(cnt, (++epn) << 8);
            // ---------- phase 2: gic + gates + dpp (kh==0) ----------
            if (t < T_ && kh == 0){
                const int slot = t & 1;
                if (tid < 32)
                    rden_l[tid] = frcp(ald(&p.den[slot*64 + tid]) +
                                       ald(&p.den[slot*64 + 32 + tid]));
                for (int i = tid; i < 4608; i += 1024){
                    int which = i / 1536, r = i - which*1536;
                    const ull* src = (which < 2) ?
                        ((const ull*)p.pgh + ((size_t)ds*2 + which)*1536 + r) :
                        ((const ull*)p.pgx + (size_t)ds*1536 + r);
                    ((ull*)pg_s)[i] = ald64(src);
                }
                __syncthreads();
                for (int i = tid; i < 2048; i += 1024){
                    int l = i & 63, kc = (i >> 6) & 15, bt = i >> 10;
                    int b = bt*16 + (l & 15);
                    int e0 = kc*32 + ((l >> 4) << 3);
                    const ull* c0 = (const ull*)p.ctx_b + (((size_t)slot*2 + 0)*32 + b)*128 + (e0 >> 2);
                    const ull* c1 = (const ull*)p.ctx_b + (((size_t)slot*2 + 1)*32 + b)*128 + (e0 >> 2);
                    ull u00 = ald64(c0), u01 = ald64(c0 + 1);
                    ull u10 = ald64(c1), u11 = ald64(c1 + 1);
                    float rd = rden_l[b];
                    uint2 x0 = __builtin_bit_cast(uint2, u00);
                    uint2 x1 = __builtin_bit_cast(uint2, u01);
                    uint2 y0 = __builtin_bit_cast(uint2, u10);
                    uint2 y1 = __builtin_bit_cast(uint2, u11);
                    float2 a0 = upk2(x0.x), b0 = upk2(y0.x);
                    float2 a1 = upk2(x0.y), b1 = upk2(y0.y);
                    float2 a2 = upk2(x1.x), b2 = upk2(y1.x);
                    float2 a3 = upk2(x1.y), b3 = upk2(y1.y);
                    unsigned w0 = pk2((a0.x + b0.x)*rd, (a0.y + b0.y)*rd);
                    unsigned w1 = pk2((a1.x + b1.x)*rd, (a1.y + b1.y)*rd);
                    unsigned w2 = pk2((a2.x + b2.x)*rd, (a2.y + b2.y)*rd);
                    unsigned w3 = pk2((a3.x + b3.x)*rd, (a3.y + b3.y)*rd);
                    *(uint4*)(cf + (size_t)i*16) = make_uint4(w0, w1, w2, w3);
                }
                __syncthreads();
                int w = tid >> 6;
                if (w < 12){
                    int jc = w >> 1, bt = w & 1;
                    int r4 = lane >> 4, c16 = lane & 15;
                    const bf16x8* Cp = (const bf16x8*)p.wgc +
                        ((size_t)(ds*6 + jc)*16)*64 + lane;
                    f32x4 acc = {0.f,0.f,0.f,0.f};
                    #pragma unroll
                    for (int kc = 0; kc < 16; ++kc){
                        bf16x8 a = *(const bf16x8*)(cf + (((bt*16 + kc)*64 + lane) << 4));
                        acc = mfma16(a, Cp[kc*64], acc);
                    }
                    #pragma unroll
                    for (int r = 0; r < 4; ++r)
                        gis[(bt*16 + r4*4 + r)*100 + jc*16 + c16] = acc[r];
                }
                __syncthreads();
                {
                    int b = pb, dl = pd;
                    int jgr = ds*32 + dl;
                    float gi_r = gis[b*100 + dl]      + pg_s[6144 + b*96 + dl]      + p.bih[jgr];
                    float gi_z = gis[b*100 + 32 + dl] + pg_s[6144 + b*96 + 32 + dl] + p.bih[1024 + jgr];
                    float gi_n = gis[b*100 + 64 + dl] + pg_s[6144 + b*96 + 64 + dl] + p.bih[2048 + jgr];
                    float gh_r = pg_s[b*96 + dl]      + pg_s[3072 + b*96 + dl]      + p.bhh[jgr];
                    float gh_z = pg_s[b*96 + 32 + dl] + pg_s[3072 + b*96 + 32 + dl] + p.bhh[1024 + jgr];
                    float gh_n = pg_s[b*96 + 64 + dl] + pg_s[3072 + b*96 + 64 + dl] + p.bhh[2048 + jgr];
                    float rr = fsig(gi_r + gh_r);
                    float zz = fsig(gi_z + gh_z);
                    float nn = ftanh(gi_n + rr*gh_n);
                    float hv = (1.f - zz)*nn + zz*h_reg;
                    h_reg = hv;
                    h_l[b*32 + dl] = hv;
                    float hv1 = __shfl_xor(hv, 1);
                    if (!(dl & 1)){
                        int d = ds*32 + dl;
                        ast2f(&p.h_f32[(size_t)b*1024 + d], hv, hv1);
                        unsigned pkv = pk2(hv, hv1);
                        int l2 = ((dl >> 3) << 4) + (b & 15);
                        size_t fo = ((((size_t)(b >> 4)*32 + ds)*64 + l2) << 2) + ((dl & 7) >> 1);
                        astu((unsigned*)p.h_fb + fo, pkv);
                    }
                }
                __syncthreads();
                {   // dproj partials (pure f32): dpp[ds][b][a] over this block's 32 d
                    int b = tid >> 5, ag = tid & 31;
                    const float* ar = p.awd + (size_t)(ds*32)*128 + ag*4;
                    float s0 = 0.f, s1 = 0.f, s2 = 0.f, s3 = 0.f;
                    #pragma unroll 8
                    for (int dl = 0; dl < 32; ++dl){
                        float hd = h_l[b*32 + dl];
                        float4 w4 = *(const float4*)(ar + (size_t)dl*128);
                        s0 += hd*w4.x; s1 += hd*w4.y; s2 += hd*w4.z; s3 += hd*w4.w;
                    }
                    float* dp = p.dpp + ((size_t)ds*32 + b)*128 + ag*4;
                    ast2f(dp, s0, s1); ast2f(dp + 2, s2, s3);
                }
            }
            gbar(cnt, (++epn) << 8);
        }
    } else if (bid < 128){
        // ================= ATT (b, half) =================
        const int aa = bid - 64, b = aa >> 1, half = aa & 1;
        unsigned short* ep_l = (unsigned short*)sm;          // 65536
        float* red  = (float*)(sm + 65536);                  // [16][522] 33408
        float* sred = (float*)(sm + 98944);                  // 4096
        float* dpl  = (float*)(sm + 103040);                 // 512
        float* avl  = (float*)(sm + 103552);                 // 512
        float* esl  = (float*)(sm + 104064);                 // 1024
        {
            const ull* src = (const ull*)(p.ep_b + ((size_t)b*512 + half*256)*128);
            for (int i = tid; i < 8192; i += 1024) ((ull*)ep_l)[i] = src[i];
            if (tid < 128) avl[tid] = p.av[tid];
        }
        __syncthreads();
        for (int t = 0; t <= T_; ++t){
            if (t < T_){
                const int slot = t & 1;
                {   // dproj = sum of 32 GATE partials
                    int a = tid & 127, g = tid >> 7;
                    float s = 0.f;
                    #pragma unroll
                    for (int i = 0; i < 4; ++i)
                        s += ald(&p.dpp[((size_t)(g*4 + i)*32 + b)*128 + a]);
                    red[g*128 + a] = s;
                }
                __syncthreads();
                if (tid < 128){
                    float s = p.bd[tid];
                    #pragma unroll
                    for (int g = 0; g < 8; ++g) s += red[g*128 + tid];
                    dpl[tid] = s;
                }
                __syncthreads();
                {
                    int s = tid >> 2, ao = tid & 3;
                    const unsigned* er = (const unsigned*)ep_l + s*64 + ao*16;
                    float sc = 0.f;
                    #pragma unroll
                    for (int i = 0; i < 16; ++i){
                        float2 e2 = upk2(er[i]);
                        int a0 = ao*32 + i*2;
                        sc += ftanh(e2.x + dpl[a0])*avl[a0]
                            + ftanh(e2.y + dpl[a0+1])*avl[a0+1];
                    }
                    sred[tid] = sc;
                }
                __syncthreads();
                if (tid < 256){
                    float sc = sred[tid*4] + sred[tid*4+1] + sred[tid*4+2] + sred[tid*4+3] + p.avb[0];
                    float ev = __expf(sc);
                    esl[tid] = ev;
                    astf(&p.es_b[(size_t)slot*16384 + b*512 + half*256 + tid], ev);
                }
                __syncthreads();
                if (tid < 64){
                    float d = esl[tid*4] + esl[tid*4+1] + esl[tid*4+2] + esl[tid*4+3];
                    #pragma unroll
                    for (int m = 1; m <= 32; m <<= 1) d += __shfl_xor(d, m);
                    if (tid == 0) astf(&p.den[slot*64 + half*32 + b], d);
                }
                {
                    int eo = tid >> 4, sg = tid & 15;
                    int e8 = eo*8;
                    const unsigned short* eb = p.enc_b + ((size_t)b*2 + half)*131072;
                    float a0=0,a1=0,a2=0,a3=0,a4=0,a5=0,a6=0,a7=0;
                    #pragma unroll 4
                    for (int i = 0; i < 16; ++i){
                        int s = sg*16 + i;
                        float ev = esl[s];
                        uint4 u = *(const uint4*)(eb + (size_t)s*512 + e8);
                        float2 v0=upk2(u.x), v1=upk2(u.y), v2=upk2(u.z), v3=upk2(u.w);
                        a0+=ev*v0.x; a1+=ev*v0.y; a2+=ev*v1.x; a3+=ev*v1.y;
                        a4+=ev*v2.x; a5+=ev*v2.y; a6+=ev*v3.x; a7+=ev*v3.y;
                    }
                    float* rr = &red[sg*522 + e8];
                    rr[0]=a0; rr[1]=a1; rr[2]=a2; rr[3]=a3;
                    rr[4]=a4; rr[5]=a5; rr[6]=a6; rr[7]=a7;
                }
                __syncthreads();
                if (tid < 512){
                    float c = 0.f;
                    #pragma unroll
                    for (int sg = 0; sg < 16; ++sg) c += red[sg*522 + tid];
                    float c1 = __shfl_xor(c, 1);
                    if (!(tid & 1))
                        astu((unsigned*)p.ctx_b + (((size_t)slot*2 + half)*32 + b)*256 + (tid >> 1),
                             pk2(c, c1));
                }
            }
            gbar(cnt, (++epn) << 8);
            gbar(cnt, (++epn) << 8);
        }
    } else {
        // ================= MEL (b, q) =================
        const int m = bid - 128, b = m >> 2, q = m & 3;
        unsigned short* ow_l = (unsigned short*)sm;   // [32 oc][1538] = 98432B
        float* dout = (float*)(sm + 98432);           // 1536 f
        float* redm = (float*)(sm + 104576);          // [32][33]
        float* rdm  = (float*)(sm + 108800);
        float* stpr = (float*)(sm + 108816);          // 8 f
        {
            const ull* src = (const ull*)p.ow_b + (size_t)q*12288;
            for (int i = tid; i < 12288; i += 1024){
                int oc = i / 384, kq = i - oc*384;
                uint2 u = __builtin_bit_cast(uint2, src[i]);
                unsigned* d = (unsigned*)ow_l + (size_t)oc*769 + kq*2;
                d[0] = u.x; d[1] = u.y;
            }
        }
        __syncthreads();
        for (int t = 0; t <= T_; ++t){
            if (t >= 1){
                const int slot = (t - 1) & 1;
                if (tid < 512){
                    ull u = ald64((const ull*)p.h_f32 + (size_t)b*512 + tid);
                    *(float2*)&dout[tid*2] = __builtin_bit_cast(float2, u);
                } else if (tid < 768){
                    int i = tid - 512;
                    unsigned u0 = aldu((const unsigned*)p.ctx_b + (((size_t)slot*2 + 0)*32 + b)*256 + i);
                    unsigned u1 = aldu((const unsigned*)p.ctx_b + (((size_t)slot*2 + 1)*32 + b)*256 + i);
                    float2 f0 = upk2(u0), f1 = upk2(u1);
                    *(float2*)&dout[1024 + i*2] = make_float2(f0.x + f1.x, f0.y + f1.y);
                } else if (tid == 1023){
                    rdm[0] = frcp(ald(&p.den[slot*64 + b]) + ald(&p.den[slot*64 + 32 + b]));
                }
                __syncthreads();
                if (tid < 512) dout[1024 + tid] *= rdm[0];
                __syncthreads();
                {
                    int kg = tid >> 5, oc = tid & 31;
                    const unsigned* wr = (const unsigned*)ow_l + (size_t)oc*769 + kg*24;
                    const float* dr = dout + kg*48;
                    float a = 0.f;
                    #pragma unroll 6
                    for (int i = 0; i < 24; ++i){
                        float2 w2 = upk2(wr[i]);
                        a += dr[i*2]*w2.x + dr[i*2+1]*w2.y;
                    }
                    redm[kg*33 + oc] = a;
                }
                if (q == 0 && tid < 512){
                    int k3 = tid*3;
                    float s = dout[k3]*p.sw[k3] + dout[k3+1]*p.sw[k3+1] + dout[k3+2]*p.sw[k3+2];
                    #pragma unroll
                    for (int mm = 1; mm <= 32; mm <<= 1) s += __shfl_xor(s, mm);
                    if ((tid & 63) == 0) stpr[tid >> 6] = s;
                    float ev = ald(&p.es_b[(size_t)slot*16384 + b*512 + tid]);
                    p.out[AW_OFF + ((size_t)b*T_ + (t-1))*S_ + tid] = ev*rdm[0];
                }
                __syncthreads();
                if (tid < 32){
                    float a = 0.f;
                    #pragma unroll
                    for (int kg = 0; kg < 32; ++kg) a += redm[kg*33 + tid];
                    int c = q*32 + tid;
                    p.out[MEL_OFF + ((size_t)b*T_ + (t-1))*M_ + c] = a + p.p_ob[c];
                } else if (tid == 32 && q == 0){
                    float tot = 0.f;
                    #pragma unroll
                    for (int w2 = 0; w2 < 8; ++w2) tot += stpr[w2];
                    p.out[STOP_OFF + (size_t)b*T_ + (t-1)] = tot + p.p_sb[0];
                }
            }
            gbar(cnt, (++epn) << 8);
            gbar(cnt, (++epn) << 8);
        }
    }
}

extern "C" void kernel_launch(void* const* d_in, const int* in_sizes, int n_in,
                              void* d_out, int out_size, void* d_ws, size_t ws_size,
                              hipStream_t stream){
    const float* enc = (const float*)d_in[0];
    const float* tm  = (const float*)d_in[1];
    const float* pw1 = (const float*)d_in[2];
    const float* pb1 = (const float*)d_in[3];
    const float* pw2 = (const float*)d_in[4];
    const float* pb2 = (const float*)d_in[5];
    const float* awe = (const float*)d_in[6];
    const float* abe = (const float*)d_in[7];
    const float* awd = (const float*)d_in[8];
    const float* abd = (const float*)d_in[9];
    const float* av  = (const float*)d_in[10];
    const float* avb = (const float*)d_in[11];
    const float* wih = (const float*)d_in[12];
    const float* whh = (const float*)d_in[13];
    const float* bih = (const float*)d_in[14];
    const float* bhh = (const float*)d_in[15];
    const float* oww = (const float*)d_in[16];
    const float* obb = (const float*)d_in[17];
    const float* sww = (const float*)d_in[18];
    const float* sbb = (const float*)d_in[19];
    float* out = (float*)d_out;
    float* ws  = (float*)d_ws;

    // workspace (float offsets), ~43 MB
    unsigned short* xall_b = (unsigned short*)ws;                //  4,194,304 ush
    unsigned short* enc_b  = (unsigned short*)(ws + 2097152);    //  8,388,608 ush
    unsigned short* ep_b   = (unsigned short*)(ws + 6291456);    //  2,097,152 ush
    unsigned short* wgh    = (unsigned short*)(ws + 7340032);    //  3,145,728 ush
    unsigned short* wgx    = (unsigned short*)(ws + 8912896);    //    786,432 ush
    unsigned short* wgc    = (unsigned short*)(ws + 9306112);    //  1,572,864 ush
    unsigned short* ow_b   = (unsigned short*)(ws + 10092544);   //    196,608 ush
    float* h_f32 = ws + 10190848;                                //     32,768 f
    unsigned short* h_fb   = (unsigned short*)(ws + 10223616);   //     32,768 ush
    unsigned short* ctx_b  = (unsigned short*)(ws + 10240000);   //     65,536 ush
    float* den  = ws + 10272768;                                 //        128 f
    float* es_b = ws + 10272896;                                 //     32,768 f
    float* pgh  = ws + 10305664;                                 //    196,608 f
    float* pgx  = ws + 10502272;                                 //     98,304 f
    float* dpp  = ws + 10600576;                                 //    131,072 f
    unsigned* cnt = (unsigned*)(ws + 10731648);

    hipMemsetAsync(h_f32, 0, 32768*4, stream);
    hipMemsetAsync(h_fb, 0, 32768*2, stream);
    hipMemsetAsync(dpp, 0, (size_t)131072*4, stream);
    hipMemsetAsync(cnt, 0, 64, stream);

    k_prep_w<<<55040, 256, 0, stream>>>(enc, whh, wih, oww,
                                        enc_b, wgh, wgx, wgc, ow_b);
    k_encproj<<<256, 256, 0, stream>>>(enc, awe, abe, ep_b);
    k_prenet<<<1024, 128, 0, stream>>>(tm, pw1, pb1, pw2, pb2, xall_b);

    hipFuncSetAttribute((const void*)k_persist,
                        hipFuncAttributeMaxDynamicSharedMemorySize, DYN_BYTES);

    KP kp;
    kp.xall_b = xall_b; kp.enc_b = enc_b; kp.ep_b = ep_b;
    kp.wgh = wgh; kp.wgx = wgx; kp.wgc = wgc; kp.ow_b = ow_b;
    kp.awd = awd; kp.sw = sww; kp.bd = abd; kp.av = av; kp.avb = avb;
    kp.bih = bih; kp.bhh = bhh; kp.p_ob = obb; kp.p_sb = sbb;
    kp.h_f32 = h_f32; kp.h_fb = h_fb;
    kp.ctx_b = ctx_b; kp.den = den; kp.es_b = es_b; kp.pgh = pgh; kp.pgx = pgx;
    kp.dpp = dpp; kp.cnt = cnt; kp.out = out;

    KP* kparg = &kp;
    void* args[] = { (void*)kparg };
    hipLaunchCooperativeKernel((void*)k_persist, dim3(256), dim3(1024),
                               args, DYN_BYTES, stream);
}

// Round 10
// 17383.797 us; speedup vs baseline: 8.0039x; 1.2734x over previous
//
#include <hip/hip_runtime.h>

// Problem constants
constexpr int B_   = 32;
constexpr int S_   = 512;
constexpr int T_   = 512;
constexpr int ENC_ = 512;
constexpr int ATT_ = 128;
constexpr int PO_  = 256;
constexpr int DEC_ = 1024;
constexpr int M_   = 128;

// Output offsets (floats)
constexpr int MEL_OFF  = 0;
constexpr int STOP_OFF = B_*T_*M_;            // 2,097,152
constexpr int AW_OFF   = STOP_OFF + B_*T_;    // 2,113,536

typedef __attribute__((ext_vector_type(8))) short bf16x8;
typedef __attribute__((ext_vector_type(4))) float f32x4;
typedef unsigned long long ull;

__device__ __forceinline__ float frcp(float x){ return __builtin_amdgcn_rcpf(x); }
__device__ __forceinline__ float ftanh(float x){ float e = __expf(2.f*x); return 1.f - 2.f*frcp(e + 1.f); }
__device__ __forceinline__ float fsig(float x){ return frcp(1.f + __expf(-x)); }

__device__ __forceinline__ float2 upk2(unsigned u){
    return make_float2(__builtin_bit_cast(float, u << 16),
                       __builtin_bit_cast(float, u & 0xffff0000u));
}
__device__ __forceinline__ unsigned short f2b(float f){
    unsigned u = __builtin_bit_cast(unsigned, f);
    return (unsigned short)((u + 0x7fffu + ((u >> 16) & 1u)) >> 16);
}
__device__ __forceinline__ unsigned pk2(float a, float b){
    return (unsigned)f2b(a) | ((unsigned)f2b(b) << 16);
}

// ---- relaxed agent-scope (device-coherent) accessors (R3/R8-proven) ----------
__device__ __forceinline__ float ald(const float* p){
    return __hip_atomic_load(p, __ATOMIC_RELAXED, __HIP_MEMORY_SCOPE_AGENT);
}
__device__ __forceinline__ ull ald64(const void* p){
    return __hip_atomic_load((const ull*)p, __ATOMIC_RELAXED, __HIP_MEMORY_SCOPE_AGENT);
}
__device__ __forceinline__ unsigned aldu(const unsigned* p){
    return __hip_atomic_load(p, __ATOMIC_RELAXED, __HIP_MEMORY_SCOPE_AGENT);
}
__device__ __forceinline__ void astf(float* p, float v){
    __hip_atomic_store(p, v, __ATOMIC_RELAXED, __HIP_MEMORY_SCOPE_AGENT);
}
union F2U { float2 f; ull u; };
__device__ __forceinline__ void ast2f(float* p, float a, float b){
    F2U x; x.f = make_float2(a, b);
    __hip_atomic_store((ull*)p, x.u, __ATOMIC_RELAXED, __HIP_MEMORY_SCOPE_AGENT);
}
__device__ __forceinline__ void astu(unsigned* p, unsigned v){
    __hip_atomic_store(p, v, __ATOMIC_RELAXED, __HIP_MEMORY_SCOPE_AGENT);
}

// ---- hierarchical global barrier: NO cache fences (R3/R8 protocol) -----------
// level 1: 8 padded group counters (32 blocks each); level 2: root (8 groups).
__device__ __forceinline__ void gbar2(unsigned* grp, unsigned* root, unsigned ep){
    asm volatile("s_waitcnt vmcnt(0) lgkmcnt(0)" ::: "memory");
    __syncthreads();
    if (threadIdx.x == 0){
        unsigned g = blockIdx.x >> 5;
        unsigned old = __hip_atomic_fetch_add(&grp[g*16], 1u, __ATOMIC_RELAXED, __HIP_MEMORY_SCOPE_AGENT);
        if (old == ep*32u - 1u)
            __hip_atomic_fetch_add(root, 1u, __ATOMIC_RELAXED, __HIP_MEMORY_SCOPE_AGENT);
        while (__hip_atomic_load(root, __ATOMIC_RELAXED, __HIP_MEMORY_SCOPE_AGENT) < ep*8u)
            __builtin_amdgcn_s_sleep(1);
    }
    __syncthreads();
}

__device__ __forceinline__ f32x4 mfma16(bf16x8 a, bf16x8 b, f32x4 c){
    return __builtin_amdgcn_mfma_f32_16x16x32_bf16(a, b, c, 0, 0, 0);
}

// ================= prep: staged layouts =================
// enc_b [32 b][2 half][256 s][512 e] bf16
// wgh   [32 ds][6 jc][32 kc][64 l][8 e]  (whh B-frags, full-K per ds)
// wgx   [32 ds][6 jc][8 kc][64 l][8 e]   (wih x-part B-frags)
// wgc   [32 ds][6 jc][16 kc][64 l][8 e]  (wih ctx-part B-frags)
// ow_b  [4 q][32 oc][1536 k] bf16
__global__ __launch_bounds__(256) void k_prep_w(const float* __restrict__ enc,
        const float* __restrict__ whh, const float* __restrict__ wih,
        const float* __restrict__ oww,
        unsigned short* __restrict__ enc_b, unsigned short* __restrict__ wgh,
        unsigned short* __restrict__ wgx, unsigned short* __restrict__ wgc,
        unsigned short* __restrict__ ow_b){
    long long idx = (long long)blockIdx.x*256 + threadIdx.x;
    if (idx < 8388608LL){
        int bh = (int)(idx >> 17); int r = (int)(idx & 131071);
        int s = r >> 9, e = r & 511;
        int b = bh >> 1, half = bh & 1;
        enc_b[idx] = f2b(enc[((size_t)b*S_ + half*256 + s)*ENC_ + e]);
    } else if (idx < 11534336LL){
        long long q = idx - 8388608LL;
        int ds = (int)(q / 98304); int r = (int)(q % 98304);
        int jc = r / 16384; int r2 = r % 16384;
        int kc = r2 >> 9, l = (r2 >> 3) & 63, e = r2 & 7;
        int j = (jc >> 1)*1024 + ds*32 + (jc & 1)*16 + (l & 15);
        int k = kc*32 + ((l >> 4) << 3) + e;
        wgh[q] = f2b(whh[(size_t)j*DEC_ + k]);
    } else if (idx < 12320768LL){
        long long q = idx - 11534336LL;
        int ds = (int)(q / 24576); int r = (int)(q % 24576);
        int jc = r / 4096; int r3 = r % 4096;
        int kc = r3 >> 9, l = (r3 >> 3) & 63, e = r3 & 7;
        int j = (jc >> 1)*1024 + ds*32 + (jc & 1)*16 + (l & 15);
        int k = kc*32 + ((l >> 4) << 3) + e;
        wgx[q] = f2b(wih[(size_t)j*768 + k]);
    } else if (idx < 13893632LL){
        long long q = idx - 12320768LL;
        int ds = (int)(q / 49152); int r = (int)(q % 49152);
        int jc = r / 8192; int r3 = r % 8192;
        int kc = r3 >> 9, l = (r3 >> 3) & 63, e = r3 & 7;
        int j = (jc >> 1)*1024 + ds*32 + (jc & 1)*16 + (l & 15);
        int k = kc*32 + ((l >> 4) << 3) + e;
        wgc[q] = f2b(wih[(size_t)j*768 + 256 + k]);
    } else if (idx < 14090240LL){
        long long q = idx - 13893632LL;
        int cg = (int)(q / 49152); int r = (int)(q % 49152);
        int oc = r / 1536, k = r % 1536;
        ow_b[q] = f2b(oww[(size_t)k*M_ + cg*32 + oc]);
    }
}

// ep_b[b][512 s][128 a] bf16 = enc @ att_we + be
__global__ __launch_bounds__(256) void k_encproj(const float* __restrict__ enc,
        const float* __restrict__ we, const float* __restrict__ be,
        unsigned short* __restrict__ ep_b){
    __shared__ float we_s[64*128];
    __shared__ float enc_s[64*64];
    int blk = blockIdx.x, tid = threadIdx.x;
    int b = blk >> 3, ss = blk & 7;
    int s = tid >> 2, ag = tid & 3;
    float acc[32];
    #pragma unroll
    for (int j = 0; j < 32; ++j) acc[j] = 0.f;
    for (int kc = 0; kc < 8; ++kc){
        __syncthreads();
        for (int i = tid; i < 8192; i += 256)
            we_s[i] = we[(size_t)(kc*64 + (i >> 7))*ATT_ + (i & 127)];
        for (int i = tid; i < 4096; i += 256)
            enc_s[i] = enc[((size_t)b*S_ + ss*64 + (i >> 6))*ENC_ + kc*64 + (i & 63)];
        __syncthreads();
        for (int kk = 0; kk < 64; ++kk){
            float ev = enc_s[s*64 + kk];
            const float* wr = &we_s[(kk << 7) + (ag << 5)];
            #pragma unroll
            for (int j = 0; j < 32; ++j) acc[j] += ev*wr[j];
        }
    }
    #pragma unroll
    for (int j = 0; j < 32; ++j){
        int a = (ag << 5) + j;
        ep_b[((size_t)b*512 + ss*64 + s)*ATT_ + a] = f2b(acc[j] + be[a]);
    }
}

// PreNet (f32 math, bf16 output)
__global__ __launch_bounds__(128) void k_prenet(const float* __restrict__ tm,
        const float* __restrict__ w1, const float* __restrict__ b1,
        const float* __restrict__ w2, const float* __restrict__ b2,
        unsigned short* __restrict__ xall){
    __shared__ float mel_l[128*20];
    __shared__ float h1_l[256*20];
    int row0 = blockIdx.x << 4;
    int t = row0 >> 5, b0 = row0 & 31;
    int tid = threadIdx.x;
    for (int p = 0; p < 16; p++){
        int idx = tid + (p << 7);
        int k = idx & 127, r = idx >> 7;
        float v = 0.f;
        if (t > 0) v = tm[((size_t)(b0 + r)*T_ + (t - 1))*M_ + k];
        mel_l[k*20 + r] = v;
    }
    __syncthreads();
    float acc1[16], acc2[16];
    #pragma unroll
    for (int i = 0; i < 16; i++){ acc1[i] = 0.f; acc2[i] = 0.f; }
    for (int k = 0; k < M_; k++){
        float wa = w1[k*256 + tid];
        float wb = w1[k*256 + tid + 128];
        float mv[16];
        *(float4*)&mv[0]  = *(const float4*)&mel_l[k*20 + 0];
        *(float4*)&mv[4]  = *(const float4*)&mel_l[k*20 + 4];
        *(float4*)&mv[8]  = *(const float4*)&mel_l[k*20 + 8];
        *(float4*)&mv[12] = *(const float4*)&mel_l[k*20 + 12];
        #pragma unroll
        for (int r = 0; r < 16; r++){ acc1[r] += mv[r]*wa; acc2[r] += mv[r]*wb; }
    }
    float bb1a = b1[tid], bb1b = b1[tid + 128];
    #pragma unroll
    for (int r = 0; r < 16; r++){
        h1_l[tid*20 + r]         = fmaxf(acc1[r] + bb1a, 0.f);
        h1_l[(tid + 128)*20 + r] = fmaxf(acc2[r] + bb1b, 0.f);
    }
    __syncthreads();
    #pragma unroll
    for (int i = 0; i < 16; i++){ acc1[i] = 0.f; acc2[i] = 0.f; }
    for (int k = 0; k < 256; k++){
        float wa = w2[k*256 + tid];
        float wb = w2[k*256 + tid + 128];
        float mv[16];
        *(float4*)&mv[0]  = *(const float4*)&h1_l[k*20 + 0];
        *(float4*)&mv[4]  = *(const float4*)&h1_l[k*20 + 4];
        *(float4*)&mv[8]  = *(const float4*)&h1_l[k*20 + 8];
        *(float4*)&mv[12] = *(const float4*)&h1_l[k*20 + 12];
        #pragma unroll
        for (int r = 0; r < 16; r++){ acc1[r] += mv[r]*wa; acc2[r] += mv[r]*wb; }
    }
    float bb2a = b2[tid], bb2b = b2[tid + 128];
    #pragma unroll
    for (int r = 0; r < 16; r++){
        xall[((size_t)row0 + r)*PO_ + tid]       = f2b(fmaxf(acc1[r] + bb2a, 0.f));
        xall[((size_t)row0 + r)*PO_ + tid + 128] = f2b(fmaxf(acc2[r] + bb2b, 0.f));
    }
}

// ================= persistent lockstep decoder =================
#define DYN_BYTES 110592

struct KP {
    const unsigned short* xall_b; const unsigned short* enc_b; const unsigned short* ep_b;
    const unsigned short* wgh; const unsigned short* wgx; const unsigned short* wgc;
    const unsigned short* ow_b;
    const float* awd; const float* sw; const float* bd; const float* av; const float* avb;
    const float* bih; const float* bhh; const float* p_ob; const float* p_sb;
    float* h_f32; unsigned short* h_fb;
    unsigned short* ctx_b; float* den; float* es_b; float* dpp;
    unsigned* grp; unsigned* root; float* out;
};

__global__ __launch_bounds__(1024) void k_persist(KP p){
    extern __shared__ char sm[];
    const int bid = blockIdx.x, tid = threadIdx.x;
    const int lane = tid & 63;
    unsigned epn = 0;
    unsigned* grp = p.grp; unsigned* root = p.root;

    if (bid < 64){
        // ================= GATE (ds = bid>>1, bh = bid&1): 16 b x full-K ======
        const int ds = bid >> 1, bh = bid & 1;
        unsigned short* hf_b = (unsigned short*)sm;            // ph1 32KB (alias cf)
        char* cf = sm;                                         // ph2 ctx frags 16KB
        float* pgh_l = (float*)(sm + 32768);                   // [2*16][100]
        float* pgx_l = (float*)(sm + 45568);                   // [2*16][100]
        float* pgc_l = (float*)(sm + 58368);                   // [2*16][100]
        float* h_l   = (float*)(sm + 71168);                   // [16][32]
        float* rden_l= (float*)(sm + 73216);                   // 16 f
        float h_reg = 0.f;

        for (int t = 0; t <= T_; ++t){
            // ---------- phase 1: full-K gh + gix MFMA, partials stay in LDS ---
            if (t < T_){
                const ull* shb = (const ull*)p.h_fb;
                for (int i = tid; i < 4096; i += 1024){
                    int u = i & 1, l = (i >> 1) & 63, kc = i >> 7;   // kc 0..31
                    ((ull*)hf_b)[i] = ald64(&shb[(((size_t)bh*32 + kc)*64 + l)*2 + u]);
                }
                __syncthreads();
                int w = tid >> 6;
                if (w < 12){
                    int jc = w >> 1, kg = w & 1;
                    int r4 = lane >> 4, c16 = lane & 15;
                    const bf16x8* Bh = (const bf16x8*)p.wgh +
                        ((size_t)(ds*6 + jc)*32)*64 + lane;
                    f32x4 acc = {0.f,0.f,0.f,0.f};
                    #pragma unroll
                    for (int c = 0; c < 16; ++c){
                        int kc = kg*16 + c;
                        bf16x8 a = *(const bf16x8*)(hf_b + ((kc*64 + lane) << 3));
                        acc = mfma16(a, Bh[kc*64], acc);
                    }
                    #pragma unroll
                    for (int r = 0; r < 4; ++r)
                        pgh_l[(kg*16 + r4*4 + r)*100 + jc*16 + c16] = acc[r];
                    const bf16x8* Xp = (const bf16x8*)p.wgx +
                        ((size_t)(ds*6 + jc)*8)*64 + lane;
                    f32x4 ax = {0.f,0.f,0.f,0.f};
                    #pragma unroll
                    for (int c = 0; c < 4; ++c){
                        int kc = kg*4 + c;
                        bf16x8 a = *(const bf16x8*)(p.xall_b +
                            ((size_t)t*32 + bh*16 + c16)*256 + kc*32 + r4*8);
                        ax = mfma16(a, Xp[kc*64], ax);
                    }
                    #pragma unroll
                    for (int r = 0; r < 4; ++r)
                        pgx_l[(kg*16 + r4*4 + r)*100 + jc*16 + c16] = ax[r];
                }
            }
            gbar2(grp, root, ++epn);
            // ---------- phase 2: gic MFMA + gates + h + dpp -------------------
            if (t < T_){
                const int slot = t & 1;
                if (tid < 16){
                    int b = bh*16 + tid;
                    rden_l[tid] = frcp(ald(&p.den[slot*64 + b]) +
                                       ald(&p.den[slot*64 + 32 + b]));
                }
                __syncthreads();
                {   // stage normalized ctx as bf16 A-frags (1024 uint4s, i=tid)
                    int i = tid;
                    int kc = i >> 6, l = i & 63;
                    int b = bh*16 + (l & 15);
                    int e0 = kc*32 + ((l >> 4) << 3);
                    const ull* c0 = (const ull*)p.ctx_b + (((size_t)slot*2 + 0)*32 + b)*128 + (e0 >> 2);
                    const ull* c1 = (const ull*)p.ctx_b + (((size_t)slot*2 + 1)*32 + b)*128 + (e0 >> 2);
                    ull u00 = ald64(c0), u01 = ald64(c0 + 1);
                    ull u10 = ald64(c1), u11 = ald64(c1 + 1);
                    float rd = rden_l[l & 15];
                    uint2 x0 = __builtin_bit_cast(uint2, u00);
                    uint2 x1 = __builtin_bit_cast(uint2, u01);
                    uint2 y0 = __builtin_bit_cast(uint2, u10);
                    uint2 y1 = __builtin_bit_cast(uint2, u11);
                    float2 a0 = upk2(x0.x), b0 = upk2(y0.x);
                    float2 a1 = upk2(x0.y), b1 = upk2(y0.y);
                    float2 a2 = upk2(x1.x), b2 = upk2(y1.x);
                    float2 a3 = upk2(x1.y), b3 = upk2(y1.y);
                    unsigned w0 = pk2((a0.x + b0.x)*rd, (a0.y + b0.y)*rd);
                    unsigned w1 = pk2((a1.x + b1.x)*rd, (a1.y + b1.y)*rd);
                    unsigned w2 = pk2((a2.x + b2.x)*rd, (a2.y + b2.y)*rd);
                    unsigned w3 = pk2((a3.x + b3.x)*rd, (a3.y + b3.y)*rd);
                    *(uint4*)(cf + (size_t)i*16) = make_uint4(w0, w1, w2, w3);
                }
                __syncthreads();
                int w = tid >> 6;
                if (w < 12){
                    int jc = w >> 1, kg = w & 1;
                    int r4 = lane >> 4, c16 = lane & 15;
                    const bf16x8* Cp = (const bf16x8*)p.wgc +
                        ((size_t)(ds*6 + jc)*16)*64 + lane;
                    f32x4 acc = {0.f,0.f,0.f,0.f};
                    #pragma unroll
                    for (int c = 0; c < 8; ++c){
                        int kc = kg*8 + c;
                        bf16x8 a = *(const bf16x8*)(cf + ((kc*64 + lane) << 4));
                        acc = mfma16(a, Cp[kc*64], acc);
                    }
                    #pragma unroll
                    for (int r = 0; r < 4; ++r)
                        pgc_l[(kg*16 + r4*4 + r)*100 + jc*16 + c16] = acc[r];
                }
                __syncthreads();
                if (tid < 512){
                    int b16 = tid >> 5, dl = tid & 31;     // col(g) = g*32 + dl
                    int dglob = ds*32 + dl;
                    const float* pa = pgh_l + b16*100;
                    const float* pb = pgh_l + (16 + b16)*100;
                    const float* xa = pgx_l + b16*100;
                    const float* xb = pgx_l + (16 + b16)*100;
                    const float* ca = pgc_l + b16*100;
                    const float* cb = pgc_l + (16 + b16)*100;
                    float gi_r = xa[dl]      + xb[dl]      + ca[dl]      + cb[dl]      + p.bih[dglob];
                    float gi_z = xa[32 + dl] + xb[32 + dl] + ca[32 + dl] + cb[32 + dl] + p.bih[1024 + dglob];
                    float gi_n = xa[64 + dl] + xb[64 + dl] + ca[64 + dl] + cb[64 + dl] + p.bih[2048 + dglob];
                    float gh_r = pa[dl]      + pb[dl]      + p.bhh[dglob];
                    float gh_z = pa[32 + dl] + pb[32 + dl] + p.bhh[1024 + dglob];
                    float gh_n = pa[64 + dl] + pb[64 + dl] + p.bhh[2048 + dglob];
                    float rr = fsig(gi_r + gh_r);
                    float zz = fsig(gi_z + gh_z);
                    float nn = ftanh(gi_n + rr*gh_n);
                    float hv = (1.f - zz)*nn + zz*h_reg;
                    h_reg = hv;
                    h_l[b16*32 + dl] = hv;
                    float hv1 = __shfl_xor(hv, 1);
                    if (!(dl & 1)){
                        int b = bh*16 + b16;
                        ast2f(&p.h_f32[(size_t)b*1024 + dglob], hv, hv1);
                        unsigned pkv = pk2(hv, hv1);
                        int l2 = ((dl >> 3) << 4) + b16;
                        size_t fo = (((size_t)bh*32 + ds)*64 + l2)*4 + ((dl & 7) >> 1);
                        astu((unsigned*)p.h_fb + fo, pkv);
                    }
                }
                __syncthreads();
                {   // dproj partials (pure f32) over this block's 32 d, 16 b
                    int b16 = tid >> 6, ag = tid & 63;
                    int a0 = ag*2;
                    const float* ar = p.awd + (size_t)(ds*32)*128 + a0;
                    float s0 = 0.f, s1 = 0.f;
                    #pragma unroll 8
                    for (int dl = 0; dl < 32; ++dl){
                        float hd = h_l[b16*32 + dl];
                        float2 w2 = *(const float2*)(ar + (size_t)dl*128);
                        s0 += hd*w2.x; s1 += hd*w2.y;
                    }
                    ast2f(&p.dpp[(((size_t)ds*2 + bh)*16 + b16)*128 + a0], s0, s1);
                }
            }
            gbar2(grp, root, ++epn);
        }
    } else if (bid < 128){
        // ================= ATT (b, half) =================
        const int aa = bid - 64, b = aa >> 1, half = aa & 1;
        unsigned short* ep_l = (unsigned short*)sm;          // 65536
        float* red  = (float*)(sm + 65536);                  // [16][522] 33408
        float* sred = (float*)(sm + 98944);                  // 4096
        float* dpl  = (float*)(sm + 103040);                 // 512
        float* avl  = (float*)(sm + 103552);                 // 512
        float* esl  = (float*)(sm + 104064);                 // 1024
        {
            const ull* src = (const ull*)(p.ep_b + ((size_t)b*512 + half*256)*128);
            for (int i = tid; i < 8192; i += 1024) ((ull*)ep_l)[i] = src[i];
            if (tid < 128) avl[tid] = p.av[tid];
        }
        __syncthreads();
        for (int t = 0; t <= T_; ++t){
            if (t < T_){
                const int slot = t & 1;
                {   // dproj = sum of 64 (ds,bh) GATE partials matching this b
                    int a = tid & 127, g = tid >> 7;
                    const int bhb = b >> 4, b15 = b & 15;
                    float s = 0.f;
                    #pragma unroll
                    for (int i = 0; i < 4; ++i){
                        int ds2 = g*4 + i;
                        s += ald(&p.dpp[(((size_t)ds2*2 + bhb)*16 + b15)*128 + a]);
                    }
                    red[g*128 + a] = s;
                }
                __syncthreads();
                if (tid < 128){
                    float s = p.bd[tid];
                    #pragma unroll
                    for (int g = 0; g < 8; ++g) s += red[g*128 + tid];
                    dpl[tid] = s;
                }
                __syncthreads();
                {
                    int s = tid >> 2, ao = tid & 3;
                    const unsigned* er = (const unsigned*)ep_l + s*64 + ao*16;
                    float sc = 0.f;
                    #pragma unroll
                    for (int i = 0; i < 16; ++i){
                        float2 e2 = upk2(er[i]);
                        int a0 = ao*32 + i*2;
                        sc += ftanh(e2.x + dpl[a0])*avl[a0]
                            + ftanh(e2.y + dpl[a0+1])*avl[a0+1];
                    }
                    sred[tid] = sc;
                }
                __syncthreads();
                if (tid < 256){
                    float sc = sred[tid*4] + sred[tid*4+1] + sred[tid*4+2] + sred[tid*4+3] + p.avb[0];
                    float ev = __expf(sc);
                    esl[tid] = ev;
                    astf(&p.es_b[(size_t)slot*16384 + b*512 + half*256 + tid], ev);
                }
                __syncthreads();
                if (tid < 64){
                    float d = esl[tid*4] + esl[tid*4+1] + esl[tid*4+2] + esl[tid*4+3];
                    #pragma unroll
                    for (int m = 1; m <= 32; m <<= 1) d += __shfl_xor(d, m);
                    if (tid == 0) astf(&p.den[slot*64 + half*32 + b], d);
                }
                {
                    int eo = tid >> 4, sg = tid & 15;
                    int e8 = eo*8;
                    const unsigned short* eb = p.enc_b + ((size_t)b*2 + half)*131072;
                    float a0=0,a1=0,a2=0,a3=0,a4=0,a5=0,a6=0,a7=0;
                    #pragma unroll 4
                    for (int i = 0; i < 16; ++i){
                        int s = sg*16 + i;
                        float ev = esl[s];
                        uint4 u = *(const uint4*)(eb + (size_t)s*512 + e8);
                        float2 v0=upk2(u.x), v1=upk2(u.y), v2=upk2(u.z), v3=upk2(u.w);
                        a0+=ev*v0.x; a1+=ev*v0.y; a2+=ev*v1.x; a3+=ev*v1.y;
                        a4+=ev*v2.x; a5+=ev*v2.y; a6+=ev*v3.x; a7+=ev*v3.y;
                    }
                    float* rr = &red[sg*522 + e8];
                    rr[0]=a0; rr[1]=a1; rr[2]=a2; rr[3]=a3;
                    rr[4]=a4; rr[5]=a5; rr[6]=a6; rr[7]=a7;
                }
                __syncthreads();
                if (tid < 512){
                    float c = 0.f;
                    #pragma unroll
                    for (int sg = 0; sg < 16; ++sg) c += red[sg*522 + tid];
                    float c1 = __shfl_xor(c, 1);
                    if (!(tid & 1))
                        astu((unsigned*)p.ctx_b + (((size_t)slot*2 + half)*32 + b)*256 + (tid >> 1),
                             pk2(c, c1));
                }
            }
            gbar2(grp, root, ++epn);
            gbar2(grp, root, ++epn);
        }
    } else {
        // ================= MEL (b, q) =================
        const int m = bid - 128, b = m >> 2, q = m & 3;
        unsigned short* ow_l = (unsigned short*)sm;   // [32 oc][1538] = 98432B
        float* dout = (float*)(sm + 98432);           // 1536 f
        float* redm = (float*)(sm + 104576);          // [32][33]
        float* rdm  = (float*)(sm + 108800);
        float* stpr = (float*)(sm + 108816);          // 8 f
        {
            const ull* src = (const ull*)p.ow_b + (size_t)q*12288;
            for (int i = tid; i < 12288; i += 1024){
                int oc = i / 384, kq = i - oc*384;
                uint2 u = __builtin_bit_cast(uint2, src[i]);
                unsigned* d = (unsigned*)ow_l + (size_t)oc*769 + kq*2;
                d[0] = u.x; d[1] = u.y;
            }
        }
        __syncthreads();
        for (int t = 0; t <= T_; ++t){
            if (t >= 1){
                const int slot = (t - 1) & 1;
                if (tid < 512){
                    ull u = ald64((const ull*)p.h_f32 + (size_t)b*512 + tid);
                    *(float2*)&dout[tid*2] = __builtin_bit_cast(float2, u);
                } else if (tid < 768){
                    int i = tid - 512;
                    unsigned u0 = aldu((const unsigned*)p.ctx_b + (((size_t)slot*2 + 0)*32 + b)*256 + i);
                    unsigned u1 = aldu((const unsigned*)p.ctx_b + (((size_t)slot*2 + 1)*32 + b)*256 + i);
                    float2 f0 = upk2(u0), f1 = upk2(u1);
                    *(float2*)&dout[1024 + i*2] = make_float2(f0.x + f1.x, f0.y + f1.y);
                } else if (tid == 1023){
                    rdm[0] = frcp(ald(&p.den[slot*64 + b]) + ald(&p.den[slot*64 + 32 + b]));
                }
                __syncthreads();
                if (tid < 512) dout[1024 + tid] *= rdm[0];
                __syncthreads();
                {
                    int kg = tid >> 5, oc = tid & 31;
                    const unsigned* wr = (const unsigned*)ow_l + (size_t)oc*769 + kg*24;
                    const float* dr = dout + kg*48;
                    float a = 0.f;
                    #pragma unroll 6
                    for (int i = 0; i < 24; ++i){
                        float2 w2 = upk2(wr[i]);
                        a += dr[i*2]*w2.x + dr[i*2+1]*w2.y;
                    }
                    redm[kg*33 + oc] = a;
                }
                if (q == 0 && tid < 512){
                    int k3 = tid*3;
                    float s = dout[k3]*p.sw[k3] + dout[k3+1]*p.sw[k3+1] + dout[k3+2]*p.sw[k3+2];
                    #pragma unroll
                    for (int mm = 1; mm <= 32; mm <<= 1) s += __shfl_xor(s, mm);
                    if ((tid & 63) == 0) stpr[tid >> 6] = s;
                    float ev = ald(&p.es_b[(size_t)slot*16384 + b*512 + tid]);
                    p.out[AW_OFF + ((size_t)b*T_ + (t-1))*S_ + tid] = ev*rdm[0];
                }
                __syncthreads();
                if (tid < 32){
                    float a = 0.f;
                    #pragma unroll
                    for (int kg = 0; kg < 32; ++kg) a += redm[kg*33 + tid];
                    int c = q*32 + tid;
                    p.out[MEL_OFF + ((size_t)b*T_ + (t-1))*M_ + c] = a + p.p_ob[c];
                } else if (tid == 32 && q == 0){
                    float tot = 0.f;
                    #pragma unroll
                    for (int w2 = 0; w2 < 8; ++w2) tot += stpr[w2];
                    p.out[STOP_OFF + (size_t)b*T_ + (t-1)] = tot + p.p_sb[0];
                }
            }
            gbar2(grp, root, ++epn);
            gbar2(grp, root, ++epn);
        }
    }
}

extern "C" void kernel_launch(void* const* d_in, const int* in_sizes, int n_in,
                              void* d_out, int out_size, void* d_ws, size_t ws_size,
                              hipStream_t stream){
    const float* enc = (const float*)d_in[0];
    const float* tm  = (const float*)d_in[1];
    const float* pw1 = (const float*)d_in[2];
    const float* pb1 = (const float*)d_in[3];
    const float* pw2 = (const float*)d_in[4];
    const float* pb2 = (const float*)d_in[5];
    const float* awe = (const float*)d_in[6];
    const float* abe = (const float*)d_in[7];
    const float* awd = (const float*)d_in[8];
    const float* abd = (const float*)d_in[9];
    const float* av  = (const float*)d_in[10];
    const float* avb = (const float*)d_in[11];
    const float* wih = (const float*)d_in[12];
    const float* whh = (const float*)d_in[13];
    const float* bih = (const float*)d_in[14];
    const float* bhh = (const float*)d_in[15];
    const float* oww = (const float*)d_in[16];
    const float* obb = (const float*)d_in[17];
    const float* sww = (const float*)d_in[18];
    const float* sbb = (const float*)d_in[19];
    float* out = (float*)d_out;
    float* ws  = (float*)d_ws;

    // workspace (float offsets), ~42 MB
    unsigned short* xall_b = (unsigned short*)ws;                //  4,194,304 ush
    unsigned short* enc_b  = (unsigned short*)(ws + 2097152);    //  8,388,608 ush
    unsigned short* ep_b   = (unsigned short*)(ws + 6291456);    //  2,097,152 ush
    unsigned short* wgh    = (unsigned short*)(ws + 7340032);    //  3,145,728 ush
    unsigned short* wgx    = (unsigned short*)(ws + 8912896);    //    786,432 ush
    unsigned short* wgc    = (unsigned short*)(ws + 9306112);    //  1,572,864 ush
    unsigned short* ow_b   = (unsigned short*)(ws + 10092544);   //    196,608 ush
    float* h_f32 = ws + 10190848;                                //     32,768 f
    unsigned short* h_fb   = (unsigned short*)(ws + 10223616);   //     32,768 ush
    unsigned short* ctx_b  = (unsigned short*)(ws + 10240000);   //     65,536 ush
    float* den  = ws + 10272768;                                 //        128 f
    float* es_b = ws + 10272896;                                 //     32,768 f
    float* dpp  = ws + 10305664;                                 //    131,072 f
    unsigned* bar = (unsigned*)(ws + 10436736);                  //    512 u (grp[8*16] + root)

    hipMemsetAsync(h_f32, 0, 32768*4, stream);
    hipMemsetAsync(h_fb, 0, 32768*2, stream);
    hipMemsetAsync(dpp, 0, (size_t)131072*4, stream);
    hipMemsetAsync(bar, 0, 2048, stream);

    k_prep_w<<<55040, 256, 0, stream>>>(enc, whh, wih, oww,
                                        enc_b, wgh, wgx, wgc, ow_b);
    k_encproj<<<256, 256, 0, stream>>>(enc, awe, abe, ep_b);
    k_prenet<<<1024, 128, 0, stream>>>(tm, pw1, pb1, pw2, pb2, xall_b);

    hipFuncSetAttribute((const void*)k_persist,
                        hipFuncAttributeMaxDynamicSharedMemorySize, DYN_BYTES);

    KP kp;
    kp.xall_b = xall_b; kp.enc_b = enc_b; kp.ep_b = ep_b;
    kp.wgh = wgh; kp.wgx = wgx; kp.wgc = wgc; kp.ow_b = ow_b;
    kp.awd = awd; kp.sw = sww; kp.bd = abd; kp.av = av; kp.avb = avb;
    kp.bih = bih; kp.bhh = bhh; kp.p_ob = obb; kp.p_sb = sbb;
    kp.h_f32 = h_f32; kp.h_fb = h_fb;
    kp.ctx_b = ctx_b; kp.den = den; kp.es_b = es_b; kp.dpp = dpp;
    kp.grp = bar; kp.root = bar + 128; kp.out = out;

    KP* kparg = &kp;
    void* args[] = { (void*)kparg };
    hipLaunchCooperativeKernel((void*)k_persist, dim3(256), dim3(1024),
                               args, DYN_BYTES, stream);
}

// Round 11
// 16956.155 us; speedup vs baseline: 8.2057x; 1.0252x over previous
//
#include <hip/hip_runtime.h>

// Problem constants
constexpr int B_   = 32;
constexpr int S_   = 512;
constexpr int T_   = 512;
constexpr int ENC_ = 512;
constexpr int ATT_ = 128;
constexpr int PO_  = 256;
constexpr int DEC_ = 1024;
constexpr int M_   = 128;

// Output offsets (floats)
constexpr int MEL_OFF  = 0;
constexpr int STOP_OFF = B_*T_*M_;            // 2,097,152
constexpr int AW_OFF   = STOP_OFF + B_*T_;    // 2,113,536

typedef __attribute__((ext_vector_type(8))) short bf16x8;
typedef __attribute__((ext_vector_type(4))) float f32x4;
typedef unsigned long long ull;

__device__ __forceinline__ float frcp(float x){ return __builtin_amdgcn_rcpf(x); }
__device__ __forceinline__ float ftanh(float x){ float e = __expf(2.f*x); return 1.f - 2.f*frcp(e + 1.f); }
__device__ __forceinline__ float fsig(float x){ return frcp(1.f + __expf(-x)); }

__device__ __forceinline__ float2 upk2(unsigned u){
    return make_float2(__builtin_bit_cast(float, u << 16),
                       __builtin_bit_cast(float, u & 0xffff0000u));
}
__device__ __forceinline__ unsigned short f2b(float f){
    unsigned u = __builtin_bit_cast(unsigned, f);
    return (unsigned short)((u + 0x7fffu + ((u >> 16) & 1u)) >> 16);
}
__device__ __forceinline__ unsigned pk2(float a, float b){
    return (unsigned)f2b(a) | ((unsigned)f2b(b) << 16);
}

// ---- relaxed agent-scope (device-coherent) accessors (R3/R8-proven) ----------
__device__ __forceinline__ float ald(const float* p){
    return __hip_atomic_load(p, __ATOMIC_RELAXED, __HIP_MEMORY_SCOPE_AGENT);
}
__device__ __forceinline__ ull ald64(const void* p){
    return __hip_atomic_load((const ull*)p, __ATOMIC_RELAXED, __HIP_MEMORY_SCOPE_AGENT);
}
__device__ __forceinline__ unsigned aldu(const unsigned* p){
    return __hip_atomic_load(p, __ATOMIC_RELAXED, __HIP_MEMORY_SCOPE_AGENT);
}
__device__ __forceinline__ void astf(float* p, float v){
    __hip_atomic_store(p, v, __ATOMIC_RELAXED, __HIP_MEMORY_SCOPE_AGENT);
}
union F2U { float2 f; ull u; };
__device__ __forceinline__ void ast2f(float* p, float a, float b){
    F2U x; x.f = make_float2(a, b);
    __hip_atomic_store((ull*)p, x.u, __ATOMIC_RELAXED, __HIP_MEMORY_SCOPE_AGENT);
}
__device__ __forceinline__ void astu(unsigned* p, unsigned v){
    __hip_atomic_store(p, v, __ATOMIC_RELAXED, __HIP_MEMORY_SCOPE_AGENT);
}

// ---- hierarchical global barrier: NO cache fences (R3/R8 protocol) -----------
__device__ __forceinline__ void gbar2(unsigned* grp, unsigned* root, unsigned ep){
    asm volatile("s_waitcnt vmcnt(0) lgkmcnt(0)" ::: "memory");
    __syncthreads();
    if (threadIdx.x == 0){
        unsigned g = blockIdx.x >> 5;
        unsigned old = __hip_atomic_fetch_add(&grp[g*16], 1u, __ATOMIC_RELAXED, __HIP_MEMORY_SCOPE_AGENT);
        if (old == ep*32u - 1u)
            __hip_atomic_fetch_add(root, 1u, __ATOMIC_RELAXED, __HIP_MEMORY_SCOPE_AGENT);
        while (__hip_atomic_load(root, __ATOMIC_RELAXED, __HIP_MEMORY_SCOPE_AGENT) < ep*8u)
            __builtin_amdgcn_s_sleep(1);
    }
    __syncthreads();
}

__device__ __forceinline__ f32x4 mfma16(bf16x8 a, bf16x8 b, f32x4 c){
    return __builtin_amdgcn_mfma_f32_16x16x32_bf16(a, b, c, 0, 0, 0);
}

// ================= prep: staged layouts =================
// enc_b [32 b][2 half][256 s][512 e] bf16
// wgh   [32 ds][6 jc][32 kc][64 l][8 e]  (whh B-frags, full-K per ds)
// wgx   [32 ds][6 jc][8 kc][64 l][8 e]   (wih x-part B-frags)
// wgc   [32 ds][6 jc][16 kc][64 l][8 e]  (wih ctx-part B-frags)
// ow_b  [4 q][32 oc][1536 k] bf16
__global__ __launch_bounds__(256) void k_prep_w(const float* __restrict__ enc,
        const float* __restrict__ whh, const float* __restrict__ wih,
        const float* __restrict__ oww,
        unsigned short* __restrict__ enc_b, unsigned short* __restrict__ wgh,
        unsigned short* __restrict__ wgx, unsigned short* __restrict__ wgc,
        unsigned short* __restrict__ ow_b){
    long long idx = (long long)blockIdx.x*256 + threadIdx.x;
    if (idx < 8388608LL){
        int bh = (int)(idx >> 17); int r = (int)(idx & 131071);
        int s = r >> 9, e = r & 511;
        int b = bh >> 1, half = bh & 1;
        enc_b[idx] = f2b(enc[((size_t)b*S_ + half*256 + s)*ENC_ + e]);
    } else if (idx < 11534336LL){
        long long q = idx - 8388608LL;
        int ds = (int)(q / 98304); int r = (int)(q % 98304);
        int jc = r / 16384; int r2 = r % 16384;
        int kc = r2 >> 9, l = (r2 >> 3) & 63, e = r2 & 7;
        int j = (jc >> 1)*1024 + ds*32 + (jc & 1)*16 + (l & 15);
        int k = kc*32 + ((l >> 4) << 3) + e;
        wgh[q] = f2b(whh[(size_t)j*DEC_ + k]);
    } else if (idx < 12320768LL){
        long long q = idx - 11534336LL;
        int ds = (int)(q / 24576); int r = (int)(q % 24576);
        int jc = r / 4096; int r3 = r % 4096;
        int kc = r3 >> 9, l = (r3 >> 3) & 63, e = r3 & 7;
        int j = (jc >> 1)*1024 + ds*32 + (jc & 1)*16 + (l & 15);
        int k = kc*32 + ((l >> 4) << 3) + e;
        wgx[q] = f2b(wih[(size_t)j*768 + k]);
    } else if (idx < 13893632LL){
        long long q = idx - 12320768LL;
        int ds = (int)(q / 49152); int r = (int)(q % 49152);
        int jc = r / 8192; int r3 = r % 8192;
        int kc = r3 >> 9, l = (r3 >> 3) & 63, e = r3 & 7;
        int j = (jc >> 1)*1024 + ds*32 + (jc & 1)*16 + (l & 15);
        int k = kc*32 + ((l >> 4) << 3) + e;
        wgc[q] = f2b(wih[(size_t)j*768 + 256 + k]);
    } else if (idx < 14090240LL){
        long long q = idx - 13893632LL;
        int cg = (int)(q / 49152); int r = (int)(q % 49152);
        int oc = r / 1536, k = r % 1536;
        ow_b[q] = f2b(oww[(size_t)k*M_ + cg*32 + oc]);
    }
}

// ep_b[b][512 s][128 a] bf16 = enc @ att_we + be
__global__ __launch_bounds__(256) void k_encproj(const float* __restrict__ enc,
        const float* __restrict__ we, const float* __restrict__ be,
        unsigned short* __restrict__ ep_b){
    __shared__ float we_s[64*128];
    __shared__ float enc_s[64*64];
    int blk = blockIdx.x, tid = threadIdx.x;
    int b = blk >> 3, ss = blk & 7;
    int s = tid >> 2, ag = tid & 3;
    float acc[32];
    #pragma unroll
    for (int j = 0; j < 32; ++j) acc[j] = 0.f;
    for (int kc = 0; kc < 8; ++kc){
        __syncthreads();
        for (int i = tid; i < 8192; i += 256)
            we_s[i] = we[(size_t)(kc*64 + (i >> 7))*ATT_ + (i & 127)];
        for (int i = tid; i < 4096; i += 256)
            enc_s[i] = enc[((size_t)b*S_ + ss*64 + (i >> 6))*ENC_ + kc*64 + (i & 63)];
        __syncthreads();
        for (int kk = 0; kk < 64; ++kk){
            float ev = enc_s[s*64 + kk];
            const float* wr = &we_s[(kk << 7) + (ag << 5)];
            #pragma unroll
            for (int j = 0; j < 32; ++j) acc[j] += ev*wr[j];
        }
    }
    #pragma unroll
    for (int j = 0; j < 32; ++j){
        int a = (ag << 5) + j;
        ep_b[((size_t)b*512 + ss*64 + s)*ATT_ + a] = f2b(acc[j] + be[a]);
    }
}

// PreNet (f32 math, bf16 output)
__global__ __launch_bounds__(128) void k_prenet(const float* __restrict__ tm,
        const float* __restrict__ w1, const float* __restrict__ b1,
        const float* __restrict__ w2, const float* __restrict__ b2,
        unsigned short* __restrict__ xall){
    __shared__ float mel_l[128*20];
    __shared__ float h1_l[256*20];
    int row0 = blockIdx.x << 4;
    int t = row0 >> 5, b0 = row0 & 31;
    int tid = threadIdx.x;
    for (int p = 0; p < 16; p++){
        int idx = tid + (p << 7);
        int k = idx & 127, r = idx >> 7;
        float v = 0.f;
        if (t > 0) v = tm[((size_t)(b0 + r)*T_ + (t - 1))*M_ + k];
        mel_l[k*20 + r] = v;
    }
    __syncthreads();
    float acc1[16], acc2[16];
    #pragma unroll
    for (int i = 0; i < 16; i++){ acc1[i] = 0.f; acc2[i] = 0.f; }
    for (int k = 0; k < M_; k++){
        float wa = w1[k*256 + tid];
        float wb = w1[k*256 + tid + 128];
        float mv[16];
        *(float4*)&mv[0]  = *(const float4*)&mel_l[k*20 + 0];
        *(float4*)&mv[4]  = *(const float4*)&mel_l[k*20 + 4];
        *(float4*)&mv[8]  = *(const float4*)&mel_l[k*20 + 8];
        *(float4*)&mv[12] = *(const float4*)&mel_l[k*20 + 12];
        #pragma unroll
        for (int r = 0; r < 16; r++){ acc1[r] += mv[r]*wa; acc2[r] += mv[r]*wb; }
    }
    float bb1a = b1[tid], bb1b = b1[tid + 128];
    #pragma unroll
    for (int r = 0; r < 16; r++){
        h1_l[tid*20 + r]         = fmaxf(acc1[r] + bb1a, 0.f);
        h1_l[(tid + 128)*20 + r] = fmaxf(acc2[r] + bb1b, 0.f);
    }
    __syncthreads();
    #pragma unroll
    for (int i = 0; i < 16; i++){ acc1[i] = 0.f; acc2[i] = 0.f; }
    for (int k = 0; k < 256; k++){
        float wa = w2[k*256 + tid];
        float wb = w2[k*256 + tid + 128];
        float mv[16];
        *(float4*)&mv[0]  = *(const float4*)&h1_l[k*20 + 0];
        *(float4*)&mv[4]  = *(const float4*)&h1_l[k*20 + 4];
        *(float4*)&mv[8]  = *(const float4*)&h1_l[k*20 + 8];
        *(float4*)&mv[12] = *(const float4*)&h1_l[k*20 + 12];
        #pragma unroll
        for (int r = 0; r < 16; r++){ acc1[r] += mv[r]*wa; acc2[r] += mv[r]*wb; }
    }
    float bb2a = b2[tid], bb2b = b2[tid + 128];
    #pragma unroll
    for (int r = 0; r < 16; r++){
        xall[((size_t)row0 + r)*PO_ + tid]       = f2b(fmaxf(acc1[r] + bb2a, 0.f));
        xall[((size_t)row0 + r)*PO_ + tid + 128] = f2b(fmaxf(acc2[r] + bb2b, 0.f));
    }
}

// ================= persistent lockstep decoder =================
#define DYN_BYTES 110592

struct KP {
    const unsigned short* xall_b; const unsigned short* enc_b; const unsigned short* ep_b;
    const unsigned short* wgh; const unsigned short* wgx; const unsigned short* wgc;
    const unsigned short* ow_b;
    const float* awd; const float* sw; const float* bd; const float* av; const float* avb;
    const float* bih; const float* bhh; const float* p_ob; const float* p_sb;
    float* h_f32; unsigned short* h_fb;
    unsigned short* ctx_b; float* den; float* es_b; float* dpp;
    unsigned* grp; unsigned* root; float* out;
};

__global__ __launch_bounds__(1024) void k_persist(KP p){
    extern __shared__ char sm[];
    const int bid = blockIdx.x, tid = threadIdx.x;
    const int lane = tid & 63;
    unsigned epn = 0;
    unsigned* grp = p.grp; unsigned* root = p.root;

    if (bid < 64){
        // ======== GATE: XCD-affinity mapping (R11) ========
        // xcd = bid&7 (assumed round-robin block->XCD). All blocks of a ds —
        // and 4 consecutive ds — land on ONE XCD, so their wgh/wgx/wgc slices
        // (4 x 312 KB = 1.25 MB) stay L2-resident. Perf heuristic only.
        const int xcd = bid & 7, slot8 = bid >> 3;
        const int ds = xcd*4 + (slot8 >> 1), bh = slot8 & 1;
        unsigned short* hf_b = (unsigned short*)sm;            // ph1 32KB (alias cf)
        char* cf = sm;                                         // ph2 ctx frags 16KB
        float* pgh_l = (float*)(sm + 32768);                   // [2*16][100]
        float* pgx_l = (float*)(sm + 45568);                   // [2*16][100]
        float* pgc_l = (float*)(sm + 58368);                   // [2*16][100]
        float* h_l   = (float*)(sm + 71168);                   // [16][32]
        float* rden_l= (float*)(sm + 73216);                   // 16 f
        float h_reg = 0.f;

        for (int t = 0; t <= T_; ++t){
            // ---------- phase 1: full-K gh + gix MFMA, partials stay in LDS ---
            if (t < T_){
                const ull* shb = (const ull*)p.h_fb;
                for (int i = tid; i < 4096; i += 1024){
                    int u = i & 1, l = (i >> 1) & 63, kc = i >> 7;   // kc 0..31
                    ((ull*)hf_b)[i] = ald64(&shb[(((size_t)bh*32 + kc)*64 + l)*2 + u]);
                }
                __syncthreads();
                int w = tid >> 6;
                if (w < 12){
                    int jc = w >> 1, kg = w & 1;
                    int r4 = lane >> 4, c16 = lane & 15;
                    const bf16x8* Bh = (const bf16x8*)p.wgh +
                        ((size_t)(ds*6 + jc)*32)*64 + lane;
                    f32x4 acc = {0.f,0.f,0.f,0.f};
                    #pragma unroll
                    for (int c = 0; c < 16; ++c){
                        int kc = kg*16 + c;
                        bf16x8 a = *(const bf16x8*)(hf_b + ((kc*64 + lane) << 3));
                        acc = mfma16(a, Bh[kc*64], acc);
                    }
                    #pragma unroll
                    for (int r = 0; r < 4; ++r)
                        pgh_l[(kg*16 + r4*4 + r)*100 + jc*16 + c16] = acc[r];
                    const bf16x8* Xp = (const bf16x8*)p.wgx +
                        ((size_t)(ds*6 + jc)*8)*64 + lane;
                    f32x4 ax = {0.f,0.f,0.f,0.f};
                    #pragma unroll
                    for (int c = 0; c < 4; ++c){
                        int kc = kg*4 + c;
                        bf16x8 a = *(const bf16x8*)(p.xall_b +
                            ((size_t)t*32 + bh*16 + c16)*256 + kc*32 + r4*8);
                        ax = mfma16(a, Xp[kc*64], ax);
                    }
                    #pragma unroll
                    for (int r = 0; r < 4; ++r)
                        pgx_l[(kg*16 + r4*4 + r)*100 + jc*16 + c16] = ax[r];
                }
            }
            gbar2(grp, root, ++epn);
            // ---------- phase 2: gic MFMA + gates + h + dpp -------------------
            if (t < T_){
                const int slot = t & 1;
                if (tid < 16){
                    int b = bh*16 + tid;
                    rden_l[tid] = frcp(ald(&p.den[slot*64 + b]) +
                                       ald(&p.den[slot*64 + 32 + b]));
                }
                __syncthreads();
                {   // stage normalized ctx as bf16 A-frags (1024 uint4s, i=tid)
                    int i = tid;
                    int kc = i >> 6, l = i & 63;
                    int b = bh*16 + (l & 15);
                    int e0 = kc*32 + ((l >> 4) << 3);
                    const ull* c0 = (const ull*)p.ctx_b + (((size_t)slot*2 + 0)*32 + b)*128 + (e0 >> 2);
                    const ull* c1 = (const ull*)p.ctx_b + (((size_t)slot*2 + 1)*32 + b)*128 + (e0 >> 2);
                    ull u00 = ald64(c0), u01 = ald64(c0 + 1);
                    ull u10 = ald64(c1), u11 = ald64(c1 + 1);
                    float rd = rden_l[l & 15];
                    uint2 x0 = __builtin_bit_cast(uint2, u00);
                    uint2 x1 = __builtin_bit_cast(uint2, u01);
                    uint2 y0 = __builtin_bit_cast(uint2, u10);
                    uint2 y1 = __builtin_bit_cast(uint2, u11);
                    float2 a0 = upk2(x0.x), b0 = upk2(y0.x);
                    float2 a1 = upk2(x0.y), b1 = upk2(y0.y);
                    float2 a2 = upk2(x1.x), b2 = upk2(y1.x);
                    float2 a3 = upk2(x1.y), b3 = upk2(y1.y);
                    unsigned w0 = pk2((a0.x + b0.x)*rd, (a0.y + b0.y)*rd);
                    unsigned w1 = pk2((a1.x + b1.x)*rd, (a1.y + b1.y)*rd);
                    unsigned w2 = pk2((a2.x + b2.x)*rd, (a2.y + b2.y)*rd);
                    unsigned w3 = pk2((a3.x + b3.x)*rd, (a3.y + b3.y)*rd);
                    *(uint4*)(cf + (size_t)i*16) = make_uint4(w0, w1, w2, w3);
                }
                __syncthreads();
                int w = tid >> 6;
                if (w < 12){
                    int jc = w >> 1, kg = w & 1;
                    int r4 = lane >> 4, c16 = lane & 15;
                    const bf16x8* Cp = (const bf16x8*)p.wgc +
                        ((size_t)(ds*6 + jc)*16)*64 + lane;
                    f32x4 acc = {0.f,0.f,0.f,0.f};
                    #pragma unroll
                    for (int c = 0; c < 8; ++c){
                        int kc = kg*8 + c;
                        bf16x8 a = *(const bf16x8*)(cf + ((kc*64 + lane) << 4));
                        acc = mfma16(a, Cp[kc*64], acc);
                    }
                    #pragma unroll
                    for (int r = 0; r < 4; ++r)
                        pgc_l[(kg*16 + r4*4 + r)*100 + jc*16 + c16] = acc[r];
                }
                __syncthreads();
                if (tid < 512){
                    int b16 = tid >> 5, dl = tid & 31;
                    int dglob = ds*32 + dl;
                    const float* pa = pgh_l + b16*100;
                    const float* pb = pgh_l + (16 + b16)*100;
                    const float* xa = pgx_l + b16*100;
                    const float* xb = pgx_l + (16 + b16)*100;
                    const float* ca = pgc_l + b16*100;
                    const float* cb = pgc_l + (16 + b16)*100;
                    float gi_r = xa[dl]      + xb[dl]      + ca[dl]      + cb[dl]      + p.bih[dglob];
                    float gi_z = xa[32 + dl] + xb[32 + dl] + ca[32 + dl] + cb[32 + dl] + p.bih[1024 + dglob];
                    float gi_n = xa[64 + dl] + xb[64 + dl] + ca[64 + dl] + cb[64 + dl] + p.bih[2048 + dglob];
                    float gh_r = pa[dl]      + pb[dl]      + p.bhh[dglob];
                    float gh_z = pa[32 + dl] + pb[32 + dl] + p.bhh[1024 + dglob];
                    float gh_n = pa[64 + dl] + pb[64 + dl] + p.bhh[2048 + dglob];
                    float rr = fsig(gi_r + gh_r);
                    float zz = fsig(gi_z + gh_z);
                    float nn = ftanh(gi_n + rr*gh_n);
                    float hv = (1.f - zz)*nn + zz*h_reg;
                    h_reg = hv;
                    h_l[b16*32 + dl] = hv;
                    float hv1 = __shfl_xor(hv, 1);
                    if (!(dl & 1)){
                        int b = bh*16 + b16;
                        ast2f(&p.h_f32[(size_t)b*1024 + dglob], hv, hv1);
                        unsigned pkv = pk2(hv, hv1);
                        int l2 = ((dl >> 3) << 4) + b16;
                        size_t fo = (((size_t)bh*32 + ds)*64 + l2)*4 + ((dl & 7) >> 1);
                        astu((unsigned*)p.h_fb + fo, pkv);
                    }
                }
                __syncthreads();
                {   // dproj partials (pure f32) over this block's 32 d, 16 b
                    int b16 = tid >> 6, ag = tid & 63;
                    int a0 = ag*2;
                    const float* ar = p.awd + (size_t)(ds*32)*128 + a0;
                    float s0 = 0.f, s1 = 0.f;
                    #pragma unroll 8
                    for (int dl = 0; dl < 32; ++dl){
                        float hd = h_l[b16*32 + dl];
                        float2 w2 = *(const float2*)(ar + (size_t)dl*128);
                        s0 += hd*w2.x; s1 += hd*w2.y;
                    }
                    ast2f(&p.dpp[(((size_t)ds*2 + bh)*16 + b16)*128 + a0], s0, s1);
                }
            }
            gbar2(grp, root, ++epn);
        }
    } else if (bid < 128){
        // ================= ATT (b, half) =================
        const int aa = bid - 64, b = aa >> 1, half = aa & 1;
        unsigned short* ep_l = (unsigned short*)sm;          // 65536
        float* red  = (float*)(sm + 65536);                  // [16][522] 33408
        float* sred = (float*)(sm + 98944);                  // 4096
        float* dpl  = (float*)(sm + 103040);                 // 512
        float* avl  = (float*)(sm + 103552);                 // 512
        float* esl  = (float*)(sm + 104064);                 // 1024
        {
            const ull* src = (const ull*)(p.ep_b + ((size_t)b*512 + half*256)*128);
            for (int i = tid; i < 8192; i += 1024) ((ull*)ep_l)[i] = src[i];
            if (tid < 128) avl[tid] = p.av[tid];
        }
        __syncthreads();
        for (int t = 0; t <= T_; ++t){
            if (t < T_){
                const int slot = t & 1;
                {   // dproj = sum of 64 (ds,bh) GATE partials matching this b
                    int a = tid & 127, g = tid >> 7;
                    const int bhb = b >> 4, b15 = b & 15;
                    float s = 0.f;
                    #pragma unroll
                    for (int i = 0; i < 4; ++i){
                        int ds2 = g*4 + i;
                        s += ald(&p.dpp[(((size_t)ds2*2 + bhb)*16 + b15)*128 + a]);
                    }
                    red[g*128 + a] = s;
                }
                __syncthreads();
                if (tid < 128){
                    float s = p.bd[tid];
                    #pragma unroll
                    for (int g = 0; g < 8; ++g) s += red[g*128 + tid];
                    dpl[tid] = s;
                }
                __syncthreads();
                {
                    int s = tid >> 2, ao = tid & 3;
                    const unsigned* er = (const unsigned*)ep_l + s*64 + ao*16;
                    float sc = 0.f;
                    #pragma unroll
                    for (int i = 0; i < 16; ++i){
                        float2 e2 = upk2(er[i]);
                        int a0 = ao*32 + i*2;
                        sc += ftanh(e2.x + dpl[a0])*avl[a0]
                            + ftanh(e2.y + dpl[a0+1])*avl[a0+1];
                    }
                    sred[tid] = sc;
                }
                __syncthreads();
                if (tid < 256){
                    float sc = sred[tid*4] + sred[tid*4+1] + sred[tid*4+2] + sred[tid*4+3] + p.avb[0];
                    float ev = __expf(sc);
                    esl[tid] = ev;
                    astf(&p.es_b[(size_t)slot*16384 + b*512 + half*256 + tid], ev);
                }
                __syncthreads();
                if (tid < 64){
                    float d = esl[tid*4] + esl[tid*4+1] + esl[tid*4+2] + esl[tid*4+3];
                    #pragma unroll
                    for (int m = 1; m <= 32; m <<= 1) d += __shfl_xor(d, m);
                    if (tid == 0) astf(&p.den[slot*64 + half*32 + b], d);
                }
                {
                    int eo = tid >> 4, sg = tid & 15;
                    int e8 = eo*8;
                    const unsigned short* eb = p.enc_b + ((size_t)b*2 + half)*131072;
                    float a0=0,a1=0,a2=0,a3=0,a4=0,a5=0,a6=0,a7=0;
                    #pragma unroll 4
                    for (int i = 0; i < 16; ++i){
                        int s = sg*16 + i;
                        float ev = esl[s];
                        uint4 u = *(const uint4*)(eb + (size_t)s*512 + e8);
                        float2 v0=upk2(u.x), v1=upk2(u.y), v2=upk2(u.z), v3=upk2(u.w);
                        a0+=ev*v0.x; a1+=ev*v0.y; a2+=ev*v1.x; a3+=ev*v1.y;
                        a4+=ev*v2.x; a5+=ev*v2.y; a6+=ev*v3.x; a7+=ev*v3.y;
                    }
                    float* rr = &red[sg*522 + e8];
                    rr[0]=a0; rr[1]=a1; rr[2]=a2; rr[3]=a3;
                    rr[4]=a4; rr[5]=a5; rr[6]=a6; rr[7]=a7;
                }
                __syncthreads();
                if (tid < 512){
                    float c = 0.f;
                    #pragma unroll
                    for (int sg = 0; sg < 16; ++sg) c += red[sg*522 + tid];
                    float c1 = __shfl_xor(c, 1);
                    if (!(tid & 1))
                        astu((unsigned*)p.ctx_b + (((size_t)slot*2 + half)*32 + b)*256 + (tid >> 1),
                             pk2(c, c1));
                }
            }
            gbar2(grp, root, ++epn);
            gbar2(grp, root, ++epn);
        }
    } else {
        // ================= MEL (b, q) =================
        const int m = bid - 128, b = m >> 2, q = m & 3;
        unsigned short* ow_l = (unsigned short*)sm;   // [32 oc][1538] = 98432B
        float* dout = (float*)(sm + 98432);           // 1536 f
        float* redm = (float*)(sm + 104576);          // [32][33]
        float* rdm  = (float*)(sm + 108800);
        float* stpr = (float*)(sm + 108816);          // 8 f
        {
            const ull* src = (const ull*)p.ow_b + (size_t)q*12288;
            for (int i = tid; i < 12288; i += 1024){
                int oc = i / 384, kq = i - oc*384;
                uint2 u = __builtin_bit_cast(uint2, src[i]);
                unsigned* d = (unsigned*)ow_l + (size_t)oc*769 + kq*2;
                d[0] = u.x; d[1] = u.y;
            }
        }
        __syncthreads();
        for (int t = 0; t <= T_; ++t){
            if (t >= 1){
                const int slot = (t - 1) & 1;
                if (tid < 512){
                    ull u = ald64((const ull*)p.h_f32 + (size_t)b*512 + tid);
                    *(float2*)&dout[tid*2] = __builtin_bit_cast(float2, u);
                } else if (tid < 768){
                    int i = tid - 512;
                    unsigned u0 = aldu((const unsigned*)p.ctx_b + (((size_t)slot*2 + 0)*32 + b)*256 + i);
                    unsigned u1 = aldu((const unsigned*)p.ctx_b + (((size_t)slot*2 + 1)*32 + b)*256 + i);
                    float2 f0 = upk2(u0), f1 = upk2(u1);
                    *(float2*)&dout[1024 + i*2] = make_float2(f0.x + f1.x, f0.y + f1.y);
                } else if (tid == 1023){
                    rdm[0] = frcp(ald(&p.den[slot*64 + b]) + ald(&p.den[slot*64 + 32 + b]));
                }
                __syncthreads();
                if (tid < 512) dout[1024 + tid] *= rdm[0];
                __syncthreads();
                {
                    int kg = tid >> 5, oc = tid & 31;
                    const unsigned* wr = (const unsigned*)ow_l + (size_t)oc*769 + kg*24;
                    const float* dr = dout + kg*48;
                    float a = 0.f;
                    #pragma unroll 6
                    for (int i = 0; i < 24; ++i){
                        float2 w2 = upk2(wr[i]);
                        a += dr[i*2]*w2.x + dr[i*2+1]*w2.y;
                    }
                    redm[kg*33 + oc] = a;
                }
                if (q == 0 && tid < 512){
                    int k3 = tid*3;
                    float s = dout[k3]*p.sw[k3] + dout[k3+1]*p.sw[k3+1] + dout[k3+2]*p.sw[k3+2];
                    #pragma unroll
                    for (int mm = 1; mm <= 32; mm <<= 1) s += __shfl_xor(s, mm);
                    if ((tid & 63) == 0) stpr[tid >> 6] = s;
                    float ev = ald(&p.es_b[(size_t)slot*16384 + b*512 + tid]);
                    p.out[AW_OFF + ((size_t)b*T_ + (t-1))*S_ + tid] = ev*rdm[0];
                }
                __syncthreads();
                if (tid < 32){
                    float a = 0.f;
                    #pragma unroll
                    for (int kg = 0; kg < 32; ++kg) a += redm[kg*33 + tid];
                    int c = q*32 + tid;
                    p.out[MEL_OFF + ((size_t)b*T_ + (t-1))*M_ + c] = a + p.p_ob[c];
                } else if (tid == 32 && q == 0){
                    float tot = 0.f;
                    #pragma unroll
                    for (int w2 = 0; w2 < 8; ++w2) tot += stpr[w2];
                    p.out[STOP_OFF + (size_t)b*T_ + (t-1)] = tot + p.p_sb[0];
                }
            }
            gbar2(grp, root, ++epn);
            gbar2(grp, root, ++epn);
        }
    }
}

extern "C" void kernel_launch(void* const* d_in, const int* in_sizes, int n_in,
                              void* d_out, int out_size, void* d_ws, size_t ws_size,
                              hipStream_t stream){
    const float* enc = (const float*)d_in[0];
    const float* tm  = (const float*)d_in[1];
    const float* pw1 = (const float*)d_in[2];
    const float* pb1 = (const float*)d_in[3];
    const float* pw2 = (const float*)d_in[4];
    const float* pb2 = (const float*)d_in[5];
    const float* awe = (const float*)d_in[6];
    const float* abe = (const float*)d_in[7];
    const float* awd = (const float*)d_in[8];
    const float* abd = (const float*)d_in[9];
    const float* av  = (const float*)d_in[10];
    const float* avb = (const float*)d_in[11];
    const float* wih = (const float*)d_in[12];
    const float* whh = (const float*)d_in[13];
    const float* bih = (const float*)d_in[14];
    const float* bhh = (const float*)d_in[15];
    const float* oww = (const float*)d_in[16];
    const float* obb = (const float*)d_in[17];
    const float* sww = (const float*)d_in[18];
    const float* sbb = (const float*)d_in[19];
    float* out = (float*)d_out;
    float* ws  = (float*)d_ws;

    // workspace (float offsets), ~42 MB
    unsigned short* xall_b = (unsigned short*)ws;                //  4,194,304 ush
    unsigned short* enc_b  = (unsigned short*)(ws + 2097152);    //  8,388,608 ush
    unsigned short* ep_b   = (unsigned short*)(ws + 6291456);    //  2,097,152 ush
    unsigned short* wgh    = (unsigned short*)(ws + 7340032);    //  3,145,728 ush
    unsigned short* wgx    = (unsigned short*)(ws + 8912896);    //    786,432 ush
    unsigned short* wgc    = (unsigned short*)(ws + 9306112);    //  1,572,864 ush
    unsigned short* ow_b   = (unsigned short*)(ws + 10092544);   //    196,608 ush
    float* h_f32 = ws + 10190848;                                //     32,768 f
    unsigned short* h_fb   = (unsigned short*)(ws + 10223616);   //     32,768 ush
    unsigned short* ctx_b  = (unsigned short*)(ws + 10240000);   //     65,536 ush
    float* den  = ws + 10272768;                                 //        128 f
    float* es_b = ws + 10272896;                                 //     32,768 f
    float* dpp  = ws + 10305664;                                 //    131,072 f
    unsigned* bar = (unsigned*)(ws + 10436736);                  //    512 u (grp[8*16] + root)

    hipMemsetAsync(h_f32, 0, 32768*4, stream);
    hipMemsetAsync(h_fb, 0, 32768*2, stream);
    hipMemsetAsync(dpp, 0, (size_t)131072*4, stream);
    hipMemsetAsync(bar, 0, 2048, stream);

    k_prep_w<<<55040, 256, 0, stream>>>(enc, whh, wih, oww,
                                        enc_b, wgh, wgx, wgc, ow_b);
    k_encproj<<<256, 256, 0, stream>>>(enc, awe, abe, ep_b);
    k_prenet<<<1024, 128, 0, stream>>>(tm, pw1, pb1, pw2, pb2, xall_b);

    hipFuncSetAttribute((const void*)k_persist,
                        hipFuncAttributeMaxDynamicSharedMemorySize, DYN_BYTES);

    KP kp;
    kp.xall_b = xall_b; kp.enc_b = enc_b; kp.ep_b = ep_b;
    kp.wgh = wgh; kp.wgx = wgx; kp.wgc = wgc; kp.ow_b = ow_b;
    kp.awd = awd; kp.sw = sww; kp.bd = abd; kp.av = av; kp.avb = avb;
    kp.bih = bih; kp.bhh = bhh; kp.p_ob = obb; kp.p_sb = sbb;
    kp.h_f32 = h_f32; kp.h_fb = h_fb;
    kp.ctx_b = ctx_b; kp.den = den; kp.es_b = es_b; kp.dpp = dpp;
    kp.grp = bar; kp.root = bar + 128; kp.out = out;

    KP* kparg = &kp;
    void* args[] = { (void*)kparg };
    hipLaunchCooperativeKernel((void*)k_persist, dim3(256), dim3(1024),
                               args, DYN_BYTES, stream);
}

// Round 12
// 15676.120 us; speedup vs baseline: 8.8758x; 1.0817x over previous
//
#include <hip/hip_runtime.h>

// Problem constants
constexpr int B_   = 32;
constexpr int S_   = 512;
constexpr int T_   = 512;
constexpr int ENC_ = 512;
constexpr int ATT_ = 128;
constexpr int PO_  = 256;
constexpr int DEC_ = 1024;
constexpr int M_   = 128;

// Output offsets (floats)
constexpr int MEL_OFF  = 0;
constexpr int STOP_OFF = B_*T_*M_;            // 2,097,152
constexpr int AW_OFF   = STOP_OFF + B_*T_;    // 2,113,536

typedef __attribute__((ext_vector_type(8))) short bf16x8;
typedef __attribute__((ext_vector_type(4))) float f32x4;
typedef unsigned long long ull;

__device__ __forceinline__ float frcp(float x){ return __builtin_amdgcn_rcpf(x); }
__device__ __forceinline__ float ftanh(float x){ float e = __expf(2.f*x); return 1.f - 2.f*frcp(e + 1.f); }
__device__ __forceinline__ float fsig(float x){ return frcp(1.f + __expf(-x)); }

__device__ __forceinline__ float2 upk2(unsigned u){
    return make_float2(__builtin_bit_cast(float, u << 16),
                       __builtin_bit_cast(float, u & 0xffff0000u));
}
__device__ __forceinline__ unsigned short f2b(float f){
    unsigned u = __builtin_bit_cast(unsigned, f);
    return (unsigned short)((u + 0x7fffu + ((u >> 16) & 1u)) >> 16);
}
__device__ __forceinline__ unsigned pk2(float a, float b){
    return (unsigned)f2b(a) | ((unsigned)f2b(b) << 16);
}

// ---- relaxed agent-scope (device-coherent) accessors (R3/R8-proven) ----------
__device__ __forceinline__ float ald(const float* p){
    return __hip_atomic_load(p, __ATOMIC_RELAXED, __HIP_MEMORY_SCOPE_AGENT);
}
__device__ __forceinline__ ull ald64(const void* p){
    return __hip_atomic_load((const ull*)p, __ATOMIC_RELAXED, __HIP_MEMORY_SCOPE_AGENT);
}
__device__ __forceinline__ unsigned aldu(const unsigned* p){
    return __hip_atomic_load(p, __ATOMIC_RELAXED, __HIP_MEMORY_SCOPE_AGENT);
}
__device__ __forceinline__ void astf(float* p, float v){
    __hip_atomic_store(p, v, __ATOMIC_RELAXED, __HIP_MEMORY_SCOPE_AGENT);
}
union F2U { float2 f; ull u; };
__device__ __forceinline__ void ast2f(float* p, float a, float b){
    F2U x; x.f = make_float2(a, b);
    __hip_atomic_store((ull*)p, x.u, __ATOMIC_RELAXED, __HIP_MEMORY_SCOPE_AGENT);
}
__device__ __forceinline__ void astu(unsigned* p, unsigned v){
    __hip_atomic_store(p, v, __ATOMIC_RELAXED, __HIP_MEMORY_SCOPE_AGENT);
}

// ---- flat flag-array global barrier: NO fences, NO RMW (R3/R8 drain protocol)
// Each block stores its own flag (private 64B line); wave 0 of every block
// polls all 256 flags in parallel (4/lane) and min-checks. One-RT detection.
__device__ __forceinline__ void gbarF(unsigned* flags, unsigned ep){
    asm volatile("s_waitcnt vmcnt(0) lgkmcnt(0)" ::: "memory");
    __syncthreads();
    if (threadIdx.x == 0) astu(&flags[blockIdx.x*16], ep);
    if (threadIdx.x < 64){
        for (;;){
            unsigned m = 0xffffffffu;
            #pragma unroll
            for (int q = 0; q < 4; ++q){
                unsigned f = aldu(&flags[(threadIdx.x*4 + q)*16]);
                m = f < m ? f : m;
            }
            if (__all(m >= ep)) break;
            __builtin_amdgcn_s_sleep(1);
        }
    }
    __syncthreads();
}

__device__ __forceinline__ f32x4 mfma16(bf16x8 a, bf16x8 b, f32x4 c){
    return __builtin_amdgcn_mfma_f32_16x16x32_bf16(a, b, c, 0, 0, 0);
}

// ================= prep: staged layouts =================
// enc_b [32 b][2 half][256 s][512 e] bf16
// wgh   [32 ds][6 jc][32 kc][64 l][8 e]  (whh B-frags, full-K per ds)
// wgx   [32 ds][6 jc][8 kc][64 l][8 e]   (wih x-part B-frags)
// wgc   [32 ds][6 jc][16 kc][64 l][8 e]  (wih ctx-part B-frags)
// ow_b  [4 q][32 oc][1536 k] bf16
__global__ __launch_bounds__(256) void k_prep_w(const float* __restrict__ enc,
        const float* __restrict__ whh, const float* __restrict__ wih,
        const float* __restrict__ oww,
        unsigned short* __restrict__ enc_b, unsigned short* __restrict__ wgh,
        unsigned short* __restrict__ wgx, unsigned short* __restrict__ wgc,
        unsigned short* __restrict__ ow_b){
    long long idx = (long long)blockIdx.x*256 + threadIdx.x;
    if (idx < 8388608LL){
        int bh = (int)(idx >> 17); int r = (int)(idx & 131071);
        int s = r >> 9, e = r & 511;
        int b = bh >> 1, half = bh & 1;
        enc_b[idx] = f2b(enc[((size_t)b*S_ + half*256 + s)*ENC_ + e]);
    } else if (idx < 11534336LL){
        long long q = idx - 8388608LL;
        int ds = (int)(q / 98304); int r = (int)(q % 98304);
        int jc = r / 16384; int r2 = r % 16384;
        int kc = r2 >> 9, l = (r2 >> 3) & 63, e = r2 & 7;
        int j = (jc >> 1)*1024 + ds*32 + (jc & 1)*16 + (l & 15);
        int k = kc*32 + ((l >> 4) << 3) + e;
        wgh[q] = f2b(whh[(size_t)j*DEC_ + k]);
    } else if (idx < 12320768LL){
        long long q = idx - 11534336LL;
        int ds = (int)(q / 24576); int r = (int)(q % 24576);
        int jc = r / 4096; int r3 = r % 4096;
        int kc = r3 >> 9, l = (r3 >> 3) & 63, e = r3 & 7;
        int j = (jc >> 1)*1024 + ds*32 + (jc & 1)*16 + (l & 15);
        int k = kc*32 + ((l >> 4) << 3) + e;
        wgx[q] = f2b(wih[(size_t)j*768 + k]);
    } else if (idx < 13893632LL){
        long long q = idx - 12320768LL;
        int ds = (int)(q / 49152); int r = (int)(q % 49152);
        int jc = r / 8192; int r3 = r % 8192;
        int kc = r3 >> 9, l = (r3 >> 3) & 63, e = r3 & 7;
        int j = (jc >> 1)*1024 + ds*32 + (jc & 1)*16 + (l & 15);
        int k = kc*32 + ((l >> 4) << 3) + e;
        wgc[q] = f2b(wih[(size_t)j*768 + 256 + k]);
    } else if (idx < 14090240LL){
        long long q = idx - 13893632LL;
        int cg = (int)(q / 49152); int r = (int)(q % 49152);
        int oc = r / 1536, k = r % 1536;
        ow_b[q] = f2b(oww[(size_t)k*M_ + cg*32 + oc]);
    }
}

// ep_b[b][512 s][128 a] bf16 = enc @ att_we + be
__global__ __launch_bounds__(256) void k_encproj(const float* __restrict__ enc,
        const float* __restrict__ we, const float* __restrict__ be,
        unsigned short* __restrict__ ep_b){
    __shared__ float we_s[64*128];
    __shared__ float enc_s[64*64];
    int blk = blockIdx.x, tid = threadIdx.x;
    int b = blk >> 3, ss = blk & 7;
    int s = tid >> 2, ag = tid & 3;
    float acc[32];
    #pragma unroll
    for (int j = 0; j < 32; ++j) acc[j] = 0.f;
    for (int kc = 0; kc < 8; ++kc){
        __syncthreads();
        for (int i = tid; i < 8192; i += 256)
            we_s[i] = we[(size_t)(kc*64 + (i >> 7))*ATT_ + (i & 127)];
        for (int i = tid; i < 4096; i += 256)
            enc_s[i] = enc[((size_t)b*S_ + ss*64 + (i >> 6))*ENC_ + kc*64 + (i & 63)];
        __syncthreads();
        for (int kk = 0; kk < 64; ++kk){
            float ev = enc_s[s*64 + kk];
            const float* wr = &we_s[(kk << 7) + (ag << 5)];
            #pragma unroll
            for (int j = 0; j < 32; ++j) acc[j] += ev*wr[j];
        }
    }
    #pragma unroll
    for (int j = 0; j < 32; ++j){
        int a = (ag << 5) + j;
        ep_b[((size_t)b*512 + ss*64 + s)*ATT_ + a] = f2b(acc[j] + be[a]);
    }
}

// PreNet (f32 math, bf16 output)
__global__ __launch_bounds__(128) void k_prenet(const float* __restrict__ tm,
        const float* __restrict__ w1, const float* __restrict__ b1,
        const float* __restrict__ w2, const float* __restrict__ b2,
        unsigned short* __restrict__ xall){
    __shared__ float mel_l[128*20];
    __shared__ float h1_l[256*20];
    int row0 = blockIdx.x << 4;
    int t = row0 >> 5, b0 = row0 & 31;
    int tid = threadIdx.x;
    for (int p = 0; p < 16; p++){
        int idx = tid + (p << 7);
        int k = idx & 127, r = idx >> 7;
        float v = 0.f;
        if (t > 0) v = tm[((size_t)(b0 + r)*T_ + (t - 1))*M_ + k];
        mel_l[k*20 + r] = v;
    }
    __syncthreads();
    float acc1[16], acc2[16];
    #pragma unroll
    for (int i = 0; i < 16; i++){ acc1[i] = 0.f; acc2[i] = 0.f; }
    for (int k = 0; k < M_; k++){
        float wa = w1[k*256 + tid];
        float wb = w1[k*256 + tid + 128];
        float mv[16];
        *(float4*)&mv[0]  = *(const float4*)&mel_l[k*20 + 0];
        *(float4*)&mv[4]  = *(const float4*)&mel_l[k*20 + 4];
        *(float4*)&mv[8]  = *(const float4*)&mel_l[k*20 + 8];
        *(float4*)&mv[12] = *(const float4*)&mel_l[k*20 + 12];
        #pragma unroll
        for (int r = 0; r < 16; r++){ acc1[r] += mv[r]*wa; acc2[r] += mv[r]*wb; }
    }
    float bb1a = b1[tid], bb1b = b1[tid + 128];
    #pragma unroll
    for (int r = 0; r < 16; r++){
        h1_l[tid*20 + r]         = fmaxf(acc1[r] + bb1a, 0.f);
        h1_l[(tid + 128)*20 + r] = fmaxf(acc2[r] + bb1b, 0.f);
    }
    __syncthreads();
    #pragma unroll
    for (int i = 0; i < 16; i++){ acc1[i] = 0.f; acc2[i] = 0.f; }
    for (int k = 0; k < 256; k++){
        float wa = w2[k*256 + tid];
        float wb = w2[k*256 + tid + 128];
        float mv[16];
        *(float4*)&mv[0]  = *(const float4*)&h1_l[k*20 + 0];
        *(float4*)&mv[4]  = *(const float4*)&h1_l[k*20 + 4];
        *(float4*)&mv[8]  = *(const float4*)&h1_l[k*20 + 8];
        *(float4*)&mv[12] = *(const float4*)&h1_l[k*20 + 12];
        #pragma unroll
        for (int r = 0; r < 16; r++){ acc1[r] += mv[r]*wa; acc2[r] += mv[r]*wb; }
    }
    float bb2a = b2[tid], bb2b = b2[tid + 128];
    #pragma unroll
    for (int r = 0; r < 16; r++){
        xall[((size_t)row0 + r)*PO_ + tid]       = f2b(fmaxf(acc1[r] + bb2a, 0.f));
        xall[((size_t)row0 + r)*PO_ + tid + 128] = f2b(fmaxf(acc2[r] + bb2b, 0.f));
    }
}

// ================= persistent lockstep decoder =================
#define DYN_BYTES 110592

struct KP {
    const unsigned short* xall_b; const unsigned short* enc_b; const unsigned short* ep_b;
    const unsigned short* wgh; const unsigned short* wgx; const unsigned short* wgc;
    const unsigned short* ow_b;
    const float* awd; const float* sw; const float* bd; const float* av; const float* avb;
    const float* bih; const float* bhh; const float* p_ob; const float* p_sb;
    float* h_f32; unsigned short* h_fb;
    unsigned short* ctx_b; float* den; float* es_b; float* dpp;
    unsigned* flags; float* out;
};

__global__ __launch_bounds__(1024) void k_persist(KP p){
    extern __shared__ char sm[];
    const int bid = blockIdx.x, tid = threadIdx.x;
    const int lane = tid & 63;
    unsigned epn = 0;
    unsigned* flags = p.flags;

    if (bid < 64){
        // ======== GATE: XCD-affinity mapping (R11-proven) ========
        const int xcd = bid & 7, slot8 = bid >> 3;
        const int ds = xcd*4 + (slot8 >> 1), bh = slot8 & 1;
        unsigned short* hf_b = (unsigned short*)sm;            // ph1 32KB (alias cf)
        char* cf = sm;                                         // ph2 ctx frags 16KB
        float* pgh_l = (float*)(sm + 32768);                   // [2*16][100]
        float* pgx_l = (float*)(sm + 45568);                   // [2*16][100]
        float* pgc_l = (float*)(sm + 58368);                   // [2*16][100]
        float* h_l   = (float*)(sm + 71168);                   // [16][32]
        float* rden_l= (float*)(sm + 73216);                   // 16 f
        float h_reg = 0.f;

        for (int t = 0; t <= T_; ++t){
            // ---------- region 1: full-K gh + gix MFMA, partials in LDS -------
            if (t < T_){
                const ull* shb = (const ull*)p.h_fb;
                for (int i = tid; i < 4096; i += 1024){
                    int u = i & 1, l = (i >> 1) & 63, kc = i >> 7;   // kc 0..31
                    ((ull*)hf_b)[i] = ald64(&shb[(((size_t)bh*32 + kc)*64 + l)*2 + u]);
                }
                __syncthreads();
                int w = tid >> 6;
                if (w < 12){
                    int jc = w >> 1, kg = w & 1;
                    int r4 = lane >> 4, c16 = lane & 15;
                    const bf16x8* Bh = (const bf16x8*)p.wgh +
                        ((size_t)(ds*6 + jc)*32)*64 + lane;
                    f32x4 acc = {0.f,0.f,0.f,0.f};
                    #pragma unroll
                    for (int c = 0; c < 16; ++c){
                        int kc = kg*16 + c;
                        bf16x8 a = *(const bf16x8*)(hf_b + ((kc*64 + lane) << 3));
                        acc = mfma16(a, Bh[kc*64], acc);
                    }
                    #pragma unroll
                    for (int r = 0; r < 4; ++r)
                        pgh_l[(kg*16 + r4*4 + r)*100 + jc*16 + c16] = acc[r];
                    const bf16x8* Xp = (const bf16x8*)p.wgx +
                        ((size_t)(ds*6 + jc)*8)*64 + lane;
                    f32x4 ax = {0.f,0.f,0.f,0.f};
                    #pragma unroll
                    for (int c = 0; c < 4; ++c){
                        int kc = kg*4 + c;
                        bf16x8 a = *(const bf16x8*)(p.xall_b +
                            ((size_t)t*32 + bh*16 + c16)*256 + kc*32 + r4*8);
                        ax = mfma16(a, Xp[kc*64], ax);
                    }
                    #pragma unroll
                    for (int r = 0; r < 4; ++r)
                        pgx_l[(kg*16 + r4*4 + r)*100 + jc*16 + c16] = ax[r];
                }
            }
            gbarF(flags, ++epn);
            // ---------- region 2: gic MFMA + gates + h + dpp ------------------
            if (t < T_){
                const int slot = t & 1;
                if (tid < 16){
                    int b = bh*16 + tid;
                    rden_l[tid] = frcp(ald(&p.den[slot*64 + b]) +
                                       ald(&p.den[slot*64 + 32 + b]));
                }
                __syncthreads();
                {   // stage normalized ctx as bf16 A-frags (1024 uint4s, i=tid)
                    int i = tid;
                    int kc = i >> 6, l = i & 63;
                    int b = bh*16 + (l & 15);
                    int e0 = kc*32 + ((l >> 4) << 3);
                    const ull* c0 = (const ull*)p.ctx_b + (((size_t)slot*2 + 0)*32 + b)*128 + (e0 >> 2);
                    const ull* c1 = (const ull*)p.ctx_b + (((size_t)slot*2 + 1)*32 + b)*128 + (e0 >> 2);
                    ull u00 = ald64(c0), u01 = ald64(c0 + 1);
                    ull u10 = ald64(c1), u11 = ald64(c1 + 1);
                    float rd = rden_l[l & 15];
                    uint2 x0 = __builtin_bit_cast(uint2, u00);
                    uint2 x1 = __builtin_bit_cast(uint2, u01);
                    uint2 y0 = __builtin_bit_cast(uint2, u10);
                    uint2 y1 = __builtin_bit_cast(uint2, u11);
                    float2 a0 = upk2(x0.x), b0 = upk2(y0.x);
                    float2 a1 = upk2(x0.y), b1 = upk2(y0.y);
                    float2 a2 = upk2(x1.x), b2 = upk2(y1.x);
                    float2 a3 = upk2(x1.y), b3 = upk2(y1.y);
                    unsigned w0 = pk2((a0.x + b0.x)*rd, (a0.y + b0.y)*rd);
                    unsigned w1 = pk2((a1.x + b1.x)*rd, (a1.y + b1.y)*rd);
                    unsigned w2 = pk2((a2.x + b2.x)*rd, (a2.y + b2.y)*rd);
                    unsigned w3 = pk2((a3.x + b3.x)*rd, (a3.y + b3.y)*rd);
                    *(uint4*)(cf + (size_t)i*16) = make_uint4(w0, w1, w2, w3);
                }
                __syncthreads();
                int w = tid >> 6;
                if (w < 12){
                    int jc = w >> 1, kg = w & 1;
                    int r4 = lane >> 4, c16 = lane & 15;
                    const bf16x8* Cp = (const bf16x8*)p.wgc +
                        ((size_t)(ds*6 + jc)*16)*64 + lane;
                    f32x4 acc = {0.f,0.f,0.f,0.f};
                    #pragma unroll
                    for (int c = 0; c < 8; ++c){
                        int kc = kg*8 + c;
                        bf16x8 a = *(const bf16x8*)(cf + ((kc*64 + lane) << 4));
                        acc = mfma16(a, Cp[kc*64], acc);
                    }
                    #pragma unroll
                    for (int r = 0; r < 4; ++r)
                        pgc_l[(kg*16 + r4*4 + r)*100 + jc*16 + c16] = acc[r];
                }
                __syncthreads();
                if (tid < 512){
                    int b16 = tid >> 5, dl = tid & 31;
                    int dglob = ds*32 + dl;
                    const float* pa = pgh_l + b16*100;
                    const float* pb = pgh_l + (16 + b16)*100;
                    const float* xa = pgx_l + b16*100;
                    const float* xb = pgx_l + (16 + b16)*100;
                    const float* ca = pgc_l + b16*100;
                    const float* cb = pgc_l + (16 + b16)*100;
                    float gi_r = xa[dl]      + xb[dl]      + ca[dl]      + cb[dl]      + p.bih[dglob];
                    float gi_z = xa[32 + dl] + xb[32 + dl] + ca[32 + dl] + cb[32 + dl] + p.bih[1024 + dglob];
                    float gi_n = xa[64 + dl] + xb[64 + dl] + ca[64 + dl] + cb[64 + dl] + p.bih[2048 + dglob];
                    float gh_r = pa[dl]      + pb[dl]      + p.bhh[dglob];
                    float gh_z = pa[32 + dl] + pb[32 + dl] + p.bhh[1024 + dglob];
                    float gh_n = pa[64 + dl] + pb[64 + dl] + p.bhh[2048 + dglob];
                    float rr = fsig(gi_r + gh_r);
                    float zz = fsig(gi_z + gh_z);
                    float nn = ftanh(gi_n + rr*gh_n);
                    float hv = (1.f - zz)*nn + zz*h_reg;
                    h_reg = hv;
                    h_l[b16*32 + dl] = hv;
                    float hv1 = __shfl_xor(hv, 1);
                    if (!(dl & 1)){
                        int b = bh*16 + b16;
                        // double-buffered h_f32: slot (t+1)&1 holds h(t+1)
                        ast2f(&p.h_f32[(size_t)((t + 1) & 1)*32768 + (size_t)b*1024 + dglob], hv, hv1);
                        unsigned pkv = pk2(hv, hv1);
                        int l2 = ((dl >> 3) << 4) + b16;
                        size_t fo = (((size_t)bh*32 + ds)*64 + l2)*4 + ((dl & 7) >> 1);
                        astu((unsigned*)p.h_fb + fo, pkv);
                    }
                }
                __syncthreads();
                {   // dproj partials (pure f32) over this block's 32 d, 16 b
                    int b16 = tid >> 6, ag = tid & 63;
                    int a0 = ag*2;
                    const float* ar = p.awd + (size_t)(ds*32)*128 + a0;
                    float s0 = 0.f, s1 = 0.f;
                    #pragma unroll 8
                    for (int dl = 0; dl < 32; ++dl){
                        float hd = h_l[b16*32 + dl];
                        float2 w2 = *(const float2*)(ar + (size_t)dl*128);
                        s0 += hd*w2.x; s1 += hd*w2.y;
                    }
                    ast2f(&p.dpp[(((size_t)ds*2 + bh)*16 + b16)*128 + a0], s0, s1);
                }
            }
            gbarF(flags, ++epn);
        }
    } else if (bid < 128){
        // ================= ATT (b, half) =================
        const int aa = bid - 64, b = aa >> 1, half = aa & 1;
        // ep_l re-strided: 256 rows x 66 unsigneds (33 ull) -> 2-way conflicts only
        unsigned short* ep_l = (unsigned short*)sm;          // 67584
        float* red  = (float*)(sm + 67584);                  // [16][522] 33408
        float* sred = (float*)(sm + 100992);                 // 4096
        float* dpl  = (float*)(sm + 105088);                 // 512
        float* avl  = (float*)(sm + 105600);                 // 512
        float* esl  = (float*)(sm + 106112);                 // 1024
        float* eslt = (float*)(sm + 107136);                 // [16][17] 1088
        {
            const ull* src = (const ull*)(p.ep_b + ((size_t)b*512 + half*256)*128);
            for (int i = tid; i < 8192; i += 1024){
                int row = i >> 5, col = i & 31;
                ((ull*)ep_l)[(size_t)row*33 + col] = src[i];
            }
            if (tid < 128) avl[tid] = p.av[tid];
        }
        __syncthreads();
        for (int t = 0; t <= T_; ++t){
            if (t < T_){
                const int slot = t & 1;
                {   // dproj = sum of 64 (ds,bh) GATE partials matching this b
                    int a = tid & 127, g = tid >> 7;
                    const int bhb = b >> 4, b15 = b & 15;
                    float s = 0.f;
                    #pragma unroll
                    for (int i = 0; i < 4; ++i){
                        int ds2 = g*4 + i;
                        s += ald(&p.dpp[(((size_t)ds2*2 + bhb)*16 + b15)*128 + a]);
                    }
                    red[g*128 + a] = s;
                }
                __syncthreads();
                if (tid < 128){
                    float s = p.bd[tid];
                    #pragma unroll
                    for (int g = 0; g < 8; ++g) s += red[g*128 + tid];
                    dpl[tid] = s;
                }
                __syncthreads();
                {   // scores: b64 reads from stride-66 ep_l (2-way = free)
                    int s = tid >> 2, ao = tid & 3;
                    const ull* er = (const ull*)ep_l + (size_t)s*33 + ao*8;
                    float sc = 0.f;
                    #pragma unroll
                    for (int i = 0; i < 8; ++i){
                        uint2 uu = __builtin_bit_cast(uint2, er[i]);
                        float2 e0 = upk2(uu.x), e1 = upk2(uu.y);
                        int a0 = ao*32 + i*4;
                        sc += ftanh(e0.x + dpl[a0])*avl[a0]
                            + ftanh(e0.y + dpl[a0+1])*avl[a0+1]
                            + ftanh(e1.x + dpl[a0+2])*avl[a0+2]
                            + ftanh(e1.y + dpl[a0+3])*avl[a0+3];
                    }
                    sred[tid] = sc;
                }
                __syncthreads();
                if (tid < 256){
                    float sc = sred[tid*4] + sred[tid*4+1] + sred[tid*4+2] + sred[tid*4+3] + p.avb[0];
                    float ev = __expf(sc);
                    esl[tid] = ev;
                    eslt[(tid & 15)*17 + (tid >> 4)] = ev;   // transposed copy
                    astf(&p.es_b[(size_t)slot*16384 + b*512 + half*256 + tid], ev);
                }
                __syncthreads();
                if (tid < 64){
                    float d = esl[tid*4] + esl[tid*4+1] + esl[tid*4+2] + esl[tid*4+3];
                    #pragma unroll
                    for (int m = 1; m <= 32; m <<= 1) d += __shfl_xor(d, m);
                    if (tid == 0) astf(&p.den[slot*64 + half*32 + b], d);
                }
                {   // ctx partials: es via conflict-free transposed reads
                    int eo = tid >> 4, sg = tid & 15;
                    int e8 = eo*8;
                    const unsigned short* eb = p.enc_b + ((size_t)b*2 + half)*131072;
                    float a0=0,a1=0,a2=0,a3=0,a4=0,a5=0,a6=0,a7=0;
                    #pragma unroll 4
                    for (int i = 0; i < 16; ++i){
                        int s = sg*16 + i;
                        float ev = eslt[i*17 + sg];
                        uint4 u = *(const uint4*)(eb + (size_t)s*512 + e8);
                        float2 v0=upk2(u.x), v1=upk2(u.y), v2=upk2(u.z), v3=upk2(u.w);
                        a0+=ev*v0.x; a1+=ev*v0.y; a2+=ev*v1.x; a3+=ev*v1.y;
                        a4+=ev*v2.x; a5+=ev*v2.y; a6+=ev*v3.x; a7+=ev*v3.y;
                    }
                    float* rr = &red[sg*522 + e8];
                    rr[0]=a0; rr[1]=a1; rr[2]=a2; rr[3]=a3;
                    rr[4]=a4; rr[5]=a5; rr[6]=a6; rr[7]=a7;
                }
                __syncthreads();
                if (tid < 512){
                    float c = 0.f;
                    #pragma unroll
                    for (int sg = 0; sg < 16; ++sg) c += red[sg*522 + tid];
                    float c1 = __shfl_xor(c, 1);
                    if (!(tid & 1))
                        astu((unsigned*)p.ctx_b + (((size_t)slot*2 + half)*32 + b)*256 + (tid >> 1),
                             pk2(c, c1));
                }
            }
            gbarF(flags, ++epn);
            gbarF(flags, ++epn);
        }
    } else {
        // ================= MEL (b, q): moved to region 2 (balance) ===========
        const int m = bid - 128, b = m >> 2, q = m & 3;
        unsigned short* ow_l = (unsigned short*)sm;   // [32 oc][1538] = 98432B
        float* dout = (float*)(sm + 98432);           // 1536 f
        float* redm = (float*)(sm + 104576);          // [32][33]
        float* rdm  = (float*)(sm + 108800);
        float* stpr = (float*)(sm + 108816);          // 8 f
        {
            const ull* src = (const ull*)p.ow_b + (size_t)q*12288;
            for (int i = tid; i < 12288; i += 1024){
                int oc = i / 384, kq = i - oc*384;
                uint2 u = __builtin_bit_cast(uint2, src[i]);
                unsigned* d = (unsigned*)ow_l + (size_t)oc*769 + kq*2;
                d[0] = u.x; d[1] = u.y;
            }
        }
        __syncthreads();
        for (int t = 0; t <= T_; ++t){
            gbarF(flags, ++epn);              // region 1: idle
            if (t >= 1){                      // region 2: outputs for step t-1
                const int slot = (t - 1) & 1;
                if (tid < 512){
                    // h(t) lives in h_f32 slot t&1 (GATE writes slot (t'+1)&1)
                    ull u = ald64((const ull*)p.h_f32 + (size_t)(t & 1)*16384 + (size_t)b*512 + tid);
                    *(float2*)&dout[tid*2] = __builtin_bit_cast(float2, u);
                } else if (tid < 768){
                    int i = tid - 512;
                    unsigned u0 = aldu((const unsigned*)p.ctx_b + (((size_t)slot*2 + 0)*32 + b)*256 + i);
                    unsigned u1 = aldu((const unsigned*)p.ctx_b + (((size_t)slot*2 + 1)*32 + b)*256 + i);
                    float2 f0 = upk2(u0), f1 = upk2(u1);
                    *(float2*)&dout[1024 + i*2] = make_float2(f0.x + f1.x, f0.y + f1.y);
                } else if (tid == 1023){
                    rdm[0] = frcp(ald(&p.den[slot*64 + b]) + ald(&p.den[slot*64 + 32 + b]));
                }
                __syncthreads();
                if (tid < 512) dout[1024 + tid] *= rdm[0];
                __syncthreads();
                {
                    int kg = tid >> 5, oc = tid & 31;
                    const unsigned* wr = (const unsigned*)ow_l + (size_t)oc*769 + kg*24;
                    const float* dr = dout + kg*48;
                    float a = 0.f;
                    #pragma unroll 6
                    for (int i = 0; i < 24; ++i){
                        float2 w2 = upk2(wr[i]);
                        a += dr[i*2]*w2.x + dr[i*2+1]*w2.y;
                    }
                    redm[kg*33 + oc] = a;
                }
                if (q == 0 && tid < 512){
                    int k3 = tid*3;
                    float s = dout[k3]*p.sw[k3] + dout[k3+1]*p.sw[k3+1] + dout[k3+2]*p.sw[k3+2];
                    #pragma unroll
                    for (int mm = 1; mm <= 32; mm <<= 1) s += __shfl_xor(s, mm);
                    if ((tid & 63) == 0) stpr[tid >> 6] = s;
                    float ev = ald(&p.es_b[(size_t)slot*16384 + b*512 + tid]);
                    p.out[AW_OFF + ((size_t)b*T_ + (t-1))*S_ + tid] = ev*rdm[0];
                }
                __syncthreads();
                if (tid < 32){
                    float a = 0.f;
                    #pragma unroll
                    for (int kg = 0; kg < 32; ++kg) a += redm[kg*33 + tid];
                    int c = q*32 + tid;
                    p.out[MEL_OFF + ((size_t)b*T_ + (t-1))*M_ + c] = a + p.p_ob[c];
                } else if (tid == 32 && q == 0){
                    float tot = 0.f;
                    #pragma unroll
                    for (int w2 = 0; w2 < 8; ++w2) tot += stpr[w2];
                    p.out[STOP_OFF + (size_t)b*T_ + (t-1)] = tot + p.p_sb[0];
                }
            }
            gbarF(flags, ++epn);
        }
    }
}

extern "C" void kernel_launch(void* const* d_in, const int* in_sizes, int n_in,
                              void* d_out, int out_size, void* d_ws, size_t ws_size,
                              hipStream_t stream){
    const float* enc = (const float*)d_in[0];
    const float* tm  = (const float*)d_in[1];
    const float* pw1 = (const float*)d_in[2];
    const float* pb1 = (const float*)d_in[3];
    const float* pw2 = (const float*)d_in[4];
    const float* pb2 = (const float*)d_in[5];
    const float* awe = (const float*)d_in[6];
    const float* abe = (const float*)d_in[7];
    const float* awd = (const float*)d_in[8];
    const float* abd = (const float*)d_in[9];
    const float* av  = (const float*)d_in[10];
    const float* avb = (const float*)d_in[11];
    const float* wih = (const float*)d_in[12];
    const float* whh = (const float*)d_in[13];
    const float* bih = (const float*)d_in[14];
    const float* bhh = (const float*)d_in[15];
    const float* oww = (const float*)d_in[16];
    const float* obb = (const float*)d_in[17];
    const float* sww = (const float*)d_in[18];
    const float* sbb = (const float*)d_in[19];
    float* out = (float*)d_out;
    float* ws  = (float*)d_ws;

    // workspace (float offsets), ~42 MB
    unsigned short* xall_b = (unsigned short*)ws;                //  4,194,304 ush
    unsigned short* enc_b  = (unsigned short*)(ws + 2097152);    //  8,388,608 ush
    unsigned short* ep_b   = (unsigned short*)(ws + 6291456);    //  2,097,152 ush
    unsigned short* wgh    = (unsigned short*)(ws + 7340032);    //  3,145,728 ush
    unsigned short* wgx    = (unsigned short*)(ws + 8912896);    //    786,432 ush
    unsigned short* wgc    = (unsigned short*)(ws + 9306112);    //  1,572,864 ush
    unsigned short* ow_b   = (unsigned short*)(ws + 10092544);   //    196,608 ush
    float* h_f32 = ws + 10190848;                                //  2x 32,768 f
    unsigned short* h_fb   = (unsigned short*)(ws + 10256384);   //     32,768 ush
    unsigned short* ctx_b  = (unsigned short*)(ws + 10272768);   //     65,536 ush
    float* den  = ws + 10305536;                                 //        128 f
    float* es_b = ws + 10305664;                                 //     32,768 f
    float* dpp  = ws + 10338432;                                 //    131,072 f
    unsigned* flags = (unsigned*)(ws + 10469504);                //  256x16 u

    hipMemsetAsync(h_f32, 0, (size_t)65536*4, stream);
    hipMemsetAsync(h_fb, 0, 32768*2, stream);
    hipMemsetAsync(dpp, 0, (size_t)131072*4, stream);
    hipMemsetAsync(flags, 0, 16384, stream);

    k_prep_w<<<55040, 256, 0, stream>>>(enc, whh, wih, oww,
                                        enc_b, wgh, wgx, wgc, ow_b);
    k_encproj<<<256, 256, 0, stream>>>(enc, awe, abe, ep_b);
    k_prenet<<<1024, 128, 0, stream>>>(tm, pw1, pb1, pw2, pb2, xall_b);

    hipFuncSetAttribute((const void*)k_persist,
                        hipFuncAttributeMaxDynamicSharedMemorySize, DYN_BYTES);

    KP kp;
    kp.xall_b = xall_b; kp.enc_b = enc_b; kp.ep_b = ep_b;
    kp.wgh = wgh; kp.wgx = wgx; kp.wgc = wgc; kp.ow_b = ow_b;
    kp.awd = awd; kp.sw = sww; kp.bd = abd; kp.av = av; kp.avb = avb;
    kp.bih = bih; kp.bhh = bhh; kp.p_ob = obb; kp.p_sb = sbb;
    kp.h_f32 = h_f32; kp.h_fb = h_fb;
    kp.ctx_b = ctx_b; kp.den = den; kp.es_b = es_b; kp.dpp = dpp;
    kp.flags = flags; kp.out = out;

    KP* kparg = &kp;
    void* args[] = { (void*)kparg };
    hipLaunchCooperativeKernel((void*)k_persist, dim3(256), dim3(1024),
                               args, DYN_BYTES, stream);
}

// Round 14
// 15282.642 us; speedup vs baseline: 9.1043x; 1.0257x over previous
//
#include <hip/hip_runtime.h>

// Problem constants
constexpr int B_   = 32;
constexpr int S_   = 512;
constexpr int T_   = 512;
constexpr int ENC_ = 512;
constexpr int ATT_ = 128;
constexpr int PO_  = 256;
constexpr int DEC_ = 1024;
constexpr int M_   = 128;

// Output offsets (floats)
constexpr int MEL_OFF  = 0;
constexpr int STOP_OFF = B_*T_*M_;            // 2,097,152
constexpr int AW_OFF   = STOP_OFF + B_*T_;    // 2,113,536

typedef __attribute__((ext_vector_type(8))) short bf16x8;
typedef __attribute__((ext_vector_type(4))) float f32x4;
typedef unsigned long long ull;

__device__ __forceinline__ float frcp(float x){ return __builtin_amdgcn_rcpf(x); }
__device__ __forceinline__ float ftanh(float x){ float e = __expf(2.f*x); return 1.f - 2.f*frcp(e + 1.f); }
__device__ __forceinline__ float fsig(float x){ return frcp(1.f + __expf(-x)); }

__device__ __forceinline__ float2 upk2(unsigned u){
    return make_float2(__builtin_bit_cast(float, u << 16),
                       __builtin_bit_cast(float, u & 0xffff0000u));
}
__device__ __forceinline__ unsigned short f2b(float f){
    unsigned u = __builtin_bit_cast(unsigned, f);
    return (unsigned short)((u + 0x7fffu + ((u >> 16) & 1u)) >> 16);
}
__device__ __forceinline__ unsigned pk2(float a, float b){
    return (unsigned)f2b(a) | ((unsigned)f2b(b) << 16);
}

// ---- relaxed agent-scope (device-coherent) accessors (R3/R8-proven) ----------
__device__ __forceinline__ float ald(const float* p){
    return __hip_atomic_load(p, __ATOMIC_RELAXED, __HIP_MEMORY_SCOPE_AGENT);
}
__device__ __forceinline__ ull ald64(const void* p){
    return __hip_atomic_load((const ull*)p, __ATOMIC_RELAXED, __HIP_MEMORY_SCOPE_AGENT);
}
__device__ __forceinline__ unsigned aldu(const unsigned* p){
    return __hip_atomic_load(p, __ATOMIC_RELAXED, __HIP_MEMORY_SCOPE_AGENT);
}
__device__ __forceinline__ void astf(float* p, float v){
    __hip_atomic_store(p, v, __ATOMIC_RELAXED, __HIP_MEMORY_SCOPE_AGENT);
}
union F2U { float2 f; ull u; };
__device__ __forceinline__ void ast2f(float* p, float a, float b){
    F2U x; x.f = make_float2(a, b);
    __hip_atomic_store((ull*)p, x.u, __ATOMIC_RELAXED, __HIP_MEMORY_SCOPE_AGENT);
}
__device__ __forceinline__ void astu(unsigned* p, unsigned v){
    __hip_atomic_store(p, v, __ATOMIC_RELAXED, __HIP_MEMORY_SCOPE_AGENT);
}

// ---- point-to-point flag sync (R8-proven drain + relaxed-flag protocol) ------
__device__ __forceinline__ void waitP64(const unsigned* f, unsigned ep){
    if (threadIdx.x < 64){
        for (;;){
            unsigned v = aldu(&f[threadIdx.x*16]);
            if (__all(v >= ep)) break;
            __builtin_amdgcn_s_sleep(1);
        }
    }
    __syncthreads();
}
__device__ __forceinline__ void waitP128(const unsigned* f, unsigned ep){
    if (threadIdx.x < 64){
        for (;;){
            unsigned a = aldu(&f[threadIdx.x*16]);
            unsigned b = aldu(&f[(threadIdx.x + 64)*16]);
            unsigned m = a < b ? a : b;
            if (__all(m >= ep)) break;
            __builtin_amdgcn_s_sleep(1);
        }
    }
    __syncthreads();
}
__device__ __forceinline__ void signalF(unsigned* f, unsigned v){
    asm volatile("s_waitcnt vmcnt(0) lgkmcnt(0)" ::: "memory");
    __syncthreads();
    if (threadIdx.x == 0) astu(f, v);
}

__device__ __forceinline__ f32x4 mfma16(bf16x8 a, bf16x8 b, f32x4 c){
    return __builtin_amdgcn_mfma_f32_16x16x32_bf16(a, b, c, 0, 0, 0);
}

// ================= prep: staged layouts =================
__global__ __launch_bounds__(256) void k_prep_w(const float* __restrict__ enc,
        const float* __restrict__ whh, const float* __restrict__ wih,
        const float* __restrict__ oww,
        unsigned short* __restrict__ enc_b, unsigned short* __restrict__ wgh,
        unsigned short* __restrict__ wgx, unsigned short* __restrict__ wgc,
        unsigned short* __restrict__ ow_b){
    long long idx = (long long)blockIdx.x*256 + threadIdx.x;
    if (idx < 8388608LL){
        int bh = (int)(idx >> 17); int r = (int)(idx & 131071);
        int s = r >> 9, e = r & 511;
        int b = bh >> 1, half = bh & 1;
        enc_b[idx] = f2b(enc[((size_t)b*S_ + half*256 + s)*ENC_ + e]);
    } else if (idx < 11534336LL){
        long long q = idx - 8388608LL;
        int ds = (int)(q / 98304); int r = (int)(q % 98304);
        int jc = r / 16384; int r2 = r % 16384;
        int kc = r2 >> 9, l = (r2 >> 3) & 63, e = r2 & 7;
        int j = (jc >> 1)*1024 + ds*32 + (jc & 1)*16 + (l & 15);
        int k = kc*32 + ((l >> 4) << 3) + e;
        wgh[q] = f2b(whh[(size_t)j*DEC_ + k]);
    } else if (idx < 12320768LL){
        long long q = idx - 11534336LL;
        int ds = (int)(q / 24576); int r = (int)(q % 24576);
        int jc = r / 4096; int r3 = r % 4096;
        int kc = r3 >> 9, l = (r3 >> 3) & 63, e = r3 & 7;
        int j = (jc >> 1)*1024 + ds*32 + (jc & 1)*16 + (l & 15);
        int k = kc*32 + ((l >> 4) << 3) + e;
        wgx[q] = f2b(wih[(size_t)j*768 + k]);
    } else if (idx < 13893632LL){
        long long q = idx - 12320768LL;
        int ds = (int)(q / 49152); int r = (int)(q % 49152);
        int jc = r / 8192; int r3 = r % 8192;
        int kc = r3 >> 9, l = (r3 >> 3) & 63, e = r3 & 7;
        int j = (jc >> 1)*1024 + ds*32 + (jc & 1)*16 + (l & 15);
        int k = kc*32 + ((l >> 4) << 3) + e;
        wgc[q] = f2b(wih[(size_t)j*768 + 256 + k]);
    } else if (idx < 14090240LL){
        long long q = idx - 13893632LL;
        int cg = (int)(q / 49152); int r = (int)(q % 49152);
        int oc = r / 1536, k = r % 1536;
        ow_b[q] = f2b(oww[(size_t)k*M_ + cg*32 + oc]);
    }
}

// ep_b[b][512 s][128 a] bf16 = enc @ att_we + be
__global__ __launch_bounds__(256) void k_encproj(const float* __restrict__ enc,
        const float* __restrict__ we, const float* __restrict__ be,
        unsigned short* __restrict__ ep_b){
    __shared__ float we_s[64*128];
    __shared__ float enc_s[64*64];
    int blk = blockIdx.x, tid = threadIdx.x;
    int b = blk >> 3, ss = blk & 7;
    int s = tid >> 2, ag = tid & 3;
    float acc[32];
    #pragma unroll
    for (int j = 0; j < 32; ++j) acc[j] = 0.f;
    for (int kc = 0; kc < 8; ++kc){
        __syncthreads();
        for (int i = tid; i < 8192; i += 256)
            we_s[i] = we[(size_t)(kc*64 + (i >> 7))*ATT_ + (i & 127)];
        for (int i = tid; i < 4096; i += 256)
            enc_s[i] = enc[((size_t)b*S_ + ss*64 + (i >> 6))*ENC_ + kc*64 + (i & 63)];
        __syncthreads();
        for (int kk = 0; kk < 64; ++kk){
            float ev = enc_s[s*64 + kk];
            const float* wr = &we_s[(kk << 7) + (ag << 5)];
            #pragma unroll
            for (int j = 0; j < 32; ++j) acc[j] += ev*wr[j];
        }
    }
    #pragma unroll
    for (int j = 0; j < 32; ++j){
        int a = (ag << 5) + j;
        ep_b[((size_t)b*512 + ss*64 + s)*ATT_ + a] = f2b(acc[j] + be[a]);
    }
}

// PreNet (f32 math, bf16 output)
__global__ __launch_bounds__(128) void k_prenet(const float* __restrict__ tm,
        const float* __restrict__ w1, const float* __restrict__ b1,
        const float* __restrict__ w2, const float* __restrict__ b2,
        unsigned short* __restrict__ xall){
    __shared__ float mel_l[128*20];
    __shared__ float h1_l[256*20];
    int row0 = blockIdx.x << 4;
    int t = row0 >> 5, b0 = row0 & 31;
    int tid = threadIdx.x;
    for (int p = 0; p < 16; p++){
        int idx = tid + (p << 7);
        int k = idx & 127, r = idx >> 7;
        float v = 0.f;
        if (t > 0) v = tm[((size_t)(b0 + r)*T_ + (t - 1))*M_ + k];
        mel_l[k*20 + r] = v;
    }
    __syncthreads();
    float acc1[16], acc2[16];
    #pragma unroll
    for (int i = 0; i < 16; i++){ acc1[i] = 0.f; acc2[i] = 0.f; }
    for (int k = 0; k < M_; k++){
        float wa = w1[k*256 + tid];
        float wb = w1[k*256 + tid + 128];
        float mv[16];
        *(float4*)&mv[0]  = *(const float4*)&mel_l[k*20 + 0];
        *(float4*)&mv[4]  = *(const float4*)&mel_l[k*20 + 4];
        *(float4*)&mv[8]  = *(const float4*)&mel_l[k*20 + 8];
        *(float4*)&mv[12] = *(const float4*)&mel_l[k*20 + 12];
        #pragma unroll
        for (int r = 0; r < 16; r++){ acc1[r] += mv[r]*wa; acc2[r] += mv[r]*wb; }
    }
    float bb1a = b1[tid], bb1b = b1[tid + 128];
    #pragma unroll
    for (int r = 0; r < 16; r++){
        h1_l[tid*20 + r]         = fmaxf(acc1[r] + bb1a, 0.f);
        h1_l[(tid + 128)*20 + r] = fmaxf(acc2[r] + bb1b, 0.f);
    }
    __syncthreads();
    #pragma unroll
    for (int i = 0; i < 16; i++){ acc1[i] = 0.f; acc2[i] = 0.f; }
    for (int k = 0; k < 256; k++){
        float wa = w2[k*256 + tid];
        float wb = w2[k*256 + tid + 128];
        float mv[16];
        *(float4*)&mv[0]  = *(const float4*)&h1_l[k*20 + 0];
        *(float4*)&mv[4]  = *(const float4*)&h1_l[k*20 + 4];
        *(float4*)&mv[8]  = *(const float4*)&h1_l[k*20 + 8];
        *(float4*)&mv[12] = *(const float4*)&h1_l[k*20 + 12];
        #pragma unroll
        for (int r = 0; r < 16; r++){ acc1[r] += mv[r]*wa; acc2[r] += mv[r]*wb; }
    }
    float bb2a = b2[tid], bb2b = b2[tid + 128];
    #pragma unroll
    for (int r = 0; r < 16; r++){
        xall[((size_t)row0 + r)*PO_ + tid]       = f2b(fmaxf(acc1[r] + bb2a, 0.f));
        xall[((size_t)row0 + r)*PO_ + tid + 128] = f2b(fmaxf(acc2[r] + bb2b, 0.f));
    }
}

// ================= persistent dataflow decoder =================
#define DYN_BYTES 110592

struct KP {
    const unsigned short* xall_b; const unsigned short* enc_b; const unsigned short* ep_b;
    const unsigned short* wgh; const unsigned short* wgx; const unsigned short* wgc;
    const unsigned short* ow_b;
    const float* awd; const float* sw; const float* bd; const float* av; const float* avb;
    const float* bih; const float* bhh; const float* p_ob; const float* p_sb;
    float* h_f32; unsigned short* h_fb;
    unsigned short* ctx_b; float* den; float* es_b; float* dpp;
    unsigned* gflag; unsigned* aflag; unsigned* mflag; float* out;
};

__global__ __launch_bounds__(1024) void k_persist(KP p){
    extern __shared__ char sm[];
    const int bid = blockIdx.x, tid = threadIdx.x;
    const int lane = tid & 63;

    if (bid < 64){
        // ======== GATE (XCD-affinity mapping, R11-proven) ========
        const int xcd = bid & 7, slot8 = bid >> 3;
        const int ds = xcd*4 + (slot8 >> 1), bh = slot8 & 1;
        unsigned short* hf_b = (unsigned short*)sm;            // r1 32KB (alias cf)
        char* cf = sm;                                         // r2 ctx frags 16KB
        float* pgh_l = (float*)(sm + 32768);                   // [2*16][100]
        float* pgx_l = (float*)(sm + 45568);                   // [2*16][100]
        float* pgc_l = (float*)(sm + 58368);                   // [2*16][100]
        float* h_l   = (float*)(sm + 71168);                   // [16][32]
        float* rden_l= (float*)(sm + 73216);                   // 16 f
        float h_reg = 0.f;

        for (int t = 0; t < T_; ++t){
            // ---- r1: full-K gh + gix MFMA (needs h(t) from all GATE) --------
            waitP64(p.gflag, (unsigned)t);
            {
                // FIX(R14): h_fb slot stride is 8192 ull (32768 ush), not 4096.
                const ull* shb = (const ull*)p.h_fb + (size_t)(t & 1)*8192;
                for (int i = tid; i < 4096; i += 1024){
                    int u = i & 1, l = (i >> 1) & 63, kc = i >> 7;
                    ((ull*)hf_b)[i] = ald64(&shb[(((size_t)bh*32 + kc)*64 + l)*2 + u]);
                }
                __syncthreads();
                int w = tid >> 6;
                if (w < 12){
                    int jc = w >> 1, kg = w & 1;
                    int r4 = lane >> 4, c16 = lane & 15;
                    const bf16x8* Bh = (const bf16x8*)p.wgh +
                        ((size_t)(ds*6 + jc)*32)*64 + lane;
                    f32x4 acc = {0.f,0.f,0.f,0.f};
                    #pragma unroll
                    for (int c = 0; c < 16; ++c){
                        int kc = kg*16 + c;
                        bf16x8 a = *(const bf16x8*)(hf_b + ((kc*64 + lane) << 3));
                        acc = mfma16(a, Bh[kc*64], acc);
                    }
                    #pragma unroll
                    for (int r = 0; r < 4; ++r)
                        pgh_l[(kg*16 + r4*4 + r)*100 + jc*16 + c16] = acc[r];
                    const bf16x8* Xp = (const bf16x8*)p.wgx +
                        ((size_t)(ds*6 + jc)*8)*64 + lane;
                    f32x4 ax = {0.f,0.f,0.f,0.f};
                    #pragma unroll
                    for (int c = 0; c < 4; ++c){
                        int kc = kg*4 + c;
                        bf16x8 a = *(const bf16x8*)(p.xall_b +
                            ((size_t)t*32 + bh*16 + c16)*256 + kc*32 + r4*8);
                        ax = mfma16(a, Xp[kc*64], ax);
                    }
                    #pragma unroll
                    for (int r = 0; r < 4; ++r)
                        pgx_l[(kg*16 + r4*4 + r)*100 + jc*16 + c16] = ax[r];
                }
                __syncthreads();
            }
            // ---- r2: gic MFMA + gates + h + dpp (needs ctx(t) from ATT) -----
            waitP64(p.aflag, (unsigned)(t + 1));
            {
                const int slot = t & 3;
                if (tid < 16){
                    int b = bh*16 + tid;
                    rden_l[tid] = frcp(ald(&p.den[slot*64 + b]) +
                                       ald(&p.den[slot*64 + 32 + b]));
                }
                __syncthreads();
                {   // stage normalized ctx as bf16 A-frags
                    int i = tid;
                    int kc = i >> 6, l = i & 63;
                    int b = bh*16 + (l & 15);
                    int e0 = kc*32 + ((l >> 4) << 3);
                    const ull* c0 = (const ull*)p.ctx_b + (((size_t)slot*2 + 0)*32 + b)*128 + (e0 >> 2);
                    const ull* c1 = (const ull*)p.ctx_b + (((size_t)slot*2 + 1)*32 + b)*128 + (e0 >> 2);
                    ull u00 = ald64(c0), u01 = ald64(c0 + 1);
                    ull u10 = ald64(c1), u11 = ald64(c1 + 1);
                    float rd = rden_l[l & 15];
                    uint2 x0 = __builtin_bit_cast(uint2, u00);
                    uint2 x1 = __builtin_bit_cast(uint2, u01);
                    uint2 y0 = __builtin_bit_cast(uint2, u10);
                    uint2 y1 = __builtin_bit_cast(uint2, u11);
                    float2 a0 = upk2(x0.x), b0 = upk2(y0.x);
                    float2 a1 = upk2(x0.y), b1 = upk2(y0.y);
                    float2 a2 = upk2(x1.x), b2 = upk2(y1.x);
                    float2 a3 = upk2(x1.y), b3 = upk2(y1.y);
                    unsigned w0 = pk2((a0.x + b0.x)*rd, (a0.y + b0.y)*rd);
                    unsigned w1 = pk2((a1.x + b1.x)*rd, (a1.y + b1.y)*rd);
                    unsigned w2 = pk2((a2.x + b2.x)*rd, (a2.y + b2.y)*rd);
                    unsigned w3 = pk2((a3.x + b3.x)*rd, (a3.y + b3.y)*rd);
                    *(uint4*)(cf + (size_t)i*16) = make_uint4(w0, w1, w2, w3);
                }
                __syncthreads();
                int w = tid >> 6;
                if (w < 12){
                    int jc = w >> 1, kg = w & 1;
                    int r4 = lane >> 4, c16 = lane & 15;
                    const bf16x8* Cp = (const bf16x8*)p.wgc +
                        ((size_t)(ds*6 + jc)*16)*64 + lane;
                    f32x4 acc = {0.f,0.f,0.f,0.f};
                    #pragma unroll
                    for (int c = 0; c < 8; ++c){
                        int kc = kg*8 + c;
                        bf16x8 a = *(const bf16x8*)(cf + ((kc*64 + lane) << 4));
                        acc = mfma16(a, Cp[kc*64], acc);
                    }
                    #pragma unroll
                    for (int r = 0; r < 4; ++r)
                        pgc_l[(kg*16 + r4*4 + r)*100 + jc*16 + c16] = acc[r];
                }
                __syncthreads();
                if (tid < 512){
                    int b16 = tid >> 5, dl = tid & 31;
                    int dglob = ds*32 + dl;
                    const float* pa = pgh_l + b16*100;
                    const float* pb = pgh_l + (16 + b16)*100;
                    const float* xa = pgx_l + b16*100;
                    const float* xb = pgx_l + (16 + b16)*100;
                    const float* ca = pgc_l + b16*100;
                    const float* cb = pgc_l + (16 + b16)*100;
                    float gi_r = xa[dl]      + xb[dl]      + ca[dl]      + cb[dl]      + p.bih[dglob];
                    float gi_z = xa[32 + dl] + xb[32 + dl] + ca[32 + dl] + cb[32 + dl] + p.bih[1024 + dglob];
                    float gi_n = xa[64 + dl] + xb[64 + dl] + ca[64 + dl] + cb[64 + dl] + p.bih[2048 + dglob];
                    float gh_r = pa[dl]      + pb[dl]      + p.bhh[dglob];
                    float gh_z = pa[32 + dl] + pb[32 + dl] + p.bhh[1024 + dglob];
                    float gh_n = pa[64 + dl] + pb[64 + dl] + p.bhh[2048 + dglob];
                    float rr = fsig(gi_r + gh_r);
                    float zz = fsig(gi_z + gh_z);
                    float nn = ftanh(gi_n + rr*gh_n);
                    float hv = (1.f - zz)*nn + zz*h_reg;
                    h_reg = hv;
                    h_l[b16*32 + dl] = hv;
                    float hv1 = __shfl_xor(hv, 1);
                    if (!(dl & 1)){
                        int b = bh*16 + b16;
                        ast2f(&p.h_f32[(size_t)((t + 1) & 3)*32768 + (size_t)b*1024 + dglob], hv, hv1);
                        unsigned pkv = pk2(hv, hv1);
                        int l2 = ((dl >> 3) << 4) + b16;
                        size_t fo = (size_t)((t + 1) & 1)*16384 +
                                    (((size_t)bh*32 + ds)*64 + l2)*4 + ((dl & 7) >> 1);
                        astu((unsigned*)p.h_fb + fo, pkv);
                    }
                }
                __syncthreads();
                {   // dproj partials (pure f32) over this block's 32 d, 16 b
                    int b16 = tid >> 6, ag = tid & 63;
                    int a0 = ag*2;
                    const float* ar = p.awd + (size_t)(ds*32)*128 + a0;
                    float s0 = 0.f, s1 = 0.f;
                    #pragma unroll 8
                    for (int dl = 0; dl < 32; ++dl){
                        float hd = h_l[b16*32 + dl];
                        float2 w2 = *(const float2*)(ar + (size_t)dl*128);
                        s0 += hd*w2.x; s1 += hd*w2.y;
                    }
                    ast2f(&p.dpp[(((size_t)ds*2 + bh)*16 + b16)*128 + a0], s0, s1);
                }
            }
            signalF(&p.gflag[bid*16], (unsigned)(t + 1));
        }
    } else if (bid < 128){
        // ================= ATT (b, half) =================
        const int aa = bid - 64, b = aa >> 1, half = aa & 1;
        unsigned short* ep_l = (unsigned short*)sm;          // stride-66 rows, 67584B
        float* red  = (float*)(sm + 67584);                  // [16][522]
        float* sred = (float*)(sm + 100992);                 // 4096
        float* dpl  = (float*)(sm + 105088);                 // 512
        float* avl  = (float*)(sm + 105600);                 // 512
        float* esl  = (float*)(sm + 106112);                 // 1024
        float* eslt = (float*)(sm + 107136);                 // [16][17]
        {
            const ull* src = (const ull*)(p.ep_b + ((size_t)b*512 + half*256)*128);
            for (int i = tid; i < 8192; i += 1024){
                int row = i >> 5, col = i & 31;
                ((ull*)ep_l)[(size_t)row*33 + col] = src[i];
            }
            if (tid < 128) avl[tid] = p.av[tid];
        }
        __syncthreads();
        for (int t = 0; t < T_; ++t){
            waitP64(p.gflag, (unsigned)t);                 // dpp(t) ready
            if (t >= 3) waitP128(p.mflag, (unsigned)(t - 2));  // slot-reuse guard
            const int slot = t & 3;
            {   // dproj = sum of 64 (ds,bh) GATE partials matching this b
                int a = tid & 127, g = tid >> 7;
                const int bhb = b >> 4, b15 = b & 15;
                float s = 0.f;
                #pragma unroll
                for (int i = 0; i < 4; ++i){
                    int ds2 = g*4 + i;
                    s += ald(&p.dpp[(((size_t)ds2*2 + bhb)*16 + b15)*128 + a]);
                }
                red[g*128 + a] = s;
            }
            __syncthreads();
            if (tid < 128){
                float s = p.bd[tid];
                #pragma unroll
                for (int g = 0; g < 8; ++g) s += red[g*128 + tid];
                dpl[tid] = s;
            }
            __syncthreads();
            {   // scores: b64 reads from stride-66 ep_l (2-way = free)
                int s = tid >> 2, ao = tid & 3;
                const ull* er = (const ull*)ep_l + (size_t)s*33 + ao*8;
                float sc = 0.f;
                #pragma unroll
                for (int i = 0; i < 8; ++i){
                    uint2 uu = __builtin_bit_cast(uint2, er[i]);
                    float2 e0 = upk2(uu.x), e1 = upk2(uu.y);
                    int a0 = ao*32 + i*4;
                    sc += ftanh(e0.x + dpl[a0])*avl[a0]
                        + ftanh(e0.y + dpl[a0+1])*avl[a0+1]
                        + ftanh(e1.x + dpl[a0+2])*avl[a0+2]
                        + ftanh(e1.y + dpl[a0+3])*avl[a0+3];
                }
                sred[tid] = sc;
            }
            __syncthreads();
            if (tid < 256){
                float sc = sred[tid*4] + sred[tid*4+1] + sred[tid*4+2] + sred[tid*4+3] + p.avb[0];
                float ev = __expf(sc);
                esl[tid] = ev;
                eslt[(tid & 15)*17 + (tid >> 4)] = ev;
                astf(&p.es_b[(size_t)slot*16384 + b*512 + half*256 + tid], ev);
            }
            __syncthreads();
            if (tid < 64){
                float d = esl[tid*4] + esl[tid*4+1] + esl[tid*4+2] + esl[tid*4+3];
                #pragma unroll
                for (int m = 1; m <= 32; m <<= 1) d += __shfl_xor(d, m);
                if (tid == 0) astf(&p.den[slot*64 + half*32 + b], d);
            }
            {   // ctx partials: conflict-free transposed es reads
                int eo = tid >> 4, sg = tid & 15;
                int e8 = eo*8;
                const unsigned short* eb = p.enc_b + ((size_t)b*2 + half)*131072;
                float a0=0,a1=0,a2=0,a3=0,a4=0,a5=0,a6=0,a7=0;
                #pragma unroll 4
                for (int i = 0; i < 16; ++i){
                    int s = sg*16 + i;
                    float ev = eslt[i*17 + sg];
                    uint4 u = *(const uint4*)(eb + (size_t)s*512 + e8);
                    float2 v0=upk2(u.x), v1=upk2(u.y), v2=upk2(u.z), v3=upk2(u.w);
                    a0+=ev*v0.x; a1+=ev*v0.y; a2+=ev*v1.x; a3+=ev*v1.y;
                    a4+=ev*v2.x; a5+=ev*v2.y; a6+=ev*v3.x; a7+=ev*v3.y;
                }
                float* rr = &red[sg*522 + e8];
                rr[0]=a0; rr[1]=a1; rr[2]=a2; rr[3]=a3;
                rr[4]=a4; rr[5]=a5; rr[6]=a6; rr[7]=a7;
            }
            __syncthreads();
            if (tid < 512){
                float c = 0.f;
                #pragma unroll
                for (int sg = 0; sg < 16; ++sg) c += red[sg*522 + tid];
                float c1 = __shfl_xor(c, 1);
                if (!(tid & 1))
                    astu((unsigned*)p.ctx_b + (((size_t)slot*2 + half)*32 + b)*256 + (tid >> 1),
                         pk2(c, c1));
            }
            signalF(&p.aflag[aa*16], (unsigned)(t + 1));
        }
    } else {
        // ================= MEL (b, q): slack-buffered, off critical path =====
        const int m = bid - 128, b = m >> 2, q = m & 3;
        unsigned short* ow_l = (unsigned short*)sm;   // [32 oc][1538]
        float* dout = (float*)(sm + 98432);           // 1536 f
        float* redm = (float*)(sm + 104576);          // [32][33]
        float* rdm  = (float*)(sm + 108800);
        float* stpr = (float*)(sm + 108816);          // 8 f
        {
            const ull* src = (const ull*)p.ow_b + (size_t)q*12288;
            for (int i = tid; i < 12288; i += 1024){
                int oc = i / 384, kq = i - oc*384;
                uint2 u = __builtin_bit_cast(uint2, src[i]);
                unsigned* d = (unsigned*)ow_l + (size_t)oc*769 + kq*2;
                d[0] = u.x; d[1] = u.y;
            }
        }
        __syncthreads();
        for (int t = 1; t <= T_; ++t){
            waitP64(p.gflag, (unsigned)t);    // h(t) ready
            waitP64(p.aflag, (unsigned)t);    // ctx(t-1)/den/es ready
            const int slot = (t - 1) & 3;
            if (tid < 512){
                ull u = ald64((const ull*)p.h_f32 + (size_t)(t & 3)*16384 + (size_t)b*512 + tid);
                *(float2*)&dout[tid*2] = __builtin_bit_cast(float2, u);
            } else if (tid < 768){
                int i = tid - 512;
                unsigned u0 = aldu((const unsigned*)p.ctx_b + (((size_t)slot*2 + 0)*32 + b)*256 + i);
                unsigned u1 = aldu((const unsigned*)p.ctx_b + (((size_t)slot*2 + 1)*32 + b)*256 + i);
                float2 f0 = upk2(u0), f1 = upk2(u1);
                *(float2*)&dout[1024 + i*2] = make_float2(f0.x + f1.x, f0.y + f1.y);
            } else if (tid == 1023){
                rdm[0] = frcp(ald(&p.den[slot*64 + b]) + ald(&p.den[slot*64 + 32 + b]));
            }
            __syncthreads();
            if (tid < 512) dout[1024 + tid] *= rdm[0];
            __syncthreads();
            {
                int kg = tid >> 5, oc = tid & 31;
                const unsigned* wr = (const unsigned*)ow_l + (size_t)oc*769 + kg*24;
                const float* dr = dout + kg*48;
                float a = 0.f;
                #pragma unroll 6
                for (int i = 0; i < 24; ++i){
                    float2 w2 = upk2(wr[i]);
                    a += dr[i*2]*w2.x + dr[i*2+1]*w2.y;
                }
                redm[kg*33 + oc] = a;
            }
            if (q == 0 && tid < 512){
                int k3 = tid*3;
                float s = dout[k3]*p.sw[k3] + dout[k3+1]*p.sw[k3+1] + dout[k3+2]*p.sw[k3+2];
                #pragma unroll
                for (int mm = 1; mm <= 32; mm <<= 1) s += __shfl_xor(s, mm);
                if ((tid & 63) == 0) stpr[tid >> 6] = s;
                float ev = ald(&p.es_b[(size_t)slot*16384 + b*512 + tid]);
                p.out[AW_OFF + ((size_t)b*T_ + (t-1))*S_ + tid] = ev*rdm[0];
            }
            __syncthreads();
            if (tid < 32){
                float a = 0.f;
                #pragma unroll
                for (int kg = 0; kg < 32; ++kg) a += redm[kg*33 + tid];
                int c = q*32 + tid;
                p.out[MEL_OFF + ((size_t)b*T_ + (t-1))*M_ + c] = a + p.p_ob[c];
            } else if (tid == 32 && q == 0){
                float tot = 0.f;
                #pragma unroll
                for (int w2 = 0; w2 < 8; ++w2) tot += stpr[w2];
                p.out[STOP_OFF + (size_t)b*T_ + (t-1)] = tot + p.p_sb[0];
            }
            signalF(&p.mflag[m*16], (unsigned)t);
        }
    }
}

extern "C" void kernel_launch(void* const* d_in, const int* in_sizes, int n_in,
                              void* d_out, int out_size, void* d_ws, size_t ws_size,
                              hipStream_t stream){
    const float* enc = (const float*)d_in[0];
    const float* tm  = (const float*)d_in[1];
    const float* pw1 = (const float*)d_in[2];
    const float* pb1 = (const float*)d_in[3];
    const float* pw2 = (const float*)d_in[4];
    const float* pb2 = (const float*)d_in[5];
    const float* awe = (const float*)d_in[6];
    const float* abe = (const float*)d_in[7];
    const float* awd = (const float*)d_in[8];
    const float* abd = (const float*)d_in[9];
    const float* av  = (const float*)d_in[10];
    const float* avb = (const float*)d_in[11];
    const float* wih = (const float*)d_in[12];
    const float* whh = (const float*)d_in[13];
    const float* bih = (const float*)d_in[14];
    const float* bhh = (const float*)d_in[15];
    const float* oww = (const float*)d_in[16];
    const float* obb = (const float*)d_in[17];
    const float* sww = (const float*)d_in[18];
    const float* sbb = (const float*)d_in[19];
    float* out = (float*)d_out;
    float* ws  = (float*)d_ws;

    // workspace (float offsets), ~42.5 MB
    unsigned short* xall_b = (unsigned short*)ws;                //  4,194,304 ush
    unsigned short* enc_b  = (unsigned short*)(ws + 2097152);    //  8,388,608 ush
    unsigned short* ep_b   = (unsigned short*)(ws + 6291456);    //  2,097,152 ush
    unsigned short* wgh    = (unsigned short*)(ws + 7340032);    //  3,145,728 ush
    unsigned short* wgx    = (unsigned short*)(ws + 8912896);    //    786,432 ush
    unsigned short* wgc    = (unsigned short*)(ws + 9306112);    //  1,572,864 ush
    unsigned short* ow_b   = (unsigned short*)(ws + 10092544);   //    196,608 ush
    float* h_f32 = ws + 10190848;                                //  4x 32,768 f
    unsigned short* h_fb   = (unsigned short*)(ws + 10321920);   //  2x 32,768 ush
    unsigned short* ctx_b  = (unsigned short*)(ws + 10354688);   //  4x 32,768 ush
    float* den  = ws + 10420224;                                 //  4x 64 f
    float* es_b = ws + 10420480;                                 //  4x 16,384 f
    float* dpp  = ws + 10486016;                                 //    131,072 f
    unsigned* gflag = (unsigned*)(ws + 10617088);                //  64x16 u
    unsigned* aflag = gflag + 1024;                              //  64x16 u
    unsigned* mflag = aflag + 1024;                              // 128x16 u

    hipMemsetAsync(h_f32, 0, (size_t)131072*4, stream);
    hipMemsetAsync(h_fb, 0, (size_t)65536*2, stream);
    hipMemsetAsync(dpp, 0, (size_t)131072*4, stream);
    hipMemsetAsync(gflag, 0, 16384, stream);

    k_prep_w<<<55040, 256, 0, stream>>>(enc, whh, wih, oww,
                                        enc_b, wgh, wgx, wgc, ow_b);
    k_encproj<<<256, 256, 0, stream>>>(enc, awe, abe, ep_b);
    k_prenet<<<1024, 128, 0, stream>>>(tm, pw1, pb1, pw2, pb2, xall_b);

    hipFuncSetAttribute((const void*)k_persist,
                        hipFuncAttributeMaxDynamicSharedMemorySize, DYN_BYTES);

    KP kp;
    kp.xall_b = xall_b; kp.enc_b = enc_b; kp.ep_b = ep_b;
    kp.wgh = wgh; kp.wgx = wgx; kp.wgc = wgc; kp.ow_b = ow_b;
    kp.awd = awd; kp.sw = sww; kp.bd = abd; kp.av = av; kp.avb = avb;
    kp.bih = bih; kp.bhh = bhh; kp.p_ob = obb; kp.p_sb = sbb;
    kp.h_f32 = h_f32; kp.h_fb = h_fb;
    kp.ctx_b = ctx_b; kp.den = den; kp.es_b = es_b; kp.dpp = dpp;
    kp.gflag = gflag; kp.aflag = aflag; kp.mflag = mflag; kp.out = out;

    KP* kparg = &kp;
    void* args[] = { (void*)kparg };
    hipLaunchCooperativeKernel((void*)k_persist, dim3(256), dim3(1024),
                               args, DYN_BYTES, stream);
}